// Round 2
// baseline (2269.472 us; speedup 1.0000x reference)
//
#include <hip/hip_runtime.h>
#include <hip/hip_bf16.h>

// Problem constants (from reference)
#define NN    20000   // nodes
#define KE    16      // ego-net size
#define FIN   128     // input feats / hidden
#define FOUT2 64      // output classes
#define NE    640000  // edges

// ---------------- do_conv core: per ego net, y = A*(A*xg), atomic scatter ----
// One block (128 threads) per node n; thread t owns feature column t.
__global__ __launch_bounds__(128) void ego_conv_kernel(
    const float* __restrict__ x, const int* __restrict__ ego_ids,
    const float* __restrict__ ego_adj, float* __restrict__ out /*zeroed*/) {
    const int n = blockIdx.x;
    const int t = threadIdx.x;
    __shared__ float A[KE * KE];
    __shared__ int ids[KE];
    const float* adj = ego_adj + (size_t)n * (KE * KE);
    A[t]       = adj[t];
    A[t + 128] = adj[t + 128];
    if (t < KE) ids[t] = ego_ids[n * KE + t];
    __syncthreads();

    float xg[KE];
#pragma unroll
    for (int k = 0; k < KE; ++k) xg[k] = x[(size_t)ids[k] * FIN + t];

    float y1[KE];
#pragma unroll
    for (int i = 0; i < KE; ++i) {
        float s = 0.f;
#pragma unroll
        for (int k = 0; k < KE; ++k) s += A[i * KE + k] * xg[k];
        y1[i] = s;
    }
#pragma unroll
    for (int i = 0; i < KE; ++i) {
        float s = 0.f;
#pragma unroll
        for (int k = 0; k < KE; ++k) s += A[i * KE + k] * y1[k];
        atomicAdd(&out[(size_t)ids[i] * FIN + t], s);
    }
}

// ---------------- dense linear: out[N,FO] = (opt ndeg-scale) in[N,128] @ W + b
template <int FO, bool RELU, bool SCALE, bool BIAS>
__global__ __launch_bounds__(FO) void linear_kernel(
    const float* __restrict__ in, const float* __restrict__ W,
    const float* __restrict__ b, const float* __restrict__ ndeg,
    float* __restrict__ out) {
    constexpr int ROWS = 8;  // 20000 % 8 == 0
    const int r0 = blockIdx.x * ROWS;
    const int j = threadIdx.x;
    __shared__ float rows[ROWS][FIN];
    for (int idx = j; idx < ROWS * FIN; idx += FO) {
        int r = idx >> 7, k = idx & 127;
        int nn = r0 + r;
        float v = in[(size_t)nn * FIN + k];
        if (SCALE) v *= ndeg[nn];
        rows[r][k] = v;
    }
    __syncthreads();
    float acc[ROWS] = {};
    for (int k = 0; k < FIN; ++k) {
        float w = W[k * FO + j];
#pragma unroll
        for (int r = 0; r < ROWS; ++r) acc[r] += rows[r][k] * w;
    }
    const float bias = BIAS ? b[j] : 0.f;
#pragma unroll
    for (int r = 0; r < ROWS; ++r) {
        float v = acc[r] + bias;
        if (RELU) v = fmaxf(v, 0.f);
        out[(size_t)(r0 + r) * FO + j] = v;
    }
}

// ---------------- GCN degree / normalization ----------------
__global__ void deg_count_kernel(const int* __restrict__ dst, int* __restrict__ deg) {
    int e = blockIdx.x * blockDim.x + threadIdx.x;
    if (e < NE) atomicAdd(&deg[dst[e]], 1);
}
__global__ void dinv_kernel(const int* __restrict__ deg, float* __restrict__ dinv) {
    int v = blockIdx.x * blockDim.x + threadIdx.x;
    if (v < NN) dinv[v] = rsqrtf((float)(deg[v] + 1));  // +1 self loop
}

// out[v,:] = hW[v,:]*dinv[v]^2 + b   (self-loop term + bias)
template <int F>
__global__ void gcn_init_kernel(const float* __restrict__ hW, const float* __restrict__ dinv,
                                const float* __restrict__ b, float* __restrict__ out) {
    int idx = blockIdx.x * blockDim.x + threadIdx.x;
    if (idx >= NN * F) return;
    int v = idx / F, j = idx & (F - 1);
    float di = dinv[v];
    out[idx] = hW[idx] * di * di + b[j];
}

// out[d,:] += hW[s,:] * dinv[s]*dinv[d]  for each edge; 4 feats per thread
template <int F>
__global__ void gcn_edge_kernel(const int* __restrict__ src, const int* __restrict__ dst,
                                const float* __restrict__ hW, const float* __restrict__ dinv,
                                float* __restrict__ out) {
    constexpr int FV = F / 4;
    long long tid = (long long)blockIdx.x * blockDim.x + threadIdx.x;
    int e = (int)(tid / FV);
    int j4 = (int)(tid % FV) * 4;
    if (e >= NE) return;
    int s = src[e], d = dst[e];
    float w = dinv[s] * dinv[d];
    const float4 v = *(const float4*)&hW[(size_t)s * F + j4];
    float* o = &out[(size_t)d * F + j4];
    atomicAdd(o + 0, v.x * w);
    atomicAdd(o + 1, v.y * w);
    atomicAdd(o + 2, v.z * w);
    atomicAdd(o + 3, v.w * w);
}

// ---------------- log_softmax over 64 classes, fp32 out ----------------
__global__ __launch_bounds__(256) void logsoftmax_kernel(const float* __restrict__ in,
                                                         float* __restrict__ out) {
    int t = threadIdx.x;
    int row = blockIdx.x * 4 + (t >> 6);  // one 64-lane wave per row
    int j = t & 63;
    float x = in[(size_t)row * FOUT2 + j];
    float m = x;
#pragma unroll
    for (int o = 32; o > 0; o >>= 1) m = fmaxf(m, __shfl_xor(m, o));
    float ex = __expf(x - m);
    float s = ex;
#pragma unroll
    for (int o = 32; o > 0; o >>= 1) s += __shfl_xor(s, o);
    out[(size_t)row * FOUT2 + j] = x - m - __logf(s);
}

extern "C" void kernel_launch(void* const* d_in, const int* in_sizes, int n_in,
                              void* d_out, int out_size, void* d_ws, size_t ws_size,
                              hipStream_t stream) {
    (void)in_sizes; (void)n_in; (void)out_size; (void)ws_size;
    const float* x      = (const float*)d_in[0];
    const int*   eidx   = (const int*)d_in[1];
    const int*   egoids = (const int*)d_in[2];
    const float* egoadj = (const float*)d_in[3];
    const float* ndeg   = (const float*)d_in[4];
    const float* W_ego1 = (const float*)d_in[5];
    const float* b_ego1 = (const float*)d_in[6];
    const float* W_gcn1 = (const float*)d_in[7];
    const float* b_gcn1 = (const float*)d_in[8];
    const float* W_ego2 = (const float*)d_in[9];
    const float* b_ego2 = (const float*)d_in[10];
    const float* W_gcn2 = (const float*)d_in[11];
    const float* b_gcn2 = (const float*)d_in[12];
    const int* src = eidx;
    const int* dst = eidx + NE;

    char* ws = (char*)d_ws;
    float* dinv = (float*)ws;                         // N*4 bytes
    int*   deg  = (int*)(ws + (128 << 10));           // N*4 bytes
    float* bufA = (float*)(ws + (256 << 10));         // N*128 f32
    float* bufB = bufA + (size_t)NN * FIN;
    float* bufC = bufB + (size_t)NN * FIN;

    // degrees (reused by both GCN layers)
    hipMemsetAsync(deg, 0, NN * sizeof(int), stream);
    deg_count_kernel<<<(NE + 255) / 256, 256, 0, stream>>>(dst, deg);
    dinv_kernel<<<(NN + 255) / 256, 256, 0, stream>>>(deg, dinv);

    // ---- layer 1 ----
    hipMemsetAsync(bufA, 0, (size_t)NN * FIN * sizeof(float), stream);
    ego_conv_kernel<<<NN, 128, 0, stream>>>(x, egoids, egoadj, bufA);
    // B = relu((ndeg .* A) @ W_ego1 + b_ego1)
    linear_kernel<128, true, true, true><<<NN / 8, 128, 0, stream>>>(bufA, W_ego1, b_ego1, ndeg, bufB);
    // C = B @ W_gcn1 (bias applied post-aggregation)
    linear_kernel<128, false, false, false><<<NN / 8, 128, 0, stream>>>(bufB, W_gcn1, nullptr, nullptr, bufC);
    gcn_init_kernel<128><<<(NN * 128 + 255) / 256, 256, 0, stream>>>(bufC, dinv, b_gcn1, bufA);
    gcn_edge_kernel<128><<<(int)(((long long)NE * (128 / 4) + 255) / 256), 256, 0, stream>>>(src, dst, bufC, dinv, bufA);

    // ---- layer 2 ----
    hipMemsetAsync(bufB, 0, (size_t)NN * FIN * sizeof(float), stream);
    ego_conv_kernel<<<NN, 128, 0, stream>>>(bufA, egoids, egoadj, bufB);
    // C = (ndeg .* B) @ W_ego2 + b_ego2  (no relu)
    linear_kernel<128, false, true, true><<<NN / 8, 128, 0, stream>>>(bufB, W_ego2, b_ego2, ndeg, bufC);
    // A = C @ W_gcn2  [N,64]
    linear_kernel<64, false, false, false><<<NN / 8, 64, 0, stream>>>(bufC, W_gcn2, nullptr, nullptr, bufA);
    gcn_init_kernel<64><<<(NN * 64 + 255) / 256, 256, 0, stream>>>(bufA, dinv, b_gcn2, bufB);
    gcn_edge_kernel<64><<<(int)(((long long)NE * (64 / 4) + 255) / 256), 256, 0, stream>>>(src, dst, bufA, dinv, bufB);

    // ---- log_softmax -> fp32 out ----
    logsoftmax_kernel<<<NN / 4, 256, 0, stream>>>(bufB, (float*)d_out);
}

// Round 3
// 903.001 us; speedup vs baseline: 2.5133x; 2.5133x over previous
//
#include <hip/hip_runtime.h>
#include <hip/hip_bf16.h>

#define NN    20000   // nodes
#define KE    16      // ego-net size
#define FIN   128     // input feats / hidden
#define FOUT2 64      // output classes
#define NE    640000  // edges

// ---------------- histograms ----------------
__global__ void deg_count_kernel(const int* __restrict__ dst, int* __restrict__ deg) {
    int e = blockIdx.x * blockDim.x + threadIdx.x;
    if (e < NE) atomicAdd(&deg[dst[e]], 1);
}
__global__ void ego_hist_kernel(const int* __restrict__ ego_flat, int* __restrict__ edeg) {
    int p = blockIdx.x * blockDim.x + threadIdx.x;
    if (p < NN * KE) atomicAdd(&edeg[ego_flat[p]], 1);
}

// ---------------- single-block exclusive scan over n counters ----------------
__global__ __launch_bounds__(256) void scan_kernel(const int* __restrict__ cnt,
                                                   int* __restrict__ ofs, int n) {
    __shared__ int part[256];
    const int t = threadIdx.x;
    const int chunk = (n + 255) / 256;
    const int lo = t * chunk;
    const int hi = min(lo + chunk, n);
    int s = 0;
    for (int i = lo; i < hi; ++i) s += cnt[i];
    part[t] = s;
    __syncthreads();
    for (int o = 1; o < 256; o <<= 1) {
        int v = (t >= o) ? part[t - o] : 0;
        __syncthreads();
        part[t] += v;
        __syncthreads();
    }
    int base = part[t] - s;  // exclusive prefix
    for (int i = lo; i < hi; ++i) { ofs[i] = base; base += cnt[i]; }
    if (lo < n && hi == n) ofs[n] = base;
}

// ---------------- bucket edges / ego memberships into CSR ----------------
__global__ void bucket_edges_kernel(const int* __restrict__ src, const int* __restrict__ dst,
                                    const int* __restrict__ rowstart, int* __restrict__ cursor,
                                    int* __restrict__ csr_src) {
    int e = blockIdx.x * blockDim.x + threadIdx.x;
    if (e >= NE) return;
    int d = dst[e];
    int pos = atomicAdd(&cursor[d], 1);
    csr_src[rowstart[d] + pos] = src[e];
}
__global__ void bucket_ego_kernel(const int* __restrict__ ego_flat,
                                  const int* __restrict__ erowstart, int* __restrict__ ecursor,
                                  int* __restrict__ ecsr) {
    int p = blockIdx.x * blockDim.x + threadIdx.x;
    if (p >= NN * KE) return;
    int v = ego_flat[p];
    int pos = atomicAdd(&ecursor[v], 1);
    ecsr[erowstart[v] + pos] = p;  // p encodes (n, i) = (p>>4, p&15)
}

__global__ void dinv_kernel(const int* __restrict__ deg, float* __restrict__ dinv) {
    int v = blockIdx.x * blockDim.x + threadIdx.x;
    if (v < NN) dinv[v] = rsqrtf((float)(deg[v] + 1));  // +1 self loop
}

// ---------------- A2[n] = A[n] @ A[n] (16x16) ----------------
__global__ __launch_bounds__(256) void a2_kernel(const float* __restrict__ ego_adj,
                                                 float* __restrict__ A2) {
    const int n = blockIdx.x, t = threadIdx.x;
    __shared__ float A[256];
    A[t] = ego_adj[(size_t)n * 256 + t];
    __syncthreads();
    const int i = t >> 4, k = t & 15;
    float s = 0.f;
#pragma unroll
    for (int j = 0; j < KE; ++j) s += A[i * KE + j] * A[j * KE + k];
    A2[(size_t)n * 256 + t] = s;
}

// ---------------- ego gather: out[v] = sum_{(n,i) in mem(v)} sum_k A2[n,i,k]*x[ids[n,k]]
__global__ __launch_bounds__(128) void ego_gather_kernel(
    const float* __restrict__ x, const int* __restrict__ ego_ids,
    const float* __restrict__ A2, const int* __restrict__ erowstart,
    const int* __restrict__ ecsr, float* __restrict__ out) {
    const int v = blockIdx.x, t = threadIdx.x;
    float s = 0.f;
    const int pbeg = erowstart[v], pend = erowstart[v + 1];
    for (int p = pbeg; p < pend; ++p) {
        const int pair = ecsr[p];
        const int n = pair >> 4;
        const int* ids = &ego_ids[n << 4];
        const float* a2row = &A2[(size_t)pair << 4];
#pragma unroll
        for (int k = 0; k < KE; ++k)
            s += a2row[k] * x[(size_t)ids[k] * FIN + t];
    }
    out[(size_t)v * FIN + t] = s;
}

// -------- dense linear: out[N,FO] = (ndeg.*in)[N,128] @ W (+b) (*dinv row) ----
template <int FO, bool RELU, bool INSCALE, bool BIAS, bool OUTSCALE>
__global__ __launch_bounds__(FO) void linear_kernel(
    const float* __restrict__ in, const float* __restrict__ W,
    const float* __restrict__ b, const float* __restrict__ ndeg,
    const float* __restrict__ dinv, float* __restrict__ out) {
    constexpr int ROWS = 8;  // 20000 % 8 == 0
    const int r0 = blockIdx.x * ROWS;
    const int j = threadIdx.x;
    __shared__ float rows[ROWS][FIN];
    for (int idx = j; idx < ROWS * FIN; idx += FO) {
        int r = idx >> 7, k = idx & 127;
        int nn = r0 + r;
        float v = in[(size_t)nn * FIN + k];
        if (INSCALE) v *= ndeg[nn];
        rows[r][k] = v;
    }
    __syncthreads();
    float acc[ROWS] = {};
    for (int k = 0; k < FIN; ++k) {
        float w = W[k * FO + j];
#pragma unroll
        for (int r = 0; r < ROWS; ++r) acc[r] += rows[r][k] * w;
    }
    const float bias = BIAS ? b[j] : 0.f;
#pragma unroll
    for (int r = 0; r < ROWS; ++r) {
        float v = acc[r] + bias;
        if (RELU) v = fmaxf(v, 0.f);
        if (OUTSCALE) v *= dinv[r0 + r];
        out[(size_t)(r0 + r) * FO + j] = v;
    }
}

// ---------------- GCN gather: out[d] = (self + sum_e hWs[src_e]) * dinv[d] + b
// hWs rows are pre-scaled by dinv[src] (OUTSCALE in producing linear).
__global__ __launch_bounds__(128) void gcn_gather128_kernel(
    const float* __restrict__ hWs, const int* __restrict__ rowstart,
    const int* __restrict__ csr_src, const float* __restrict__ dinv,
    const float* __restrict__ b, float* __restrict__ out) {
    const int d = blockIdx.x, t = threadIdx.x;
    float s = hWs[(size_t)d * FIN + t];  // self loop (already *dinv[d])
    int e = rowstart[d];
    const int eend = rowstart[d + 1];
    for (; e + 4 <= eend; e += 4) {
        int s0 = csr_src[e], s1 = csr_src[e + 1], s2 = csr_src[e + 2], s3 = csr_src[e + 3];
        s += hWs[(size_t)s0 * FIN + t] + hWs[(size_t)s1 * FIN + t]
           + hWs[(size_t)s2 * FIN + t] + hWs[(size_t)s3 * FIN + t];
    }
    for (; e < eend; ++e) s += hWs[(size_t)csr_src[e] * FIN + t];
    out[(size_t)d * FIN + t] = s * dinv[d] + b[t];
}

// ---------------- fused GCN gather (F=64) + bias + log_softmax -> d_out ------
__global__ __launch_bounds__(256) void gcn_gather_lsm_kernel(
    const float* __restrict__ hWs, const int* __restrict__ rowstart,
    const int* __restrict__ csr_src, const float* __restrict__ dinv,
    const float* __restrict__ b, float* __restrict__ out) {
    const int tid = threadIdx.x;
    const int d = blockIdx.x * 4 + (tid >> 6);  // one 64-lane wave per node
    const int t = tid & 63;
    float s = hWs[(size_t)d * FOUT2 + t];  // self loop
    int e = rowstart[d];
    const int eend = rowstart[d + 1];
    for (; e + 4 <= eend; e += 4) {
        int s0 = csr_src[e], s1 = csr_src[e + 1], s2 = csr_src[e + 2], s3 = csr_src[e + 3];
        s += hWs[(size_t)s0 * FOUT2 + t] + hWs[(size_t)s1 * FOUT2 + t]
           + hWs[(size_t)s2 * FOUT2 + t] + hWs[(size_t)s3 * FOUT2 + t];
    }
    for (; e < eend; ++e) s += hWs[(size_t)csr_src[e] * FOUT2 + t];
    const float xv = s * dinv[d] + b[t];
    float m = xv;
#pragma unroll
    for (int o = 32; o > 0; o >>= 1) m = fmaxf(m, __shfl_xor(m, o));
    float ex = __expf(xv - m);
    float sm = ex;
#pragma unroll
    for (int o = 32; o > 0; o >>= 1) sm += __shfl_xor(sm, o);
    out[(size_t)d * FOUT2 + t] = xv - m - __logf(sm);
}

extern "C" void kernel_launch(void* const* d_in, const int* in_sizes, int n_in,
                              void* d_out, int out_size, void* d_ws, size_t ws_size,
                              hipStream_t stream) {
    (void)in_sizes; (void)n_in; (void)out_size; (void)ws_size;
    const float* x      = (const float*)d_in[0];
    const int*   eidx   = (const int*)d_in[1];
    const int*   egoids = (const int*)d_in[2];
    const float* egoadj = (const float*)d_in[3];
    const float* ndeg   = (const float*)d_in[4];
    const float* W_ego1 = (const float*)d_in[5];
    const float* b_ego1 = (const float*)d_in[6];
    const float* W_gcn1 = (const float*)d_in[7];
    const float* b_gcn1 = (const float*)d_in[8];
    const float* W_ego2 = (const float*)d_in[9];
    const float* b_ego2 = (const float*)d_in[10];
    const float* W_gcn2 = (const float*)d_in[11];
    const float* b_gcn2 = (const float*)d_in[12];
    const int* src = eidx;
    const int* dst = eidx + NE;

    // ---- workspace layout (~56 MB) ----
    int* ip = (int*)d_ws;
    int* deg       = ip;               // NN
    int* cursor    = deg + NN;         // NN
    int* edeg      = cursor + NN;      // NN
    int* ecursor   = edeg + NN;        // NN   (zero these 4 together)
    int* rowstart  = ecursor + NN;     // NN+1
    int* erowstart = rowstart + NN + 8;// NN+1
    int* csr_src   = erowstart + NN + 8;   // NE
    int* ecsr      = csr_src + NE;         // NN*KE
    float* dinv = (float*)(ecsr + NN * KE);          // NN
    float* A2   = dinv + NN;                         // NN*256
    float* bufA = A2 + (size_t)NN * 256;             // NN*128
    float* bufB = bufA + (size_t)NN * FIN;           // NN*128
    float* bufC = bufB + (size_t)NN * FIN;           // NN*128

    // ---- CSR build (edges by dst, ego memberships by target) ----
    hipMemsetAsync(deg, 0, 4 * NN * sizeof(int), stream);
    deg_count_kernel<<<(NE + 255) / 256, 256, 0, stream>>>(dst, deg);
    ego_hist_kernel<<<(NN * KE + 255) / 256, 256, 0, stream>>>(egoids, edeg);
    scan_kernel<<<1, 256, 0, stream>>>(deg, rowstart, NN);
    scan_kernel<<<1, 256, 0, stream>>>(edeg, erowstart, NN);
    bucket_edges_kernel<<<(NE + 255) / 256, 256, 0, stream>>>(src, dst, rowstart, cursor, csr_src);
    bucket_ego_kernel<<<(NN * KE + 255) / 256, 256, 0, stream>>>(egoids, erowstart, ecursor, ecsr);
    dinv_kernel<<<(NN + 255) / 256, 256, 0, stream>>>(deg, dinv);
    a2_kernel<<<NN, 256, 0, stream>>>(egoadj, A2);

    // ---- layer 1 ----
    ego_gather_kernel<<<NN, 128, 0, stream>>>(x, egoids, A2, erowstart, ecsr, bufA);
    // B = relu((ndeg .* A) @ W_ego1 + b_ego1)
    linear_kernel<128, true, true, true, false><<<NN / 8, 128, 0, stream>>>(bufA, W_ego1, b_ego1, ndeg, nullptr, bufB);
    // C = (B @ W_gcn1) * dinv[row]   (pre-scaled messages)
    linear_kernel<128, false, false, false, true><<<NN / 8, 128, 0, stream>>>(bufB, W_gcn1, nullptr, nullptr, dinv, bufC);
    gcn_gather128_kernel<<<NN, 128, 0, stream>>>(bufC, rowstart, csr_src, dinv, b_gcn1, bufA);

    // ---- layer 2 ----
    ego_gather_kernel<<<NN, 128, 0, stream>>>(bufA, egoids, A2, erowstart, ecsr, bufB);
    // C = (ndeg .* B) @ W_ego2 + b_ego2 (no relu)
    linear_kernel<128, false, true, true, false><<<NN / 8, 128, 0, stream>>>(bufB, W_ego2, b_ego2, ndeg, nullptr, bufC);
    // A = (C @ W_gcn2) * dinv[row]  [N,64]
    linear_kernel<64, false, false, false, true><<<NN / 8, 64, 0, stream>>>(bufC, W_gcn2, nullptr, nullptr, dinv, bufA);
    // fused gather + bias + log_softmax
    gcn_gather_lsm_kernel<<<NN / 4, 256, 0, stream>>>(bufA, rowstart, csr_src, dinv, b_gcn2, (float*)d_out);
}

// Round 4
// 579.754 us; speedup vs baseline: 3.9145x; 1.5576x over previous
//
#include <hip/hip_runtime.h>
#include <hip/hip_bf16.h>

#define NN    20000   // nodes
#define KE    16      // ego-net size
#define FIN   128     // input feats / hidden
#define FOUT2 64      // output classes
#define NE    640000  // edges

// ---------------- histograms ----------------
__global__ void deg_count_kernel(const int* __restrict__ dst, int* __restrict__ deg) {
    int e = blockIdx.x * blockDim.x + threadIdx.x;
    if (e < NE) atomicAdd(&deg[dst[e]], 1);
}
__global__ void ego_hist_kernel(const int* __restrict__ ego_flat, int* __restrict__ edeg) {
    int p = blockIdx.x * blockDim.x + threadIdx.x;
    if (p < NN * KE) atomicAdd(&edeg[ego_flat[p]], 1);
}

// ---------------- single-block exclusive scan over n counters ----------------
__global__ __launch_bounds__(256) void scan_kernel(const int* __restrict__ cnt,
                                                   int* __restrict__ ofs, int n) {
    __shared__ int part[256];
    const int t = threadIdx.x;
    const int chunk = (n + 255) / 256;
    const int lo = t * chunk;
    const int hi = min(lo + chunk, n);
    int s = 0;
    for (int i = lo; i < hi; ++i) s += cnt[i];
    part[t] = s;
    __syncthreads();
    for (int o = 1; o < 256; o <<= 1) {
        int v = (t >= o) ? part[t - o] : 0;
        __syncthreads();
        part[t] += v;
        __syncthreads();
    }
    int base = part[t] - s;  // exclusive prefix
    for (int i = lo; i < hi; ++i) { ofs[i] = base; base += cnt[i]; }
    if (lo < n && hi == n) ofs[n] = base;
}

// ---------------- bucket edges / ego memberships into CSR ----------------
__global__ void bucket_edges_kernel(const int* __restrict__ src, const int* __restrict__ dst,
                                    const int* __restrict__ rowstart, int* __restrict__ cursor,
                                    int* __restrict__ csr_src) {
    int e = blockIdx.x * blockDim.x + threadIdx.x;
    if (e >= NE) return;
    int d = dst[e];
    int pos = atomicAdd(&cursor[d], 1);
    csr_src[rowstart[d] + pos] = src[e];
}
__global__ void bucket_ego_kernel(const int* __restrict__ ego_flat,
                                  const int* __restrict__ erowstart, int* __restrict__ ecursor,
                                  int* __restrict__ ecsr) {
    int p = blockIdx.x * blockDim.x + threadIdx.x;
    if (p >= NN * KE) return;
    int v = ego_flat[p];
    int pos = atomicAdd(&ecursor[v], 1);
    ecsr[erowstart[v] + pos] = p;  // p encodes (n, i) = (p>>4, p&15)
}

__global__ void dinv_kernel(const int* __restrict__ deg, float* __restrict__ dinv) {
    int v = blockIdx.x * blockDim.x + threadIdx.x;
    if (v < NN) dinv[v] = rsqrtf((float)(deg[v] + 1));  // +1 self loop
}

// ---------------- A2[n] = A[n] @ A[n] (16x16) ----------------
__global__ __launch_bounds__(256) void a2_kernel(const float* __restrict__ ego_adj,
                                                 float* __restrict__ A2) {
    const int n = blockIdx.x, t = threadIdx.x;
    __shared__ float A[256];
    A[t] = ego_adj[(size_t)n * 256 + t];
    __syncthreads();
    const int i = t >> 4, k = t & 15;
    float s = 0.f;
#pragma unroll
    for (int j = 0; j < KE; ++j) s += A[i * KE + j] * A[j * KE + k];
    A2[(size_t)n * 256 + t] = s;
}

// ---------------- ego phase 1: Y[n] = A2[n] @ x[ids[n]]  (16x128 per net) ----
__global__ __launch_bounds__(128) void ego_apply_kernel(
    const float* __restrict__ x, const int* __restrict__ ego_ids,
    const float* __restrict__ A2, float* __restrict__ Y) {
    const int n = blockIdx.x, t = threadIdx.x;
    __shared__ float As[256];
    __shared__ int ids[KE];
    const float* a2 = A2 + (size_t)n * 256;
    As[t] = a2[t];
    As[t + 128] = a2[t + 128];
    if (t < KE) ids[t] = ego_ids[n * KE + t];
    __syncthreads();
    float xg[KE];
#pragma unroll
    for (int k = 0; k < KE; ++k) xg[k] = x[(size_t)ids[k] * FIN + t];
    float* yout = Y + ((size_t)n * KE) * FIN + t;
#pragma unroll
    for (int i = 0; i < KE; ++i) {
        float s = 0.f;
#pragma unroll
        for (int k = 0; k < KE; ++k) s += As[i * KE + k] * xg[k];
        yout[i * FIN] = s;
    }
}

// ---------------- ego phase 2: out[v] = sum_{p in mem(v)} Y[p] ----------------
__global__ __launch_bounds__(128) void ego_reduce_kernel(
    const float* __restrict__ Y, const int* __restrict__ erowstart,
    const int* __restrict__ ecsr, float* __restrict__ out) {
    const int v = blockIdx.x, t = threadIdx.x;
    float s = 0.f;
    int p = erowstart[v];
    const int pend = erowstart[v + 1];
    for (; p + 4 <= pend; p += 4) {
        int p0 = ecsr[p], p1 = ecsr[p + 1], p2 = ecsr[p + 2], p3 = ecsr[p + 3];
        s += Y[(size_t)p0 * FIN + t] + Y[(size_t)p1 * FIN + t]
           + Y[(size_t)p2 * FIN + t] + Y[(size_t)p3 * FIN + t];
    }
    for (; p < pend; ++p) s += Y[(size_t)ecsr[p] * FIN + t];
    out[(size_t)v * FIN + t] = s;
}

// ---------------- fallback one-phase ego gather (if ws too small) -----------
__global__ __launch_bounds__(128) void ego_gather_kernel(
    const float* __restrict__ x, const int* __restrict__ ego_ids,
    const float* __restrict__ A2, const int* __restrict__ erowstart,
    const int* __restrict__ ecsr, float* __restrict__ out) {
    const int v = blockIdx.x, t = threadIdx.x;
    float s = 0.f;
    const int pbeg = erowstart[v], pend = erowstart[v + 1];
    for (int p = pbeg; p < pend; ++p) {
        const int pair = ecsr[p];
        const int n = pair >> 4;
        const int* ids = &ego_ids[n << 4];
        const float* a2row = &A2[(size_t)pair << 4];
#pragma unroll
        for (int k = 0; k < KE; ++k)
            s += a2row[k] * x[(size_t)ids[k] * FIN + t];
    }
    out[(size_t)v * FIN + t] = s;
}

// -------- dense linear: out[N,FO] = (ndeg.*in)[N,128] @ W (+b) (*dinv row) ----
template <int FO, bool RELU, bool INSCALE, bool BIAS, bool OUTSCALE>
__global__ __launch_bounds__(FO) void linear_kernel(
    const float* __restrict__ in, const float* __restrict__ W,
    const float* __restrict__ b, const float* __restrict__ ndeg,
    const float* __restrict__ dinv, float* __restrict__ out) {
    constexpr int ROWS = 8;  // 20000 % 8 == 0
    const int r0 = blockIdx.x * ROWS;
    const int j = threadIdx.x;
    __shared__ float rows[ROWS][FIN];
    for (int idx = j; idx < ROWS * FIN; idx += FO) {
        int r = idx >> 7, k = idx & 127;
        int nn = r0 + r;
        float v = in[(size_t)nn * FIN + k];
        if (INSCALE) v *= ndeg[nn];
        rows[r][k] = v;
    }
    __syncthreads();
    float acc[ROWS] = {};
    for (int k = 0; k < FIN; ++k) {
        float w = W[k * FO + j];
#pragma unroll
        for (int r = 0; r < ROWS; ++r) acc[r] += rows[r][k] * w;
    }
    const float bias = BIAS ? b[j] : 0.f;
#pragma unroll
    for (int r = 0; r < ROWS; ++r) {
        float v = acc[r] + bias;
        if (RELU) v = fmaxf(v, 0.f);
        if (OUTSCALE) v *= dinv[r0 + r];
        out[(size_t)(r0 + r) * FO + j] = v;
    }
}

// ---------------- GCN gather: out[d] = (self + sum_e hWs[src_e]) * dinv[d] + b
__global__ __launch_bounds__(128) void gcn_gather128_kernel(
    const float* __restrict__ hWs, const int* __restrict__ rowstart,
    const int* __restrict__ csr_src, const float* __restrict__ dinv,
    const float* __restrict__ b, float* __restrict__ out) {
    const int d = blockIdx.x, t = threadIdx.x;
    float s = hWs[(size_t)d * FIN + t];  // self loop (already *dinv[d])
    int e = rowstart[d];
    const int eend = rowstart[d + 1];
    for (; e + 4 <= eend; e += 4) {
        int s0 = csr_src[e], s1 = csr_src[e + 1], s2 = csr_src[e + 2], s3 = csr_src[e + 3];
        s += hWs[(size_t)s0 * FIN + t] + hWs[(size_t)s1 * FIN + t]
           + hWs[(size_t)s2 * FIN + t] + hWs[(size_t)s3 * FIN + t];
    }
    for (; e < eend; ++e) s += hWs[(size_t)csr_src[e] * FIN + t];
    out[(size_t)d * FIN + t] = s * dinv[d] + b[t];
}

// ---------------- fused GCN gather (F=64) + bias + log_softmax -> d_out ------
__global__ __launch_bounds__(256) void gcn_gather_lsm_kernel(
    const float* __restrict__ hWs, const int* __restrict__ rowstart,
    const int* __restrict__ csr_src, const float* __restrict__ dinv,
    const float* __restrict__ b, float* __restrict__ out) {
    const int tid = threadIdx.x;
    const int d = blockIdx.x * 4 + (tid >> 6);  // one 64-lane wave per node
    const int t = tid & 63;
    float s = hWs[(size_t)d * FOUT2 + t];  // self loop
    int e = rowstart[d];
    const int eend = rowstart[d + 1];
    for (; e + 4 <= eend; e += 4) {
        int s0 = csr_src[e], s1 = csr_src[e + 1], s2 = csr_src[e + 2], s3 = csr_src[e + 3];
        s += hWs[(size_t)s0 * FOUT2 + t] + hWs[(size_t)s1 * FOUT2 + t]
           + hWs[(size_t)s2 * FOUT2 + t] + hWs[(size_t)s3 * FOUT2 + t];
    }
    for (; e < eend; ++e) s += hWs[(size_t)csr_src[e] * FOUT2 + t];
    const float xv = s * dinv[d] + b[t];
    float m = xv;
#pragma unroll
    for (int o = 32; o > 0; o >>= 1) m = fmaxf(m, __shfl_xor(m, o));
    float ex = __expf(xv - m);
    float sm = ex;
#pragma unroll
    for (int o = 32; o > 0; o >>= 1) sm += __shfl_xor(sm, o);
    out[(size_t)d * FOUT2 + t] = xv - m - __logf(sm);
}

extern "C" void kernel_launch(void* const* d_in, const int* in_sizes, int n_in,
                              void* d_out, int out_size, void* d_ws, size_t ws_size,
                              hipStream_t stream) {
    (void)in_sizes; (void)n_in; (void)out_size;
    const float* x      = (const float*)d_in[0];
    const int*   eidx   = (const int*)d_in[1];
    const int*   egoids = (const int*)d_in[2];
    const float* egoadj = (const float*)d_in[3];
    const float* ndeg   = (const float*)d_in[4];
    const float* W_ego1 = (const float*)d_in[5];
    const float* b_ego1 = (const float*)d_in[6];
    const float* W_gcn1 = (const float*)d_in[7];
    const float* b_gcn1 = (const float*)d_in[8];
    const float* W_ego2 = (const float*)d_in[9];
    const float* b_ego2 = (const float*)d_in[10];
    const float* W_gcn2 = (const float*)d_in[11];
    const float* b_gcn2 = (const float*)d_in[12];
    const int* src = eidx;
    const int* dst = eidx + NE;

    // ---- workspace layout ----
    int* ip = (int*)d_ws;
    int* deg       = ip;               // NN
    int* cursor    = deg + NN;         // NN
    int* edeg      = cursor + NN;      // NN
    int* ecursor   = edeg + NN;        // NN   (zero these 4 together)
    int* rowstart  = ecursor + NN;     // NN+1
    int* erowstart = rowstart + NN + 8;// NN+1
    int* csr_src   = erowstart + NN + 8;   // NE
    int* ecsr      = csr_src + NE;         // NN*KE
    float* dinv = (float*)(ecsr + NN * KE);          // NN
    float* A2   = dinv + NN;                         // NN*256
    float* bufA = A2 + (size_t)NN * 256;             // NN*128
    float* bufB = bufA + (size_t)NN * FIN;           // NN*128
    float* bufC = bufB + (size_t)NN * FIN;           // NN*128
    float* Y    = bufC + (size_t)NN * FIN;           // NN*KE*128 (164 MB)
    const size_t need = (size_t)((char*)(Y + (size_t)NN * KE * FIN) - (char*)d_ws);
    const bool twophase = (ws_size >= need);  // constant across calls -> graph-safe

    // ---- CSR build (edges by dst, ego memberships by target) ----
    hipMemsetAsync(deg, 0, 4 * NN * sizeof(int), stream);
    deg_count_kernel<<<(NE + 255) / 256, 256, 0, stream>>>(dst, deg);
    ego_hist_kernel<<<(NN * KE + 255) / 256, 256, 0, stream>>>(egoids, edeg);
    scan_kernel<<<1, 256, 0, stream>>>(deg, rowstart, NN);
    scan_kernel<<<1, 256, 0, stream>>>(edeg, erowstart, NN);
    bucket_edges_kernel<<<(NE + 255) / 256, 256, 0, stream>>>(src, dst, rowstart, cursor, csr_src);
    bucket_ego_kernel<<<(NN * KE + 255) / 256, 256, 0, stream>>>(egoids, erowstart, ecursor, ecsr);
    dinv_kernel<<<(NN + 255) / 256, 256, 0, stream>>>(deg, dinv);
    a2_kernel<<<NN, 256, 0, stream>>>(egoadj, A2);

    // ---- layer 1 ----
    if (twophase) {
        ego_apply_kernel<<<NN, 128, 0, stream>>>(x, egoids, A2, Y);
        ego_reduce_kernel<<<NN, 128, 0, stream>>>(Y, erowstart, ecsr, bufA);
    } else {
        ego_gather_kernel<<<NN, 128, 0, stream>>>(x, egoids, A2, erowstart, ecsr, bufA);
    }
    // B = relu((ndeg .* A) @ W_ego1 + b_ego1)
    linear_kernel<128, true, true, true, false><<<NN / 8, 128, 0, stream>>>(bufA, W_ego1, b_ego1, ndeg, nullptr, bufB);
    // C = (B @ W_gcn1) * dinv[row]   (pre-scaled messages)
    linear_kernel<128, false, false, false, true><<<NN / 8, 128, 0, stream>>>(bufB, W_gcn1, nullptr, nullptr, dinv, bufC);
    gcn_gather128_kernel<<<NN, 128, 0, stream>>>(bufC, rowstart, csr_src, dinv, b_gcn1, bufA);

    // ---- layer 2 ----
    if (twophase) {
        ego_apply_kernel<<<NN, 128, 0, stream>>>(bufA, egoids, A2, Y);
        ego_reduce_kernel<<<NN, 128, 0, stream>>>(Y, erowstart, ecsr, bufB);
    } else {
        ego_gather_kernel<<<NN, 128, 0, stream>>>(bufA, egoids, A2, erowstart, ecsr, bufB);
    }
    // C = (ndeg .* B) @ W_ego2 + b_ego2 (no relu)
    linear_kernel<128, false, true, true, false><<<NN / 8, 128, 0, stream>>>(bufB, W_ego2, b_ego2, ndeg, nullptr, bufC);
    // A = (C @ W_gcn2) * dinv[row]  [N,64]
    linear_kernel<64, false, false, false, true><<<NN / 8, 64, 0, stream>>>(bufC, W_gcn2, nullptr, nullptr, dinv, bufA);
    // fused gather + bias + log_softmax
    gcn_gather_lsm_kernel<<<NN / 4, 256, 0, stream>>>(bufA, rowstart, csr_src, dinv, b_gcn2, (float*)d_out);
}

// Round 6
// 503.204 us; speedup vs baseline: 4.5100x; 1.1521x over previous
//
#include <hip/hip_runtime.h>
#include <hip/hip_bf16.h>

#define NN    20000   // nodes
#define KE    16      // ego-net size
#define FIN   128     // input feats / hidden
#define FOUT2 64      // output classes
#define NE    640000  // edges

// ---- bf16 helpers (ushort storage, fp32 math) ----
__device__ __forceinline__ float bf2f(unsigned short u) {
    union { float f; unsigned int i; } c; c.i = ((unsigned int)u) << 16; return c.f;
}
__device__ __forceinline__ unsigned short f2bf(float f) {
    union { float f; unsigned int i; } c; c.f = f;
    unsigned int lsb = (c.i >> 16) & 1u;
    c.i += 0x7fffu + lsb;           // round-to-nearest-even
    return (unsigned short)(c.i >> 16);
}
__device__ __forceinline__ float ldx(const float* p, size_t i) { return p[i]; }
__device__ __forceinline__ float ldx(const unsigned short* p, size_t i) { return bf2f(p[i]); }

// ---------------- fused histograms: edge-dst degree + ego-membership ----------
__global__ void hist2_kernel(const int* __restrict__ dst, const int* __restrict__ ego_flat,
                             int* __restrict__ deg, int* __restrict__ edeg) {
    int i = blockIdx.x * blockDim.x + threadIdx.x;
    if (i < NE) {
        atomicAdd(&deg[dst[i]], 1);
    } else {
        int p = i - NE;
        if (p < NN * KE) atomicAdd(&edeg[ego_flat[p]], 1);
    }
}

// ---------------- two scans in one dispatch (block 0: deg[+dinv], block 1: edeg)
__global__ __launch_bounds__(256) void scan2_kernel(const int* __restrict__ deg,
                                                    const int* __restrict__ edeg,
                                                    int* __restrict__ rowstart,
                                                    int* __restrict__ erowstart,
                                                    float* __restrict__ dinv) {
    const int* cnt = (blockIdx.x == 0) ? deg : edeg;
    int* ofs = (blockIdx.x == 0) ? rowstart : erowstart;
    __shared__ int part[256];
    const int t = threadIdx.x;
    const int chunk = (NN + 255) / 256;
    const int lo = t * chunk;
    const int hi = min(lo + chunk, NN);
    int s = 0;
    for (int i = lo; i < hi; ++i) {
        s += cnt[i];
        if (blockIdx.x == 0) dinv[i] = rsqrtf((float)(cnt[i] + 1));  // +1 self loop
    }
    part[t] = s;
    __syncthreads();
    for (int o = 1; o < 256; o <<= 1) {
        int v = (t >= o) ? part[t - o] : 0;
        __syncthreads();
        part[t] += v;
        __syncthreads();
    }
    int base = part[t] - s;  // exclusive prefix
    for (int i = lo; i < hi; ++i) { ofs[i] = base; base += cnt[i]; }
    if (lo < NN && hi == NN) ofs[NN] = base;
}

// ---------------- fused bucketing into both CSRs ----------------
__global__ void bucket2_kernel(const int* __restrict__ src, const int* __restrict__ dst,
                               const int* __restrict__ ego_flat,
                               const int* __restrict__ rowstart, const int* __restrict__ erowstart,
                               int* __restrict__ cursor, int* __restrict__ ecursor,
                               int* __restrict__ csr_src, int* __restrict__ ecsr) {
    int i = blockIdx.x * blockDim.x + threadIdx.x;
    if (i < NE) {
        int d = dst[i];
        int pos = atomicAdd(&cursor[d], 1);
        csr_src[rowstart[d] + pos] = src[i];
    } else {
        int p = i - NE;
        if (p < NN * KE) {
            int v = ego_flat[p];
            int pos = atomicAdd(&ecursor[v], 1);
            ecsr[erowstart[v] + pos] = p;  // p encodes (n,i); Y row index == p
        }
    }
}

// ---------------- A2[n] = A[n] @ A[n] (16x16, fp32) ----------------
__global__ __launch_bounds__(256) void a2_kernel(const float* __restrict__ ego_adj,
                                                 float* __restrict__ A2) {
    const int n = blockIdx.x, t = threadIdx.x;
    __shared__ float A[256];
    A[t] = ego_adj[(size_t)n * 256 + t];
    __syncthreads();
    const int i = t >> 4, k = t & 15;
    float s = 0.f;
#pragma unroll
    for (int j = 0; j < KE; ++j) s += A[i * KE + j] * A[j * KE + k];
    A2[(size_t)n * 256 + t] = s;
}

// ---------------- ego phase 1: Y[n] = A2[n] @ x[ids[n]]  -> bf16 ----------
template <typename T>
__global__ __launch_bounds__(128) void ego_apply_kernel(
    const T* __restrict__ x, const int* __restrict__ ego_ids,
    const float* __restrict__ A2, unsigned short* __restrict__ Y) {
    const int n = blockIdx.x, t = threadIdx.x;
    __shared__ float As[256];
    __shared__ int ids[KE];
    const float* a2 = A2 + (size_t)n * 256;
    As[t] = a2[t];
    As[t + 128] = a2[t + 128];
    if (t < KE) ids[t] = ego_ids[n * KE + t];
    __syncthreads();
    float xg[KE];
#pragma unroll
    for (int k = 0; k < KE; ++k) xg[k] = ldx(x, (size_t)ids[k] * FIN + t);
    unsigned short* yout = Y + ((size_t)n * KE) * FIN + t;
#pragma unroll
    for (int i = 0; i < KE; ++i) {
        float s = 0.f;
#pragma unroll
        for (int k = 0; k < KE; ++k) s += As[i * KE + k] * xg[k];
        yout[i * FIN] = f2bf(s);
    }
}

// ------- fused ego reduce + ndeg scale + linear(128x128) + bias (+relu) ------
// out_fp32[v,:] = relu?( (ndeg[v] * sum_{p in mem(v)} Y[p]) @ W + b )
template <bool RELU>
__global__ __launch_bounds__(128) void ego_reduce_linear_kernel(
    const unsigned short* __restrict__ Y, const int* __restrict__ erowstart,
    const int* __restrict__ ecsr, const float* __restrict__ ndeg,
    const float* __restrict__ W, const float* __restrict__ b,
    float* __restrict__ out) {
    constexpr int ROWS = 8;
    const int r0 = blockIdx.x * ROWS;
    const int t = threadIdx.x;
    __shared__ float rows[ROWS][FIN];
    for (int r = 0; r < ROWS; ++r) {
        const int v = r0 + r;
        float s = 0.f;
        int p = erowstart[v];
        const int pend = erowstart[v + 1];
        for (; p + 4 <= pend; p += 4) {
            int p0 = ecsr[p], p1 = ecsr[p + 1], p2 = ecsr[p + 2], p3 = ecsr[p + 3];
            s += bf2f(Y[(size_t)p0 * FIN + t]) + bf2f(Y[(size_t)p1 * FIN + t])
               + bf2f(Y[(size_t)p2 * FIN + t]) + bf2f(Y[(size_t)p3 * FIN + t]);
        }
        for (; p < pend; ++p) s += bf2f(Y[(size_t)ecsr[p] * FIN + t]);
        rows[r][t] = s * ndeg[v];
    }
    __syncthreads();
    float acc[ROWS] = {};
    for (int k = 0; k < FIN; ++k) {
        float w = W[k * FIN + t];
#pragma unroll
        for (int r = 0; r < ROWS; ++r) acc[r] += rows[r][k] * w;
    }
    const float bias = b[t];
#pragma unroll
    for (int r = 0; r < ROWS; ++r) {
        float v = acc[r] + bias;
        if (RELU) v = fmaxf(v, 0.f);
        out[(size_t)(r0 + r) * FIN + t] = v;
    }
}

// -------- message linear: msg[v,:] = bf16( (in[v,:] @ W) * dinv[v] ) ---------
template <int FO>
__global__ __launch_bounds__(FO) void linear_msg_kernel(
    const float* __restrict__ in, const float* __restrict__ W,
    const float* __restrict__ dinv, unsigned short* __restrict__ out) {
    constexpr int ROWS = 8;
    const int r0 = blockIdx.x * ROWS;
    const int j = threadIdx.x;
    __shared__ float rows[ROWS][FIN];
    for (int idx = j; idx < ROWS * FIN; idx += FO) {
        int r = idx >> 7, k = idx & 127;
        rows[r][k] = in[(size_t)(r0 + r) * FIN + k];
    }
    __syncthreads();
    float acc[ROWS] = {};
    for (int k = 0; k < FIN; ++k) {
        float w = W[k * FO + j];
#pragma unroll
        for (int r = 0; r < ROWS; ++r) acc[r] += rows[r][k] * w;
    }
#pragma unroll
    for (int r = 0; r < ROWS; ++r)
        out[(size_t)(r0 + r) * FO + j] = f2bf(acc[r] * dinv[r0 + r]);
}

// ------- GCN gather (F=128, bf16 msgs): h[d] = bf16((self+sum)*dinv[d]+b) ----
// 4 nodes per block, 64 lanes per node, 2 features per lane (ushort2 loads).
__global__ __launch_bounds__(256) void gcn_gather128_kernel(
    const unsigned short* __restrict__ msg, const int* __restrict__ rowstart,
    const int* __restrict__ csr_src, const float* __restrict__ dinv,
    const float* __restrict__ b, unsigned short* __restrict__ out) {
    const int tid = threadIdx.x;
    const int d = blockIdx.x * 4 + (tid >> 6);
    const int l = tid & 63;  // feature pair index
    const ushort2* m2 = (const ushort2*)msg;
    ushort2 v = m2[(size_t)d * 64 + l];  // self loop
    float sx = bf2f(v.x), sy = bf2f(v.y);
    int e = rowstart[d];
    const int eend = rowstart[d + 1];
    for (; e + 2 <= eend; e += 2) {
        int s0 = csr_src[e], s1 = csr_src[e + 1];
        ushort2 a = m2[(size_t)s0 * 64 + l];
        ushort2 c = m2[(size_t)s1 * 64 + l];
        sx += bf2f(a.x) + bf2f(c.x);
        sy += bf2f(a.y) + bf2f(c.y);
    }
    for (; e < eend; ++e) {
        ushort2 a = m2[(size_t)csr_src[e] * 64 + l];
        sx += bf2f(a.x); sy += bf2f(a.y);
    }
    const float di = dinv[d];
    const float2 bb = ((const float2*)b)[l];
    ushort2 o; o.x = f2bf(sx * di + bb.x); o.y = f2bf(sy * di + bb.y);
    ((ushort2*)out)[(size_t)d * 64 + l] = o;
}

// ------- fused GCN gather (F=64, bf16 msgs) + bias + log_softmax -> fp32 -----
__global__ __launch_bounds__(256) void gcn_gather_lsm_kernel(
    const unsigned short* __restrict__ msg, const int* __restrict__ rowstart,
    const int* __restrict__ csr_src, const float* __restrict__ dinv,
    const float* __restrict__ b, float* __restrict__ out) {
    const int tid = threadIdx.x;
    const int d = blockIdx.x * 4 + (tid >> 6);  // one 64-lane wave per node
    const int t = tid & 63;
    float s = bf2f(msg[(size_t)d * FOUT2 + t]);  // self loop
    int e = rowstart[d];
    const int eend = rowstart[d + 1];
    for (; e + 4 <= eend; e += 4) {
        int s0 = csr_src[e], s1 = csr_src[e + 1], s2 = csr_src[e + 2], s3 = csr_src[e + 3];
        s += bf2f(msg[(size_t)s0 * FOUT2 + t]) + bf2f(msg[(size_t)s1 * FOUT2 + t])
           + bf2f(msg[(size_t)s2 * FOUT2 + t]) + bf2f(msg[(size_t)s3 * FOUT2 + t]);
    }
    for (; e < eend; ++e) s += bf2f(msg[(size_t)csr_src[e] * FOUT2 + t]);
    const float xv = s * dinv[d] + b[t];
    float m = xv;
#pragma unroll
    for (int o = 32; o > 0; o >>= 1) m = fmaxf(m, __shfl_xor(m, o));
    float ex = __expf(xv - m);
    float sm = ex;
#pragma unroll
    for (int o = 32; o > 0; o >>= 1) sm += __shfl_xor(sm, o);
    out[(size_t)d * FOUT2 + t] = xv - m - __logf(sm);
}

extern "C" void kernel_launch(void* const* d_in, const int* in_sizes, int n_in,
                              void* d_out, int out_size, void* d_ws, size_t ws_size,
                              hipStream_t stream) {
    (void)in_sizes; (void)n_in; (void)out_size; (void)ws_size;
    const float* x      = (const float*)d_in[0];
    const int*   eidx   = (const int*)d_in[1];
    const int*   egoids = (const int*)d_in[2];
    const float* egoadj = (const float*)d_in[3];
    const float* ndeg   = (const float*)d_in[4];
    const float* W_ego1 = (const float*)d_in[5];
    const float* b_ego1 = (const float*)d_in[6];
    const float* W_gcn1 = (const float*)d_in[7];
    const float* b_gcn1 = (const float*)d_in[8];
    const float* W_ego2 = (const float*)d_in[9];
    const float* b_ego2 = (const float*)d_in[10];
    const float* W_gcn2 = (const float*)d_in[11];
    const float* b_gcn2 = (const float*)d_in[12];
    const int* src = eidx;
    const int* dst = eidx + NE;

    // ---- workspace layout (~130 MB; R4 proved ws >= ~230 MB) ----
    int* ip = (int*)d_ws;
    int* deg       = ip;                    // NN   -- deg/cursor/edeg/ecursor zeroed together
    int* cursor    = deg + NN;              // NN
    int* edeg      = cursor + NN;           // NN
    int* ecursor   = edeg + NN;             // NN
    int* rowstart  = ecursor + NN;          // NN+1
    int* erowstart = rowstart + NN + 8;     // NN+1
    int* csr_src   = erowstart + NN + 8;    // NE
    int* ecsr      = csr_src + NE;          // NN*KE
    float* dinv = (float*)(ecsr + NN * KE);             // NN
    float* A2   = dinv + NN;                            // NN*256 fp32
    float* fA   = A2 + (size_t)NN * 256;                // NN*128 fp32 (fused out)
    unsigned short* mA = (unsigned short*)(fA + (size_t)NN * FIN);  // NN*128 bf16 msgs L1
    unsigned short* hA = mA + (size_t)NN * FIN;          // NN*128 bf16 hidden
    unsigned short* m2 = hA + (size_t)NN * FIN;          // NN*64  bf16 msgs L2
    unsigned short* Y  = m2 + (size_t)NN * FOUT2;        // NN*KE*128 bf16

    // ---- CSR build ----
    (void)hipMemsetAsync(deg, 0, 4 * NN * sizeof(int), stream);
    const int tot = NE + NN * KE;
    hist2_kernel<<<(tot + 255) / 256, 256, 0, stream>>>(dst, egoids, deg, edeg);
    scan2_kernel<<<2, 256, 0, stream>>>(deg, edeg, rowstart, erowstart, dinv);
    bucket2_kernel<<<(tot + 255) / 256, 256, 0, stream>>>(src, dst, egoids, rowstart, erowstart,
                                                          cursor, ecursor, csr_src, ecsr);
    a2_kernel<<<NN, 256, 0, stream>>>(egoadj, A2);

    // ---- layer 1 ----
    ego_apply_kernel<float><<<NN, 128, 0, stream>>>(x, egoids, A2, Y);
    ego_reduce_linear_kernel<true><<<NN / 8, 128, 0, stream>>>(Y, erowstart, ecsr, ndeg, W_ego1, b_ego1, fA);
    linear_msg_kernel<128><<<NN / 8, 128, 0, stream>>>(fA, W_gcn1, dinv, mA);
    gcn_gather128_kernel<<<NN / 4, 256, 0, stream>>>(mA, rowstart, csr_src, dinv, b_gcn1, hA);

    // ---- layer 2 ----
    ego_apply_kernel<unsigned short><<<NN, 128, 0, stream>>>(hA, egoids, A2, Y);
    ego_reduce_linear_kernel<false><<<NN / 8, 128, 0, stream>>>(Y, erowstart, ecsr, ndeg, W_ego2, b_ego2, fA);
    linear_msg_kernel<64><<<NN / 8, 64, 0, stream>>>(fA, W_gcn2, dinv, m2);
    gcn_gather_lsm_kernel<<<NN / 4, 256, 0, stream>>>(m2, rowstart, csr_src, dinv, b_gcn2, (float*)d_out);
}

// Round 7
// 436.157 us; speedup vs baseline: 5.2033x; 1.1537x over previous
//
#include <hip/hip_runtime.h>
#include <hip/hip_bf16.h>

#define NN    20000   // nodes
#define KE    16      // ego-net size
#define FIN   128     // input feats / hidden
#define FOUT2 64      // output classes
#define NE    640000  // edges
#define NB    79      // scan blocks per array: ceil(NN/256)

// ---- bf16 helpers (ushort storage, fp32 math) ----
__device__ __forceinline__ float bf2f(unsigned short u) {
    union { float f; unsigned int i; } c; c.i = ((unsigned int)u) << 16; return c.f;
}
__device__ __forceinline__ unsigned short f2bf(float f) {
    union { float f; unsigned int i; } c; c.f = f;
    unsigned int lsb = (c.i >> 16) & 1u;
    c.i += 0x7fffu + lsb;           // round-to-nearest-even
    return (unsigned short)(c.i >> 16);
}
__device__ __forceinline__ float2 ldx2(const float* p, size_t i) {
    return *(const float2*)(p + i);
}
__device__ __forceinline__ float2 ldx2(const unsigned short* p, size_t i) {
    ushort2 u = *(const ushort2*)(p + i);
    float2 r; r.x = bf2f(u.x); r.y = bf2f(u.y); return r;
}

// ---------------- fused histograms: edge-dst degree + ego-membership ----------
__global__ void hist2_kernel(const int* __restrict__ dst, const int* __restrict__ ego_flat,
                             int* __restrict__ deg, int* __restrict__ edeg) {
    int i = blockIdx.x * blockDim.x + threadIdx.x;
    if (i < NE) {
        atomicAdd(&deg[dst[i]], 1);
    } else {
        int p = i - NE;
        if (p < NN * KE) atomicAdd(&edeg[ego_flat[p]], 1);
    }
}

// ---------------- 3-phase exclusive scan over deg and edeg -------------------
// phase 1: per-256-chunk LDS scan; write within-block exclusive prefix + block sums
__global__ __launch_bounds__(256) void scan_p1_kernel(
    const int* __restrict__ deg, const int* __restrict__ edeg,
    int* __restrict__ scantmp /*2*NN*/, int* __restrict__ bsums /*2*NB*/,
    float* __restrict__ dinv) {
    const int arr = (blockIdx.x >= NB) ? 1 : 0;
    const int blk = blockIdx.x - arr * NB;
    const int t = threadIdx.x;
    const int i = blk * 256 + t;
    const int* cnt = arr ? edeg : deg;
    int v = (i < NN) ? cnt[i] : 0;
    if (!arr && i < NN) dinv[i] = rsqrtf((float)(v + 1));  // +1 self loop
    __shared__ int sh[256];
    sh[t] = v;
    __syncthreads();
    for (int o = 1; o < 256; o <<= 1) {
        int u = (t >= o) ? sh[t - o] : 0;
        __syncthreads();
        sh[t] += u;
        __syncthreads();
    }
    if (i < NN) scantmp[arr * NN + i] = sh[t] - v;  // exclusive within block
    if (t == 255) bsums[arr * NB + blk] = sh[255];
}
// phase 2: single block scans the two NB-length block-sum arrays (exclusive, in place)
__global__ __launch_bounds__(256) void scan_p2_kernel(int* __restrict__ bsums) {
    const int t = threadIdx.x;
    __shared__ int sh[256];
    for (int a = 0; a < 2; ++a) {
        int v = (t < NB) ? bsums[a * NB + t] : 0;
        sh[t] = v;
        __syncthreads();
        for (int o = 1; o < 256; o <<= 1) {
            int u = (t >= o) ? sh[t - o] : 0;
            __syncthreads();
            sh[t] += u;
            __syncthreads();
        }
        if (t < NB) bsums[a * NB + t] = sh[t] - v;  // exclusive block offset
        __syncthreads();
    }
}
// phase 3: final offsets = within-block prefix + block offset; totals are constants
__global__ __launch_bounds__(256) void scan_p3_kernel(
    const int* __restrict__ scantmp, const int* __restrict__ bsums,
    int* __restrict__ rowstart, int* __restrict__ erowstart) {
    const int arr = (blockIdx.x >= NB) ? 1 : 0;
    const int blk = blockIdx.x - arr * NB;
    const int t = threadIdx.x;
    const int i = blk * 256 + t;
    if (i < NN) {
        int val = scantmp[arr * NN + i] + bsums[arr * NB + blk];
        if (arr) erowstart[i] = val; else rowstart[i] = val;
    }
    if (blockIdx.x == 0 && t == 0) { rowstart[NN] = NE; erowstart[NN] = NN * KE; }
}

// ---------------- fused bucketing into both CSRs ----------------
__global__ void bucket2_kernel(const int* __restrict__ src, const int* __restrict__ dst,
                               const int* __restrict__ ego_flat,
                               const int* __restrict__ rowstart, const int* __restrict__ erowstart,
                               int* __restrict__ cursor, int* __restrict__ ecursor,
                               int* __restrict__ csr_src, int* __restrict__ ecsr) {
    int i = blockIdx.x * blockDim.x + threadIdx.x;
    if (i < NE) {
        int d = dst[i];
        int pos = atomicAdd(&cursor[d], 1);
        csr_src[rowstart[d] + pos] = src[i];
    } else {
        int p = i - NE;
        if (p < NN * KE) {
            int v = ego_flat[p];
            int pos = atomicAdd(&ecursor[v], 1);
            ecsr[erowstart[v] + pos] = p;  // p encodes (n,i); Y row index == p
        }
    }
}

// ---------------- A2[n] = A[n] @ A[n] (16x16, fp32) ----------------
__global__ __launch_bounds__(256) void a2_kernel(const float* __restrict__ ego_adj,
                                                 float* __restrict__ A2) {
    const int n = blockIdx.x, t = threadIdx.x;
    __shared__ float A[256];
    A[t] = ego_adj[(size_t)n * 256 + t];
    __syncthreads();
    const int i = t >> 4, k = t & 15;
    float s = 0.f;
#pragma unroll
    for (int j = 0; j < KE; ++j) s += A[i * KE + j] * A[j * KE + k];
    A2[(size_t)n * 256 + t] = s;
}

// ------- ego phase 1: Y[n] = A2[n] @ x[ids[n]] -> bf16; 2 nets per block -----
// wave w handles net n = blockIdx*2+w; lane l handles feature pair 2l..2l+1.
template <typename T>
__global__ __launch_bounds__(128) void ego_apply_kernel(
    const T* __restrict__ x, const int* __restrict__ ego_ids,
    const float* __restrict__ A2, unsigned short* __restrict__ Y) {
    const int w = threadIdx.x >> 6;
    const int l = threadIdx.x & 63;
    const int n = blockIdx.x * 2 + w;
    __shared__ float As[2][256];
    __shared__ int ids[2][KE];
    const float* a2 = A2 + (size_t)n * 256;
    As[w][l]       = a2[l];
    As[w][l + 64]  = a2[l + 64];
    As[w][l + 128] = a2[l + 128];
    As[w][l + 192] = a2[l + 192];
    if (l < KE) ids[w][l] = ego_ids[n * KE + l];
    __syncthreads();
    float2 xg[KE];
#pragma unroll
    for (int k = 0; k < KE; ++k) xg[k] = ldx2(x, (size_t)ids[w][k] * FIN + 2 * l);
    unsigned short* yout = Y + (size_t)n * KE * FIN + 2 * l;
#pragma unroll
    for (int i = 0; i < KE; ++i) {
        float sx = 0.f, sy = 0.f;
#pragma unroll
        for (int k = 0; k < KE; ++k) {
            float a = As[w][i * KE + k];
            sx += a * xg[k].x;
            sy += a * xg[k].y;
        }
        ushort2 o; o.x = f2bf(sx); o.y = f2bf(sy);
        *(ushort2*)(yout + i * FIN) = o;
    }
}

// ------- fused ego reduce + ndeg scale + linear(128x128) + bias (+relu) ------
template <bool RELU>
__global__ __launch_bounds__(128) void ego_reduce_linear_kernel(
    const unsigned short* __restrict__ Y, const int* __restrict__ erowstart,
    const int* __restrict__ ecsr, const float* __restrict__ ndeg,
    const float* __restrict__ W, const float* __restrict__ b,
    float* __restrict__ out) {
    constexpr int ROWS = 8;
    const int r0 = blockIdx.x * ROWS;
    const int t = threadIdx.x;
    __shared__ float rows[ROWS][FIN];
    {
        const int half = t >> 6;     // 0/1: which row of the pair
        const int l = t & 63;        // feature pair index
        for (int rr = 0; rr < ROWS; rr += 2) {
            const int r = rr + half;
            const int v = r0 + r;
            float sx = 0.f, sy = 0.f;
            int p = erowstart[v];
            const int pend = erowstart[v + 1];
            for (; p + 4 <= pend; p += 4) {
                int p0 = ecsr[p], p1 = ecsr[p + 1], p2 = ecsr[p + 2], p3 = ecsr[p + 3];
                float2 a = ldx2(Y, (size_t)p0 * FIN + 2 * l);
                float2 c = ldx2(Y, (size_t)p1 * FIN + 2 * l);
                float2 d = ldx2(Y, (size_t)p2 * FIN + 2 * l);
                float2 e = ldx2(Y, (size_t)p3 * FIN + 2 * l);
                sx += a.x + c.x + d.x + e.x;
                sy += a.y + c.y + d.y + e.y;
            }
            for (; p < pend; ++p) {
                float2 a = ldx2(Y, (size_t)ecsr[p] * FIN + 2 * l);
                sx += a.x; sy += a.y;
            }
            const float nd = ndeg[v];
            float2 o; o.x = sx * nd; o.y = sy * nd;
            *(float2*)&rows[r][2 * l] = o;
        }
    }
    __syncthreads();
    float acc[ROWS] = {};
    for (int k = 0; k < FIN; ++k) {
        float w = W[k * FIN + t];
#pragma unroll
        for (int r = 0; r < ROWS; ++r) acc[r] += rows[r][k] * w;
    }
    const float bias = b[t];
#pragma unroll
    for (int r = 0; r < ROWS; ++r) {
        float v = acc[r] + bias;
        if (RELU) v = fmaxf(v, 0.f);
        out[(size_t)(r0 + r) * FIN + t] = v;
    }
}

// -------- message linear: msg[v,:] = bf16( (in[v,:] @ W) * dinv[v] ) ---------
template <int FO>
__global__ __launch_bounds__(FO) void linear_msg_kernel(
    const float* __restrict__ in, const float* __restrict__ W,
    const float* __restrict__ dinv, unsigned short* __restrict__ out) {
    constexpr int ROWS = 8;
    const int r0 = blockIdx.x * ROWS;
    const int j = threadIdx.x;
    __shared__ float rows[ROWS][FIN];
    for (int idx = j; idx < ROWS * FIN; idx += FO) {
        int r = idx >> 7, k = idx & 127;
        rows[r][k] = in[(size_t)(r0 + r) * FIN + k];
    }
    __syncthreads();
    float acc[ROWS] = {};
    for (int k = 0; k < FIN; ++k) {
        float w = W[k * FO + j];
#pragma unroll
        for (int r = 0; r < ROWS; ++r) acc[r] += rows[r][k] * w;
    }
#pragma unroll
    for (int r = 0; r < ROWS; ++r)
        out[(size_t)(r0 + r) * FO + j] = f2bf(acc[r] * dinv[r0 + r]);
}

// ------- GCN gather (F=128, bf16 msgs): h[d] = bf16((self+sum)*dinv[d]+b) ----
__global__ __launch_bounds__(256) void gcn_gather128_kernel(
    const unsigned short* __restrict__ msg, const int* __restrict__ rowstart,
    const int* __restrict__ csr_src, const float* __restrict__ dinv,
    const float* __restrict__ b, unsigned short* __restrict__ out) {
    const int tid = threadIdx.x;
    const int d = blockIdx.x * 4 + (tid >> 6);
    const int l = tid & 63;  // feature pair index
    const ushort2* m2 = (const ushort2*)msg;
    ushort2 v = m2[(size_t)d * 64 + l];  // self loop
    float sx = bf2f(v.x), sy = bf2f(v.y);
    int e = rowstart[d];
    const int eend = rowstart[d + 1];
    for (; e + 2 <= eend; e += 2) {
        int s0 = csr_src[e], s1 = csr_src[e + 1];
        ushort2 a = m2[(size_t)s0 * 64 + l];
        ushort2 c = m2[(size_t)s1 * 64 + l];
        sx += bf2f(a.x) + bf2f(c.x);
        sy += bf2f(a.y) + bf2f(c.y);
    }
    for (; e < eend; ++e) {
        ushort2 a = m2[(size_t)csr_src[e] * 64 + l];
        sx += bf2f(a.x); sy += bf2f(a.y);
    }
    const float di = dinv[d];
    const float2 bb = ((const float2*)b)[l];
    ushort2 o; o.x = f2bf(sx * di + bb.x); o.y = f2bf(sy * di + bb.y);
    ((ushort2*)out)[(size_t)d * 64 + l] = o;
}

// ------- fused GCN gather (F=64, bf16 msgs) + bias + log_softmax -> fp32 -----
__global__ __launch_bounds__(256) void gcn_gather_lsm_kernel(
    const unsigned short* __restrict__ msg, const int* __restrict__ rowstart,
    const int* __restrict__ csr_src, const float* __restrict__ dinv,
    const float* __restrict__ b, float* __restrict__ out) {
    const int tid = threadIdx.x;
    const int d = blockIdx.x * 4 + (tid >> 6);  // one 64-lane wave per node
    const int t = tid & 63;
    float s = bf2f(msg[(size_t)d * FOUT2 + t]);  // self loop
    int e = rowstart[d];
    const int eend = rowstart[d + 1];
    for (; e + 4 <= eend; e += 4) {
        int s0 = csr_src[e], s1 = csr_src[e + 1], s2 = csr_src[e + 2], s3 = csr_src[e + 3];
        s += bf2f(msg[(size_t)s0 * FOUT2 + t]) + bf2f(msg[(size_t)s1 * FOUT2 + t])
           + bf2f(msg[(size_t)s2 * FOUT2 + t]) + bf2f(msg[(size_t)s3 * FOUT2 + t]);
    }
    for (; e < eend; ++e) s += bf2f(msg[(size_t)csr_src[e] * FOUT2 + t]);
    const float xv = s * dinv[d] + b[t];
    float m = xv;
#pragma unroll
    for (int o = 32; o > 0; o >>= 1) m = fmaxf(m, __shfl_xor(m, o));
    float ex = __expf(xv - m);
    float sm = ex;
#pragma unroll
    for (int o = 32; o > 0; o >>= 1) sm += __shfl_xor(sm, o);
    out[(size_t)d * FOUT2 + t] = xv - m - __logf(sm);
}

extern "C" void kernel_launch(void* const* d_in, const int* in_sizes, int n_in,
                              void* d_out, int out_size, void* d_ws, size_t ws_size,
                              hipStream_t stream) {
    (void)in_sizes; (void)n_in; (void)out_size; (void)ws_size;
    const float* x      = (const float*)d_in[0];
    const int*   eidx   = (const int*)d_in[1];
    const int*   egoids = (const int*)d_in[2];
    const float* egoadj = (const float*)d_in[3];
    const float* ndeg   = (const float*)d_in[4];
    const float* W_ego1 = (const float*)d_in[5];
    const float* b_ego1 = (const float*)d_in[6];
    const float* W_gcn1 = (const float*)d_in[7];
    const float* b_gcn1 = (const float*)d_in[8];
    const float* W_ego2 = (const float*)d_in[9];
    const float* b_ego2 = (const float*)d_in[10];
    const float* W_gcn2 = (const float*)d_in[11];
    const float* b_gcn2 = (const float*)d_in[12];
    const int* src = eidx;
    const int* dst = eidx + NE;

    // ---- workspace layout (~131 MB; R4 proved ws >= ~230 MB) ----
    int* ip = (int*)d_ws;
    int* deg       = ip;                    // NN   -- deg/cursor/edeg/ecursor zeroed together
    int* cursor    = deg + NN;              // NN
    int* edeg      = cursor + NN;           // NN
    int* ecursor   = edeg + NN;             // NN
    int* rowstart  = ecursor + NN;          // NN+1
    int* erowstart = rowstart + NN + 8;     // NN+1
    int* csr_src   = erowstart + NN + 8;    // NE
    int* ecsr      = csr_src + NE;          // NN*KE
    int* scantmp   = ecsr + NN * KE;        // 2*NN
    int* bsums     = scantmp + 2 * NN;      // 2*NB (+pad)
    float* dinv = (float*)(bsums + 256);                // NN
    float* A2   = dinv + NN;                            // NN*256 fp32
    float* fA   = A2 + (size_t)NN * 256;                // NN*128 fp32 (fused out)
    unsigned short* mA = (unsigned short*)(fA + (size_t)NN * FIN);  // NN*128 bf16 msgs L1
    unsigned short* hA = mA + (size_t)NN * FIN;          // NN*128 bf16 hidden
    unsigned short* m2 = hA + (size_t)NN * FIN;          // NN*64  bf16 msgs L2
    unsigned short* Y  = m2 + (size_t)NN * FOUT2;        // NN*KE*128 bf16

    // ---- CSR build ----
    (void)hipMemsetAsync(deg, 0, 4 * NN * sizeof(int), stream);
    const int tot = NE + NN * KE;
    hist2_kernel<<<(tot + 255) / 256, 256, 0, stream>>>(dst, egoids, deg, edeg);
    scan_p1_kernel<<<2 * NB, 256, 0, stream>>>(deg, edeg, scantmp, bsums, dinv);
    scan_p2_kernel<<<1, 256, 0, stream>>>(bsums);
    scan_p3_kernel<<<2 * NB, 256, 0, stream>>>(scantmp, bsums, rowstart, erowstart);
    bucket2_kernel<<<(tot + 255) / 256, 256, 0, stream>>>(src, dst, egoids, rowstart, erowstart,
                                                          cursor, ecursor, csr_src, ecsr);
    a2_kernel<<<NN, 256, 0, stream>>>(egoadj, A2);

    // ---- layer 1 ----
    ego_apply_kernel<float><<<NN / 2, 128, 0, stream>>>(x, egoids, A2, Y);
    ego_reduce_linear_kernel<true><<<NN / 8, 128, 0, stream>>>(Y, erowstart, ecsr, ndeg, W_ego1, b_ego1, fA);
    linear_msg_kernel<128><<<NN / 8, 128, 0, stream>>>(fA, W_gcn1, dinv, mA);
    gcn_gather128_kernel<<<NN / 4, 256, 0, stream>>>(mA, rowstart, csr_src, dinv, b_gcn1, hA);

    // ---- layer 2 ----
    ego_apply_kernel<unsigned short><<<NN / 2, 128, 0, stream>>>(hA, egoids, A2, Y);
    ego_reduce_linear_kernel<false><<<NN / 8, 128, 0, stream>>>(Y, erowstart, ecsr, ndeg, W_ego2, b_ego2, fA);
    linear_msg_kernel<64><<<NN / 8, 64, 0, stream>>>(fA, W_gcn2, dinv, m2);
    gcn_gather_lsm_kernel<<<NN / 4, 256, 0, stream>>>(m2, rowstart, csr_src, dinv, b_gcn2, (float*)d_out);
}

// Round 8
// 394.437 us; speedup vs baseline: 5.7537x; 1.1058x over previous
//
#include <hip/hip_runtime.h>
#include <hip/hip_bf16.h>

#define NN    20000   // nodes
#define KE    16      // ego-net size
#define FIN   128     // input feats / hidden
#define FOUT2 64      // output classes
#define NE    640000  // edges
#define NB    79      // scan blocks per array: ceil(NN/256)
#define TOT   (NE + NN * KE)   // 960000 items in unified hist/bucket index space

// ---- bf16 helpers (ushort storage, fp32 math) ----
__device__ __forceinline__ float bf2f(unsigned short u) {
    union { float f; unsigned int i; } c; c.i = ((unsigned int)u) << 16; return c.f;
}
__device__ __forceinline__ unsigned short f2bf(float f) {
    union { float f; unsigned int i; } c; c.f = f;
    unsigned int lsb = (c.i >> 16) & 1u;
    c.i += 0x7fffu + lsb;           // round-to-nearest-even
    return (unsigned short)(c.i >> 16);
}
__device__ __forceinline__ float2 ldx2(const float* p, size_t i) {
    return *(const float2*)(p + i);
}
__device__ __forceinline__ float2 ldx2(const unsigned short* p, size_t i) {
    ushort2 u = *(const ushort2*)(p + i);
    float2 r; r.x = bf2f(u.x); r.y = bf2f(u.y); return r;
}

// ---- hist + position capture: pos[i] = rank of item i within its key -------
// 4 items per thread (independent atomics pipeline the latency).
__global__ void hist2_kernel(const int* __restrict__ dst, const int* __restrict__ ego_flat,
                             int* __restrict__ deg, int* __restrict__ edeg,
                             int* __restrict__ posarr) {
    const int base = (blockIdx.x * blockDim.x + threadIdx.x) * 4;
#pragma unroll
    for (int q = 0; q < 4; ++q) {
        const int i = base + q;
        if (i >= TOT) return;
        if (i < NE) posarr[i] = atomicAdd(&deg[dst[i]], 1);
        else        posarr[i] = atomicAdd(&edeg[ego_flat[i - NE]], 1);
    }
}

// ---------------- 3-phase exclusive scan over deg and edeg -------------------
__global__ __launch_bounds__(256) void scan_p1_kernel(
    const int* __restrict__ deg, const int* __restrict__ edeg,
    int* __restrict__ scantmp /*2*NN*/, int* __restrict__ bsums /*2*NB*/,
    float* __restrict__ dinv) {
    const int arr = (blockIdx.x >= NB) ? 1 : 0;
    const int blk = blockIdx.x - arr * NB;
    const int t = threadIdx.x;
    const int i = blk * 256 + t;
    const int* cnt = arr ? edeg : deg;
    int v = (i < NN) ? cnt[i] : 0;
    if (!arr && i < NN) dinv[i] = rsqrtf((float)(v + 1));  // +1 self loop
    __shared__ int sh[256];
    sh[t] = v;
    __syncthreads();
    for (int o = 1; o < 256; o <<= 1) {
        int u = (t >= o) ? sh[t - o] : 0;
        __syncthreads();
        sh[t] += u;
        __syncthreads();
    }
    if (i < NN) scantmp[arr * NN + i] = sh[t] - v;  // exclusive within block
    if (t == 255) bsums[arr * NB + blk] = sh[255];
}
__global__ __launch_bounds__(256) void scan_p2_kernel(int* __restrict__ bsums) {
    const int t = threadIdx.x;
    __shared__ int sh[256];
    for (int a = 0; a < 2; ++a) {
        int v = (t < NB) ? bsums[a * NB + t] : 0;
        sh[t] = v;
        __syncthreads();
        for (int o = 1; o < 256; o <<= 1) {
            int u = (t >= o) ? sh[t - o] : 0;
            __syncthreads();
            sh[t] += u;
            __syncthreads();
        }
        if (t < NB) bsums[a * NB + t] = sh[t] - v;  // exclusive block offset
        __syncthreads();
    }
}
__global__ __launch_bounds__(256) void scan_p3_kernel(
    const int* __restrict__ scantmp, const int* __restrict__ bsums,
    int* __restrict__ rowstart, int* __restrict__ erowstart) {
    const int arr = (blockIdx.x >= NB) ? 1 : 0;
    const int blk = blockIdx.x - arr * NB;
    const int t = threadIdx.x;
    const int i = blk * 256 + t;
    if (i < NN) {
        int val = scantmp[arr * NN + i] + bsums[arr * NB + blk];
        if (arr) erowstart[i] = val; else rowstart[i] = val;
    }
    if (blockIdx.x == 0 && t == 0) { rowstart[NN] = NE; erowstart[NN] = NN * KE; }
}

// ---- bucket pass: pure scatter, no atomics (positions precomputed) ---------
__global__ void bucket2_kernel(const int* __restrict__ src, const int* __restrict__ dst,
                               const int* __restrict__ ego_flat,
                               const int* __restrict__ rowstart, const int* __restrict__ erowstart,
                               const int* __restrict__ posarr,
                               int* __restrict__ csr_src, int* __restrict__ ecsr) {
    const int base = (blockIdx.x * blockDim.x + threadIdx.x) * 4;
#pragma unroll
    for (int q = 0; q < 4; ++q) {
        const int i = base + q;
        if (i >= TOT) return;
        if (i < NE) {
            int d = dst[i];
            csr_src[rowstart[d] + posarr[i]] = src[i];
        } else {
            int p = i - NE;
            int v = ego_flat[p];
            ecsr[erowstart[v] + posarr[i]] = p;  // p encodes (n,i); Y row index == p
        }
    }
}

// ------- ego phase 1: Y[n] = (A@A) @ x[ids[n]] -> bf16; 2 nets per block -----
// A2 computed in LDS from ego_adj (saves the a2 dispatch + 40 MB round trip).
template <typename T>
__global__ __launch_bounds__(128) void ego_apply_kernel(
    const T* __restrict__ x, const int* __restrict__ ego_ids,
    const float* __restrict__ ego_adj, unsigned short* __restrict__ Y) {
    const int w = threadIdx.x >> 6;
    const int l = threadIdx.x & 63;
    const int n = blockIdx.x * 2 + w;
    __shared__ float Ar[2][256];
    __shared__ float As[2][256];
    __shared__ int ids[2][KE];
    const float* a = ego_adj + (size_t)n * 256;
    Ar[w][l]       = a[l];
    Ar[w][l + 64]  = a[l + 64];
    Ar[w][l + 128] = a[l + 128];
    Ar[w][l + 192] = a[l + 192];
    if (l < KE) ids[w][l] = ego_ids[n * KE + l];
    __syncthreads();
#pragma unroll
    for (int q = 0; q < 4; ++q) {
        const int m = l * 4 + q;           // entry of A2
        const int i = m >> 4, k = m & 15;
        float s = 0.f;
#pragma unroll
        for (int j = 0; j < KE; ++j) s += Ar[w][i * KE + j] * Ar[w][j * KE + k];
        As[w][m] = s;
    }
    __syncthreads();
    float2 xg[KE];
#pragma unroll
    for (int k = 0; k < KE; ++k) xg[k] = ldx2(x, (size_t)ids[w][k] * FIN + 2 * l);
    unsigned short* yout = Y + (size_t)n * KE * FIN + 2 * l;
#pragma unroll
    for (int i = 0; i < KE; ++i) {
        float sx = 0.f, sy = 0.f;
#pragma unroll
        for (int k = 0; k < KE; ++k) {
            float a2 = As[w][i * KE + k];
            sx += a2 * xg[k].x;
            sy += a2 * xg[k].y;
        }
        ushort2 o; o.x = f2bf(sx); o.y = f2bf(sy);
        *(ushort2*)(yout + i * FIN) = o;
    }
}

// ------- fused ego reduce + ndeg scale + linear(128x128) + bias (+relu) ------
template <bool RELU>
__global__ __launch_bounds__(128) void ego_reduce_linear_kernel(
    const unsigned short* __restrict__ Y, const int* __restrict__ erowstart,
    const int* __restrict__ ecsr, const float* __restrict__ ndeg,
    const float* __restrict__ W, const float* __restrict__ b,
    float* __restrict__ out) {
    constexpr int ROWS = 8;
    const int r0 = blockIdx.x * ROWS;
    const int t = threadIdx.x;
    __shared__ float rows[ROWS][FIN];
    {
        const int half = t >> 6;     // 0/1: which row of the pair
        const int l = t & 63;        // feature pair index
        for (int rr = 0; rr < ROWS; rr += 2) {
            const int r = rr + half;
            const int v = r0 + r;
            float sx = 0.f, sy = 0.f;
            int p = erowstart[v];
            const int pend = erowstart[v + 1];
            for (; p + 4 <= pend; p += 4) {
                int p0 = ecsr[p], p1 = ecsr[p + 1], p2 = ecsr[p + 2], p3 = ecsr[p + 3];
                float2 a = ldx2(Y, (size_t)p0 * FIN + 2 * l);
                float2 c = ldx2(Y, (size_t)p1 * FIN + 2 * l);
                float2 d = ldx2(Y, (size_t)p2 * FIN + 2 * l);
                float2 e = ldx2(Y, (size_t)p3 * FIN + 2 * l);
                sx += a.x + c.x + d.x + e.x;
                sy += a.y + c.y + d.y + e.y;
            }
            for (; p < pend; ++p) {
                float2 a = ldx2(Y, (size_t)ecsr[p] * FIN + 2 * l);
                sx += a.x; sy += a.y;
            }
            const float nd = ndeg[v];
            float2 o; o.x = sx * nd; o.y = sy * nd;
            *(float2*)&rows[r][2 * l] = o;
        }
    }
    __syncthreads();
    float acc[ROWS] = {};
    for (int k = 0; k < FIN; ++k) {
        float w = W[k * FIN + t];
#pragma unroll
        for (int r = 0; r < ROWS; ++r) acc[r] += rows[r][k] * w;
    }
    const float bias = b[t];
#pragma unroll
    for (int r = 0; r < ROWS; ++r) {
        float v = acc[r] + bias;
        if (RELU) v = fmaxf(v, 0.f);
        out[(size_t)(r0 + r) * FIN + t] = v;
    }
}

// -------- message linear: msg[v,:] = bf16( (in[v,:] @ W) * dinv[v] ) ---------
template <int FO>
__global__ __launch_bounds__(FO) void linear_msg_kernel(
    const float* __restrict__ in, const float* __restrict__ W,
    const float* __restrict__ dinv, unsigned short* __restrict__ out) {
    constexpr int ROWS = 8;
    const int r0 = blockIdx.x * ROWS;
    const int j = threadIdx.x;
    __shared__ float rows[ROWS][FIN];
    for (int idx = j; idx < ROWS * FIN; idx += FO) {
        int r = idx >> 7, k = idx & 127;
        rows[r][k] = in[(size_t)(r0 + r) * FIN + k];
    }
    __syncthreads();
    float acc[ROWS] = {};
    for (int k = 0; k < FIN; ++k) {
        float w = W[k * FO + j];
#pragma unroll
        for (int r = 0; r < ROWS; ++r) acc[r] += rows[r][k] * w;
    }
#pragma unroll
    for (int r = 0; r < ROWS; ++r)
        out[(size_t)(r0 + r) * FO + j] = f2bf(acc[r] * dinv[r0 + r]);
}

// ------- GCN gather (F=128, bf16 msgs): h[d] = bf16((self+sum)*dinv[d]+b) ----
__global__ __launch_bounds__(256) void gcn_gather128_kernel(
    const unsigned short* __restrict__ msg, const int* __restrict__ rowstart,
    const int* __restrict__ csr_src, const float* __restrict__ dinv,
    const float* __restrict__ b, unsigned short* __restrict__ out) {
    const int tid = threadIdx.x;
    const int d = blockIdx.x * 4 + (tid >> 6);
    const int l = tid & 63;  // feature pair index
    const ushort2* m2 = (const ushort2*)msg;
    ushort2 v = m2[(size_t)d * 64 + l];  // self loop
    float sx = bf2f(v.x), sy = bf2f(v.y);
    int e = rowstart[d];
    const int eend = rowstart[d + 1];
    for (; e + 2 <= eend; e += 2) {
        int s0 = csr_src[e], s1 = csr_src[e + 1];
        ushort2 a = m2[(size_t)s0 * 64 + l];
        ushort2 c = m2[(size_t)s1 * 64 + l];
        sx += bf2f(a.x) + bf2f(c.x);
        sy += bf2f(a.y) + bf2f(c.y);
    }
    for (; e < eend; ++e) {
        ushort2 a = m2[(size_t)csr_src[e] * 64 + l];
        sx += bf2f(a.x); sy += bf2f(a.y);
    }
    const float di = dinv[d];
    const float2 bb = ((const float2*)b)[l];
    ushort2 o; o.x = f2bf(sx * di + bb.x); o.y = f2bf(sy * di + bb.y);
    ((ushort2*)out)[(size_t)d * 64 + l] = o;
}

// ------- fused GCN gather (F=64, bf16 msgs) + bias + log_softmax -> fp32 -----
__global__ __launch_bounds__(256) void gcn_gather_lsm_kernel(
    const unsigned short* __restrict__ msg, const int* __restrict__ rowstart,
    const int* __restrict__ csr_src, const float* __restrict__ dinv,
    const float* __restrict__ b, float* __restrict__ out) {
    const int tid = threadIdx.x;
    const int d = blockIdx.x * 4 + (tid >> 6);  // one 64-lane wave per node
    const int t = tid & 63;
    float s = bf2f(msg[(size_t)d * FOUT2 + t]);  // self loop
    int e = rowstart[d];
    const int eend = rowstart[d + 1];
    for (; e + 4 <= eend; e += 4) {
        int s0 = csr_src[e], s1 = csr_src[e + 1], s2 = csr_src[e + 2], s3 = csr_src[e + 3];
        s += bf2f(msg[(size_t)s0 * FOUT2 + t]) + bf2f(msg[(size_t)s1 * FOUT2 + t])
           + bf2f(msg[(size_t)s2 * FOUT2 + t]) + bf2f(msg[(size_t)s3 * FOUT2 + t]);
    }
    for (; e < eend; ++e) s += bf2f(msg[(size_t)csr_src[e] * FOUT2 + t]);
    const float xv = s * dinv[d] + b[t];
    float m = xv;
#pragma unroll
    for (int o = 32; o > 0; o >>= 1) m = fmaxf(m, __shfl_xor(m, o));
    float ex = __expf(xv - m);
    float sm = ex;
#pragma unroll
    for (int o = 32; o > 0; o >>= 1) sm += __shfl_xor(sm, o);
    out[(size_t)d * FOUT2 + t] = xv - m - __logf(sm);
}

extern "C" void kernel_launch(void* const* d_in, const int* in_sizes, int n_in,
                              void* d_out, int out_size, void* d_ws, size_t ws_size,
                              hipStream_t stream) {
    (void)in_sizes; (void)n_in; (void)out_size; (void)ws_size;
    const float* x      = (const float*)d_in[0];
    const int*   eidx   = (const int*)d_in[1];
    const int*   egoids = (const int*)d_in[2];
    const float* egoadj = (const float*)d_in[3];
    const float* ndeg   = (const float*)d_in[4];
    const float* W_ego1 = (const float*)d_in[5];
    const float* b_ego1 = (const float*)d_in[6];
    const float* W_gcn1 = (const float*)d_in[7];
    const float* b_gcn1 = (const float*)d_in[8];
    const float* W_ego2 = (const float*)d_in[9];
    const float* b_ego2 = (const float*)d_in[10];
    const float* W_gcn2 = (const float*)d_in[11];
    const float* b_gcn2 = (const float*)d_in[12];
    const int* src = eidx;
    const int* dst = eidx + NE;

    // ---- workspace layout (~115 MB) ----
    int* ip = (int*)d_ws;
    int* deg       = ip;                    // NN  (zeroed)
    int* edeg      = deg + NN;              // NN  (zeroed)
    int* rowstart  = edeg + NN;             // NN+1
    int* erowstart = rowstart + NN + 8;     // NN+1
    int* csr_src   = erowstart + NN + 8;    // NE
    int* ecsr      = csr_src + NE;          // NN*KE
    int* scantmp   = ecsr + NN * KE;        // 2*NN
    int* bsums     = scantmp + 2 * NN;      // 2*NB (+pad)
    int* posarr    = bsums + 256;           // TOT
    float* dinv = (float*)(posarr + TOT);               // NN
    float* fA   = dinv + NN;                            // NN*128 fp32 (fused out)
    unsigned short* mA = (unsigned short*)(fA + (size_t)NN * FIN);  // NN*128 bf16 msgs L1
    unsigned short* hA = mA + (size_t)NN * FIN;          // NN*128 bf16 hidden
    unsigned short* m2 = hA + (size_t)NN * FIN;          // NN*64  bf16 msgs L2
    unsigned short* Y  = m2 + (size_t)NN * FOUT2;        // NN*KE*128 bf16

    // ---- CSR build ----
    (void)hipMemsetAsync(deg, 0, 2 * NN * sizeof(int), stream);
    hist2_kernel<<<(TOT / 4 + 255) / 256, 256, 0, stream>>>(dst, egoids, deg, edeg, posarr);
    scan_p1_kernel<<<2 * NB, 256, 0, stream>>>(deg, edeg, scantmp, bsums, dinv);
    scan_p2_kernel<<<1, 256, 0, stream>>>(bsums);
    scan_p3_kernel<<<2 * NB, 256, 0, stream>>>(scantmp, bsums, rowstart, erowstart);
    bucket2_kernel<<<(TOT / 4 + 255) / 256, 256, 0, stream>>>(src, dst, egoids, rowstart,
                                                              erowstart, posarr, csr_src, ecsr);

    // ---- layer 1 ----
    ego_apply_kernel<float><<<NN / 2, 128, 0, stream>>>(x, egoids, egoadj, Y);
    ego_reduce_linear_kernel<true><<<NN / 8, 128, 0, stream>>>(Y, erowstart, ecsr, ndeg, W_ego1, b_ego1, fA);
    linear_msg_kernel<128><<<NN / 8, 128, 0, stream>>>(fA, W_gcn1, dinv, mA);
    gcn_gather128_kernel<<<NN / 4, 256, 0, stream>>>(mA, rowstart, csr_src, dinv, b_gcn1, hA);

    // ---- layer 2 ----
    ego_apply_kernel<unsigned short><<<NN / 2, 128, 0, stream>>>(hA, egoids, egoadj, Y);
    ego_reduce_linear_kernel<false><<<NN / 8, 128, 0, stream>>>(Y, erowstart, ecsr, ndeg, W_ego2, b_ego2, fA);
    linear_msg_kernel<64><<<NN / 8, 64, 0, stream>>>(fA, W_gcn2, dinv, m2);
    gcn_gather_lsm_kernel<<<NN / 4, 256, 0, stream>>>(m2, rowstart, csr_src, dinv, b_gcn2, (float*)d_out);
}

// Round 9
// 392.239 us; speedup vs baseline: 5.7859x; 1.0056x over previous
//
#include <hip/hip_runtime.h>
#include <hip/hip_bf16.h>

#define NN    20000   // nodes
#define KE    16      // ego-net size
#define FIN   128     // input feats / hidden
#define FOUT2 64      // output classes
#define NE    640000  // edges
#define NB    79      // scan blocks per array: ceil(NN/256)
#define TOT   (NE + NN * KE)        // 960000 items in unified hist/bucket space
#define HB    469                   // hist/bucket blocks: ceil(TOT/8/256)

// ---- bf16 helpers (ushort storage, fp32 math) ----
__device__ __forceinline__ float bf2f(unsigned short u) {
    union { float f; unsigned int i; } c; c.i = ((unsigned int)u) << 16; return c.f;
}
__device__ __forceinline__ unsigned short f2bf(float f) {
    union { float f; unsigned int i; } c; c.f = f;
    unsigned int lsb = (c.i >> 16) & 1u;
    c.i += 0x7fffu + lsb;           // round-to-nearest-even
    return (unsigned short)(c.i >> 16);
}
__device__ __forceinline__ float2 ldx2(const float* p, size_t i) {
    return *(const float2*)(p + i);
}
__device__ __forceinline__ float2 ldx2(const unsigned short* p, size_t i) {
    ushort2 u = *(const ushort2*)(p + i);
    float2 r; r.x = bf2f(u.x); r.y = bf2f(u.y); return r;
}

// ---- fused: ego_apply layer-1 (blocks [0,NN/4)) || hist+pos (blocks >= NN/4)
// apply: Y[n] = (A@A) @ x[ids[n]] -> bf16, 4 nets per 256-thr block.
// hist:  posarr[i] = rank of item i within its key (8 items/thread).
__global__ __launch_bounds__(256) void apply1_hist_kernel(
    const float* __restrict__ x, const int* __restrict__ ego_ids,
    const float* __restrict__ ego_adj, unsigned short* __restrict__ Y,
    const int* __restrict__ dst, int* __restrict__ deg, int* __restrict__ edeg,
    int* __restrict__ posarr) {
    __shared__ float Ar[4][256];
    __shared__ float As[4][256];
    __shared__ int ids[4][KE];
    if (blockIdx.x >= NN / 4) {     // ---- histogram part ----
        const int base = ((blockIdx.x - NN / 4) * 256 + threadIdx.x) * 8;
#pragma unroll
        for (int q = 0; q < 8; ++q) {
            const int i = base + q;
            if (i >= TOT) return;
            if (i < NE) posarr[i] = atomicAdd(&deg[dst[i]], 1);
            else        posarr[i] = atomicAdd(&edeg[ego_ids[i - NE]], 1);
        }
        return;
    }
    // ---- ego apply part ----
    const int w = threadIdx.x >> 6;
    const int l = threadIdx.x & 63;
    const int n = blockIdx.x * 4 + w;
    const float* a = ego_adj + (size_t)n * 256;
    Ar[w][l]       = a[l];
    Ar[w][l + 64]  = a[l + 64];
    Ar[w][l + 128] = a[l + 128];
    Ar[w][l + 192] = a[l + 192];
    if (l < KE) ids[w][l] = ego_ids[n * KE + l];
    __syncthreads();
#pragma unroll
    for (int q = 0; q < 4; ++q) {
        const int m = l * 4 + q;           // entry of A2 = A@A
        const int i = m >> 4, k = m & 15;
        float s = 0.f;
#pragma unroll
        for (int j = 0; j < KE; ++j) s += Ar[w][i * KE + j] * Ar[w][j * KE + k];
        As[w][m] = s;
    }
    __syncthreads();
    float2 xg[KE];
#pragma unroll
    for (int k = 0; k < KE; ++k) xg[k] = ldx2(x, (size_t)ids[w][k] * FIN + 2 * l);
    unsigned short* yout = Y + (size_t)n * KE * FIN + 2 * l;
#pragma unroll
    for (int i = 0; i < KE; ++i) {
        float sx = 0.f, sy = 0.f;
#pragma unroll
        for (int k = 0; k < KE; ++k) {
            float a2 = As[w][i * KE + k];
            sx += a2 * xg[k].x;
            sy += a2 * xg[k].y;
        }
        ushort2 o; o.x = f2bf(sx); o.y = f2bf(sy);
        *(ushort2*)(yout + i * FIN) = o;
    }
}

// ---- plain ego apply (layer 2, bf16 input), 4 nets per 256-thr block -------
__global__ __launch_bounds__(256) void ego_apply2_kernel(
    const unsigned short* __restrict__ x, const int* __restrict__ ego_ids,
    const float* __restrict__ ego_adj, unsigned short* __restrict__ Y) {
    const int w = threadIdx.x >> 6;
    const int l = threadIdx.x & 63;
    const int n = blockIdx.x * 4 + w;
    __shared__ float Ar[4][256];
    __shared__ float As[4][256];
    __shared__ int ids[4][KE];
    const float* a = ego_adj + (size_t)n * 256;
    Ar[w][l]       = a[l];
    Ar[w][l + 64]  = a[l + 64];
    Ar[w][l + 128] = a[l + 128];
    Ar[w][l + 192] = a[l + 192];
    if (l < KE) ids[w][l] = ego_ids[n * KE + l];
    __syncthreads();
#pragma unroll
    for (int q = 0; q < 4; ++q) {
        const int m = l * 4 + q;
        const int i = m >> 4, k = m & 15;
        float s = 0.f;
#pragma unroll
        for (int j = 0; j < KE; ++j) s += Ar[w][i * KE + j] * Ar[w][j * KE + k];
        As[w][m] = s;
    }
    __syncthreads();
    float2 xg[KE];
#pragma unroll
    for (int k = 0; k < KE; ++k) xg[k] = ldx2(x, (size_t)ids[w][k] * FIN + 2 * l);
    unsigned short* yout = Y + (size_t)n * KE * FIN + 2 * l;
#pragma unroll
    for (int i = 0; i < KE; ++i) {
        float sx = 0.f, sy = 0.f;
#pragma unroll
        for (int k = 0; k < KE; ++k) {
            float a2 = As[w][i * KE + k];
            sx += a2 * xg[k].x;
            sy += a2 * xg[k].y;
        }
        ushort2 o; o.x = f2bf(sx); o.y = f2bf(sy);
        *(ushort2*)(yout + i * FIN) = o;
    }
}

// ---------------- 3-phase exclusive scan over deg and edeg -------------------
__global__ __launch_bounds__(256) void scan_p1_kernel(
    const int* __restrict__ deg, const int* __restrict__ edeg,
    int* __restrict__ scantmp, int* __restrict__ bsums, float* __restrict__ dinv) {
    const int arr = (blockIdx.x >= NB) ? 1 : 0;
    const int blk = blockIdx.x - arr * NB;
    const int t = threadIdx.x;
    const int i = blk * 256 + t;
    const int* cnt = arr ? edeg : deg;
    int v = (i < NN) ? cnt[i] : 0;
    if (!arr && i < NN) dinv[i] = rsqrtf((float)(v + 1));  // +1 self loop
    __shared__ int sh[256];
    sh[t] = v;
    __syncthreads();
    for (int o = 1; o < 256; o <<= 1) {
        int u = (t >= o) ? sh[t - o] : 0;
        __syncthreads();
        sh[t] += u;
        __syncthreads();
    }
    if (i < NN) scantmp[arr * NN + i] = sh[t] - v;  // exclusive within block
    if (t == 255) bsums[arr * NB + blk] = sh[255];
}
__global__ __launch_bounds__(256) void scan_p2_kernel(int* __restrict__ bsums) {
    const int t = threadIdx.x;
    __shared__ int sh[256];
    for (int a = 0; a < 2; ++a) {
        int v = (t < NB) ? bsums[a * NB + t] : 0;
        sh[t] = v;
        __syncthreads();
        for (int o = 1; o < 256; o <<= 1) {
            int u = (t >= o) ? sh[t - o] : 0;
            __syncthreads();
            sh[t] += u;
            __syncthreads();
        }
        if (t < NB) bsums[a * NB + t] = sh[t] - v;
        __syncthreads();
    }
}
__global__ __launch_bounds__(256) void scan_p3_kernel(
    const int* __restrict__ scantmp, const int* __restrict__ bsums,
    int* __restrict__ rowstart, int* __restrict__ erowstart) {
    const int arr = (blockIdx.x >= NB) ? 1 : 0;
    const int blk = blockIdx.x - arr * NB;
    const int t = threadIdx.x;
    const int i = blk * 256 + t;
    if (i < NN) {
        int val = scantmp[arr * NN + i] + bsums[arr * NB + blk];
        if (arr) erowstart[i] = val; else rowstart[i] = val;
    }
    if (blockIdx.x == 0 && t == 0) { rowstart[NN] = NE; erowstart[NN] = NN * KE; }
}

// ---- bucket pass: pure scatter, no atomics (positions precomputed) ---------
__global__ void bucket2_kernel(const int* __restrict__ src, const int* __restrict__ dst,
                               const int* __restrict__ ego_flat,
                               const int* __restrict__ rowstart, const int* __restrict__ erowstart,
                               const int* __restrict__ posarr,
                               int* __restrict__ csr_src, int* __restrict__ ecsr) {
    const int base = (blockIdx.x * blockDim.x + threadIdx.x) * 8;
#pragma unroll
    for (int q = 0; q < 8; ++q) {
        const int i = base + q;
        if (i >= TOT) return;
        if (i < NE) {
            int d = dst[i];
            csr_src[rowstart[d] + posarr[i]] = src[i];
        } else {
            int p = i - NE;
            int v = ego_flat[p];
            ecsr[erowstart[v] + posarr[i]] = p;  // p encodes (n,i); Y row index == p
        }
    }
}

// ---- fused: ego reduce + ndeg scale + linear_ego(+relu) + linear_gcn*dinv ---
// msg[v,:] = bf16( (relu?( (ndeg[v]*sum Y) @ W1 + b1 )) @ W2 * dinv[v] )
template <int FO, bool RELU>
__global__ __launch_bounds__(256) void ego_dual_kernel(
    const unsigned short* __restrict__ Y, const int* __restrict__ erowstart,
    const int* __restrict__ ecsr, const float* __restrict__ ndeg,
    const float* __restrict__ W1, const float* __restrict__ b1,
    const float* __restrict__ W2, const float* __restrict__ dinv,
    unsigned short* __restrict__ msg) {
    constexpr int ROWS = 8;
    const int r0 = blockIdx.x * ROWS;
    const int t = threadIdx.x;
    __shared__ float rows[ROWS][FIN];
    __shared__ float rows2[ROWS][FIN];
    {   // gather: 4 waves, each handles 2 rows; lane = feature pair
        const int wv = t >> 6;
        const int l = t & 63;
        for (int rr = 0; rr < ROWS; rr += 4) {
            const int r = rr + wv;
            const int v = r0 + r;
            float sx = 0.f, sy = 0.f;
            int p = erowstart[v];
            const int pend = erowstart[v + 1];
            for (; p + 4 <= pend; p += 4) {
                int p0 = ecsr[p], p1 = ecsr[p + 1], p2 = ecsr[p + 2], p3 = ecsr[p + 3];
                float2 a = ldx2(Y, (size_t)p0 * FIN + 2 * l);
                float2 c = ldx2(Y, (size_t)p1 * FIN + 2 * l);
                float2 d = ldx2(Y, (size_t)p2 * FIN + 2 * l);
                float2 e = ldx2(Y, (size_t)p3 * FIN + 2 * l);
                sx += a.x + c.x + d.x + e.x;
                sy += a.y + c.y + d.y + e.y;
            }
            for (; p < pend; ++p) {
                float2 a = ldx2(Y, (size_t)ecsr[p] * FIN + 2 * l);
                sx += a.x; sy += a.y;
            }
            const float nd = ndeg[v];
            float2 o; o.x = sx * nd; o.y = sy * nd;
            *(float2*)&rows[r][2 * l] = o;
        }
    }
    __syncthreads();
    {   // mm1: rows2 = relu(rows @ W1 + b1); thread covers 4 (row,feat) cells
        const int j = t & 127;
        const int g = t >> 7;              // row group 0/1 -> rows 4g..4g+3
        float acc[4] = {};
        for (int k = 0; k < FIN; ++k) {
            float w = W1[k * FIN + j];
#pragma unroll
            for (int r = 0; r < 4; ++r) acc[r] += rows[g * 4 + r][k] * w;
        }
        const float bias = b1[j];
#pragma unroll
        for (int r = 0; r < 4; ++r) {
            float v = acc[r] + bias;
            if (RELU) v = fmaxf(v, 0.f);
            rows2[g * 4 + r][j] = v;
        }
    }
    __syncthreads();
    // mm2: msg = (rows2 @ W2) * dinv -> bf16
    if (FO == 128) {
        const int j = t & 127;
        const int g = t >> 7;
        float acc[4] = {};
        for (int k = 0; k < FIN; ++k) {
            float w = W2[k * FO + j];
#pragma unroll
            for (int r = 0; r < 4; ++r) acc[r] += rows2[g * 4 + r][k] * w;
        }
#pragma unroll
        for (int r = 0; r < 4; ++r) {
            const int v = r0 + g * 4 + r;
            msg[(size_t)v * FO + j] = f2bf(acc[r] * dinv[v]);
        }
    } else {  // FO == 64
        const int j = t & 63;
        const int g = t >> 6;              // 0..3 -> rows 2g, 2g+1
        float acc[2] = {};
        for (int k = 0; k < FIN; ++k) {
            float w = W2[k * FO + j];
#pragma unroll
            for (int r = 0; r < 2; ++r) acc[r] += rows2[g * 2 + r][k] * w;
        }
#pragma unroll
        for (int r = 0; r < 2; ++r) {
            const int v = r0 + g * 2 + r;
            msg[(size_t)v * FO + j] = f2bf(acc[r] * dinv[v]);
        }
    }
}

// ------- GCN gather (F=128, bf16 msgs): h[d] = bf16((self+sum)*dinv[d]+b) ----
__global__ __launch_bounds__(256) void gcn_gather128_kernel(
    const unsigned short* __restrict__ msg, const int* __restrict__ rowstart,
    const int* __restrict__ csr_src, const float* __restrict__ dinv,
    const float* __restrict__ b, unsigned short* __restrict__ out) {
    const int tid = threadIdx.x;
    const int d = blockIdx.x * 4 + (tid >> 6);
    const int l = tid & 63;  // feature pair index
    const ushort2* m2 = (const ushort2*)msg;
    ushort2 v = m2[(size_t)d * 64 + l];  // self loop
    float sx = bf2f(v.x), sy = bf2f(v.y);
    int e = rowstart[d];
    const int eend = rowstart[d + 1];
    for (; e + 2 <= eend; e += 2) {
        int s0 = csr_src[e], s1 = csr_src[e + 1];
        ushort2 a = m2[(size_t)s0 * 64 + l];
        ushort2 c = m2[(size_t)s1 * 64 + l];
        sx += bf2f(a.x) + bf2f(c.x);
        sy += bf2f(a.y) + bf2f(c.y);
    }
    for (; e < eend; ++e) {
        ushort2 a = m2[(size_t)csr_src[e] * 64 + l];
        sx += bf2f(a.x); sy += bf2f(a.y);
    }
    const float di = dinv[d];
    const float2 bb = ((const float2*)b)[l];
    ushort2 o; o.x = f2bf(sx * di + bb.x); o.y = f2bf(sy * di + bb.y);
    ((ushort2*)out)[(size_t)d * 64 + l] = o;
}

// ------- fused GCN gather (F=64, bf16 msgs) + bias + log_softmax -> fp32 -----
__global__ __launch_bounds__(256) void gcn_gather_lsm_kernel(
    const unsigned short* __restrict__ msg, const int* __restrict__ rowstart,
    const int* __restrict__ csr_src, const float* __restrict__ dinv,
    const float* __restrict__ b, float* __restrict__ out) {
    const int tid = threadIdx.x;
    const int d = blockIdx.x * 4 + (tid >> 6);  // one 64-lane wave per node
    const int t = tid & 63;
    float s = bf2f(msg[(size_t)d * FOUT2 + t]);  // self loop
    int e = rowstart[d];
    const int eend = rowstart[d + 1];
    for (; e + 4 <= eend; e += 4) {
        int s0 = csr_src[e], s1 = csr_src[e + 1], s2 = csr_src[e + 2], s3 = csr_src[e + 3];
        s += bf2f(msg[(size_t)s0 * FOUT2 + t]) + bf2f(msg[(size_t)s1 * FOUT2 + t])
           + bf2f(msg[(size_t)s2 * FOUT2 + t]) + bf2f(msg[(size_t)s3 * FOUT2 + t]);
    }
    for (; e < eend; ++e) s += bf2f(msg[(size_t)csr_src[e] * FOUT2 + t]);
    const float xv = s * dinv[d] + b[t];
    float m = xv;
#pragma unroll
    for (int o = 32; o > 0; o >>= 1) m = fmaxf(m, __shfl_xor(m, o));
    float ex = __expf(xv - m);
    float sm = ex;
#pragma unroll
    for (int o = 32; o > 0; o >>= 1) sm += __shfl_xor(sm, o);
    out[(size_t)d * FOUT2 + t] = xv - m - __logf(sm);
}

extern "C" void kernel_launch(void* const* d_in, const int* in_sizes, int n_in,
                              void* d_out, int out_size, void* d_ws, size_t ws_size,
                              hipStream_t stream) {
    (void)in_sizes; (void)n_in; (void)out_size; (void)ws_size;
    const float* x      = (const float*)d_in[0];
    const int*   eidx   = (const int*)d_in[1];
    const int*   egoids = (const int*)d_in[2];
    const float* egoadj = (const float*)d_in[3];
    const float* ndeg   = (const float*)d_in[4];
    const float* W_ego1 = (const float*)d_in[5];
    const float* b_ego1 = (const float*)d_in[6];
    const float* W_gcn1 = (const float*)d_in[7];
    const float* b_gcn1 = (const float*)d_in[8];
    const float* W_ego2 = (const float*)d_in[9];
    const float* b_ego2 = (const float*)d_in[10];
    const float* W_gcn2 = (const float*)d_in[11];
    const float* b_gcn2 = (const float*)d_in[12];
    const int* src = eidx;
    const int* dst = eidx + NE;

    // ---- workspace layout (~103 MB) ----
    int* ip = (int*)d_ws;
    int* deg       = ip;                    // NN  (zeroed)
    int* edeg      = deg + NN;              // NN  (zeroed)
    int* rowstart  = edeg + NN;             // NN+1
    int* erowstart = rowstart + NN + 8;     // NN+1
    int* csr_src   = erowstart + NN + 8;    // NE
    int* ecsr      = csr_src + NE;          // NN*KE
    int* scantmp   = ecsr + NN * KE;        // 2*NN
    int* bsums     = scantmp + 2 * NN;      // 2*NB (+pad)
    int* posarr    = bsums + 256;           // TOT
    float* dinv = (float*)(posarr + TOT);               // NN
    unsigned short* mA = (unsigned short*)(dinv + NN);   // NN*128 bf16 msgs L1
    unsigned short* hA = mA + (size_t)NN * FIN;          // NN*128 bf16 hidden
    unsigned short* m2 = hA + (size_t)NN * FIN;          // NN*64  bf16 msgs L2
    unsigned short* Y  = m2 + (size_t)NN * FOUT2;        // NN*KE*128 bf16

    // ---- CSR build overlapped with layer-1 ego apply ----
    (void)hipMemsetAsync(deg, 0, 2 * NN * sizeof(int), stream);
    apply1_hist_kernel<<<NN / 4 + HB, 256, 0, stream>>>(x, egoids, egoadj, Y,
                                                        dst, deg, edeg, posarr);
    scan_p1_kernel<<<2 * NB, 256, 0, stream>>>(deg, edeg, scantmp, bsums, dinv);
    scan_p2_kernel<<<1, 256, 0, stream>>>(bsums);
    scan_p3_kernel<<<2 * NB, 256, 0, stream>>>(scantmp, bsums, rowstart, erowstart);
    bucket2_kernel<<<HB, 256, 0, stream>>>(src, dst, egoids, rowstart,
                                           erowstart, posarr, csr_src, ecsr);

    // ---- layer 1 ----
    ego_dual_kernel<128, true><<<NN / 8, 256, 0, stream>>>(Y, erowstart, ecsr, ndeg,
                                                           W_ego1, b_ego1, W_gcn1, dinv, mA);
    gcn_gather128_kernel<<<NN / 4, 256, 0, stream>>>(mA, rowstart, csr_src, dinv, b_gcn1, hA);

    // ---- layer 2 ----
    ego_apply2_kernel<<<NN / 4, 256, 0, stream>>>(hA, egoids, egoadj, Y);
    ego_dual_kernel<64, false><<<NN / 8, 256, 0, stream>>>(Y, erowstart, ecsr, ndeg,
                                                           W_ego2, b_ego2, W_gcn2, dinv, m2);
    gcn_gather_lsm_kernel<<<NN / 4, 256, 0, stream>>>(m2, rowstart, csr_src, dinv, b_gcn2, (float*)d_out);
}

// Round 10
// 382.284 us; speedup vs baseline: 5.9366x; 1.0260x over previous
//
#include <hip/hip_runtime.h>
#include <hip/hip_bf16.h>

#define NN    20000   // nodes
#define KE    16      // ego-net size
#define FIN   128     // input feats / hidden
#define FOUT2 64      // output classes
#define NE    640000  // edges
#define NB    79      // scan blocks per array: ceil(NN/256)
#define TOT   (NE + NN * KE)        // 960000 items in unified hist/bucket space
#define HB    469                   // hist/bucket blocks: ceil(TOT/8/256)
#define APAD  17                    // padded row stride for A in LDS (bank-conflict-free)

// ---- bf16 helpers (ushort storage, fp32 math) ----
__device__ __forceinline__ float bf2f(unsigned short u) {
    union { float f; unsigned int i; } c; c.i = ((unsigned int)u) << 16; return c.f;
}
__device__ __forceinline__ unsigned short f2bf(float f) {
    union { float f; unsigned int i; } c; c.f = f;
    unsigned int lsb = (c.i >> 16) & 1u;
    c.i += 0x7fffu + lsb;           // round-to-nearest-even
    return (unsigned short)(c.i >> 16);
}
__device__ __forceinline__ float2 ldx2(const float* p, size_t i) {
    return *(const float2*)(p + i);
}
__device__ __forceinline__ float2 ldx2(const unsigned short* p, size_t i) {
    ushort2 u = *(const ushort2*)(p + i);
    float2 r; r.x = bf2f(u.x); r.y = bf2f(u.y); return r;
}

// ---- shared ego-apply body: Y[n] = (A@A) @ x[ids[n]] -> bf16 ---------------
// Ar padded to stride 17 (conflict-free reads); As stored so that
// A2[i][k] = As[i*16 + (k>>2)*4 + (k&3)], written as one float4 per lane.
template <typename T>
__device__ __forceinline__ void ego_apply_body(
    const T* __restrict__ x, const int* __restrict__ ego_ids,
    const float* __restrict__ ego_adj, unsigned short* __restrict__ Y,
    float (*Ar)[KE * APAD], float (*As)[256], int (*ids)[KE], int n_base) {
    const int w = threadIdx.x >> 6;
    const int l = threadIdx.x & 63;
    const int n = n_base + w;
    const float* a = ego_adj + (size_t)n * 256;
#pragma unroll
    for (int q = 0; q < 4; ++q) {
        const int idx = l + q * 64;
        Ar[w][(idx >> 4) * APAD + (idx & 15)] = a[idx];
    }
    if (l < KE) ids[w][l] = ego_ids[n * KE + l];
    __syncthreads();
    {   // A2 row i = l>>2, cols c*4..c*4+3 where c = l&3
        const int i = l >> 2, c = l & 3;
        float4 s = {0.f, 0.f, 0.f, 0.f};
#pragma unroll
        for (int j = 0; j < KE; ++j) {
            const float aij = Ar[w][i * APAD + j];
            const float* arow = &Ar[w][j * APAD + c * 4];
            s.x += aij * arow[0];
            s.y += aij * arow[1];
            s.z += aij * arow[2];
            s.w += aij * arow[3];
        }
        *(float4*)&As[w][l * 4] = s;   // As[i*16 + c*4 + q] = A2[i][c*4+q]
    }
    __syncthreads();
    float2 xg[KE];
#pragma unroll
    for (int k = 0; k < KE; ++k) xg[k] = ldx2(x, (size_t)ids[w][k] * FIN + 2 * l);
    unsigned short* yout = Y + (size_t)n * KE * FIN + 2 * l;
#pragma unroll
    for (int i = 0; i < KE; ++i) {
        float sx = 0.f, sy = 0.f;
#pragma unroll
        for (int k = 0; k < KE; ++k) {
            float a2 = As[w][i * 16 + k];   // k = c*4+q iterates identically
            sx += a2 * xg[k].x;
            sy += a2 * xg[k].y;
        }
        ushort2 o; o.x = f2bf(sx); o.y = f2bf(sy);
        *(ushort2*)(yout + i * FIN) = o;
    }
}

// ---- fused: hist+pos (blocks [0,HB)) || ego_apply layer-1 (blocks >= HB) ---
// hist FIRST so its latency-bound blocks are resident while apply streams.
__global__ __launch_bounds__(256) void apply1_hist_kernel(
    const float* __restrict__ x, const int* __restrict__ ego_ids,
    const float* __restrict__ ego_adj, unsigned short* __restrict__ Y,
    const int* __restrict__ dst, int* __restrict__ deg, int* __restrict__ edeg,
    int* __restrict__ posarr) {
    __shared__ float Ar[4][KE * APAD];
    __shared__ float As[4][256];
    __shared__ int ids[4][KE];
    if (blockIdx.x < HB) {          // ---- histogram part ----
        const int base = (blockIdx.x * 256 + threadIdx.x) * 8;
#pragma unroll
        for (int q = 0; q < 8; ++q) {
            const int i = base + q;
            if (i >= TOT) return;
            if (i < NE) posarr[i] = atomicAdd(&deg[dst[i]], 1);
            else        posarr[i] = atomicAdd(&edeg[ego_ids[i - NE]], 1);
        }
        return;
    }
    ego_apply_body<float>(x, ego_ids, ego_adj, Y, Ar, As, ids, (blockIdx.x - HB) * 4);
}

// ---- plain ego apply (layer 2, bf16 input), 4 nets per 256-thr block -------
__global__ __launch_bounds__(256) void ego_apply2_kernel(
    const unsigned short* __restrict__ x, const int* __restrict__ ego_ids,
    const float* __restrict__ ego_adj, unsigned short* __restrict__ Y) {
    __shared__ float Ar[4][KE * APAD];
    __shared__ float As[4][256];
    __shared__ int ids[4][KE];
    ego_apply_body<unsigned short>(x, ego_ids, ego_adj, Y, Ar, As, ids, blockIdx.x * 4);
}

// ---------------- 3-phase exclusive scan over deg and edeg -------------------
__global__ __launch_bounds__(256) void scan_p1_kernel(
    const int* __restrict__ deg, const int* __restrict__ edeg,
    int* __restrict__ scantmp, int* __restrict__ bsums, float* __restrict__ dinv) {
    const int arr = (blockIdx.x >= NB) ? 1 : 0;
    const int blk = blockIdx.x - arr * NB;
    const int t = threadIdx.x;
    const int i = blk * 256 + t;
    const int* cnt = arr ? edeg : deg;
    int v = (i < NN) ? cnt[i] : 0;
    if (!arr && i < NN) dinv[i] = rsqrtf((float)(v + 1));  // +1 self loop
    __shared__ int sh[256];
    sh[t] = v;
    __syncthreads();
    for (int o = 1; o < 256; o <<= 1) {
        int u = (t >= o) ? sh[t - o] : 0;
        __syncthreads();
        sh[t] += u;
        __syncthreads();
    }
    if (i < NN) scantmp[arr * NN + i] = sh[t] - v;  // exclusive within block
    if (t == 255) bsums[arr * NB + blk] = sh[255];
}
__global__ __launch_bounds__(256) void scan_p2_kernel(int* __restrict__ bsums) {
    const int t = threadIdx.x;
    __shared__ int sh[256];
    for (int a = 0; a < 2; ++a) {
        int v = (t < NB) ? bsums[a * NB + t] : 0;
        sh[t] = v;
        __syncthreads();
        for (int o = 1; o < 256; o <<= 1) {
            int u = (t >= o) ? sh[t - o] : 0;
            __syncthreads();
            sh[t] += u;
            __syncthreads();
        }
        if (t < NB) bsums[a * NB + t] = sh[t] - v;
        __syncthreads();
    }
}
__global__ __launch_bounds__(256) void scan_p3_kernel(
    const int* __restrict__ scantmp, const int* __restrict__ bsums,
    int* __restrict__ rowstart, int* __restrict__ erowstart) {
    const int arr = (blockIdx.x >= NB) ? 1 : 0;
    const int blk = blockIdx.x - arr * NB;
    const int t = threadIdx.x;
    const int i = blk * 256 + t;
    if (i < NN) {
        int val = scantmp[arr * NN + i] + bsums[arr * NB + blk];
        if (arr) erowstart[i] = val; else rowstart[i] = val;
    }
    if (blockIdx.x == 0 && t == 0) { rowstart[NN] = NE; erowstart[NN] = NN * KE; }
}

// ---- bucket pass: pure scatter, no atomics (positions precomputed) ---------
__global__ void bucket2_kernel(const int* __restrict__ src, const int* __restrict__ dst,
                               const int* __restrict__ ego_flat,
                               const int* __restrict__ rowstart, const int* __restrict__ erowstart,
                               const int* __restrict__ posarr,
                               int* __restrict__ csr_src, int* __restrict__ ecsr) {
    const int base = (blockIdx.x * blockDim.x + threadIdx.x) * 8;
#pragma unroll
    for (int q = 0; q < 8; ++q) {
        const int i = base + q;
        if (i >= TOT) return;
        if (i < NE) {
            int d = dst[i];
            csr_src[rowstart[d] + posarr[i]] = src[i];
        } else {
            int p = i - NE;
            int v = ego_flat[p];
            ecsr[erowstart[v] + posarr[i]] = p;  // p encodes (n,i); Y row index == p
        }
    }
}

// ---- fused: ego reduce + ndeg scale + linear_ego(+relu) + linear_gcn*dinv ---
template <int FO, bool RELU>
__global__ __launch_bounds__(256) void ego_dual_kernel(
    const unsigned short* __restrict__ Y, const int* __restrict__ erowstart,
    const int* __restrict__ ecsr, const float* __restrict__ ndeg,
    const float* __restrict__ W1, const float* __restrict__ b1,
    const float* __restrict__ W2, const float* __restrict__ dinv,
    unsigned short* __restrict__ msg) {
    constexpr int ROWS = 8;
    const int r0 = blockIdx.x * ROWS;
    const int t = threadIdx.x;
    __shared__ float rows[ROWS][FIN];
    __shared__ float rows2[ROWS][FIN];
    {   // gather: 4 waves, each handles 2 rows; lane = feature pair
        const int wv = t >> 6;
        const int l = t & 63;
        for (int rr = 0; rr < ROWS; rr += 4) {
            const int r = rr + wv;
            const int v = r0 + r;
            float sx = 0.f, sy = 0.f;
            int p = erowstart[v];
            const int pend = erowstart[v + 1];
            for (; p + 4 <= pend; p += 4) {
                int p0 = ecsr[p], p1 = ecsr[p + 1], p2 = ecsr[p + 2], p3 = ecsr[p + 3];
                float2 a = ldx2(Y, (size_t)p0 * FIN + 2 * l);
                float2 c = ldx2(Y, (size_t)p1 * FIN + 2 * l);
                float2 d = ldx2(Y, (size_t)p2 * FIN + 2 * l);
                float2 e = ldx2(Y, (size_t)p3 * FIN + 2 * l);
                sx += a.x + c.x + d.x + e.x;
                sy += a.y + c.y + d.y + e.y;
            }
            for (; p < pend; ++p) {
                float2 a = ldx2(Y, (size_t)ecsr[p] * FIN + 2 * l);
                sx += a.x; sy += a.y;
            }
            const float nd = ndeg[v];
            float2 o; o.x = sx * nd; o.y = sy * nd;
            *(float2*)&rows[r][2 * l] = o;
        }
    }
    __syncthreads();
    {   // mm1: rows2 = relu(rows @ W1 + b1)
        const int j = t & 127;
        const int g = t >> 7;              // row group 0/1 -> rows 4g..4g+3
        float acc[4] = {};
        for (int k = 0; k < FIN; ++k) {
            float w = W1[k * FIN + j];
#pragma unroll
            for (int r = 0; r < 4; ++r) acc[r] += rows[g * 4 + r][k] * w;
        }
        const float bias = b1[j];
#pragma unroll
        for (int r = 0; r < 4; ++r) {
            float v = acc[r] + bias;
            if (RELU) v = fmaxf(v, 0.f);
            rows2[g * 4 + r][j] = v;
        }
    }
    __syncthreads();
    // mm2: msg = (rows2 @ W2) * dinv -> bf16
    if (FO == 128) {
        const int j = t & 127;
        const int g = t >> 7;
        float acc[4] = {};
        for (int k = 0; k < FIN; ++k) {
            float w = W2[k * FO + j];
#pragma unroll
            for (int r = 0; r < 4; ++r) acc[r] += rows2[g * 4 + r][k] * w;
        }
#pragma unroll
        for (int r = 0; r < 4; ++r) {
            const int v = r0 + g * 4 + r;
            msg[(size_t)v * FO + j] = f2bf(acc[r] * dinv[v]);
        }
    } else {  // FO == 64
        const int j = t & 63;
        const int g = t >> 6;              // 0..3 -> rows 2g, 2g+1
        float acc[2] = {};
        for (int k = 0; k < FIN; ++k) {
            float w = W2[k * FO + j];
#pragma unroll
            for (int r = 0; r < 2; ++r) acc[r] += rows2[g * 2 + r][k] * w;
        }
#pragma unroll
        for (int r = 0; r < 2; ++r) {
            const int v = r0 + g * 2 + r;
            msg[(size_t)v * FO + j] = f2bf(acc[r] * dinv[v]);
        }
    }
}

// ------- GCN gather (F=128, bf16 msgs): h[d] = bf16((self+sum)*dinv[d]+b) ----
__global__ __launch_bounds__(256) void gcn_gather128_kernel(
    const unsigned short* __restrict__ msg, const int* __restrict__ rowstart,
    const int* __restrict__ csr_src, const float* __restrict__ dinv,
    const float* __restrict__ b, unsigned short* __restrict__ out) {
    const int tid = threadIdx.x;
    const int d = blockIdx.x * 4 + (tid >> 6);
    const int l = tid & 63;  // feature pair index
    const ushort2* m2 = (const ushort2*)msg;
    ushort2 v = m2[(size_t)d * 64 + l];  // self loop
    float sx = bf2f(v.x), sy = bf2f(v.y);
    int e = rowstart[d];
    const int eend = rowstart[d + 1];
    for (; e + 2 <= eend; e += 2) {
        int s0 = csr_src[e], s1 = csr_src[e + 1];
        ushort2 a = m2[(size_t)s0 * 64 + l];
        ushort2 c = m2[(size_t)s1 * 64 + l];
        sx += bf2f(a.x) + bf2f(c.x);
        sy += bf2f(a.y) + bf2f(c.y);
    }
    for (; e < eend; ++e) {
        ushort2 a = m2[(size_t)csr_src[e] * 64 + l];
        sx += bf2f(a.x); sy += bf2f(a.y);
    }
    const float di = dinv[d];
    const float2 bb = ((const float2*)b)[l];
    ushort2 o; o.x = f2bf(sx * di + bb.x); o.y = f2bf(sy * di + bb.y);
    ((ushort2*)out)[(size_t)d * 64 + l] = o;
}

// ------- fused GCN gather (F=64, bf16 msgs) + bias + log_softmax -> fp32 -----
__global__ __launch_bounds__(256) void gcn_gather_lsm_kernel(
    const unsigned short* __restrict__ msg, const int* __restrict__ rowstart,
    const int* __restrict__ csr_src, const float* __restrict__ dinv,
    const float* __restrict__ b, float* __restrict__ out) {
    const int tid = threadIdx.x;
    const int d = blockIdx.x * 4 + (tid >> 6);  // one 64-lane wave per node
    const int t = tid & 63;
    float s = bf2f(msg[(size_t)d * FOUT2 + t]);  // self loop
    int e = rowstart[d];
    const int eend = rowstart[d + 1];
    for (; e + 4 <= eend; e += 4) {
        int s0 = csr_src[e], s1 = csr_src[e + 1], s2 = csr_src[e + 2], s3 = csr_src[e + 3];
        s += bf2f(msg[(size_t)s0 * FOUT2 + t]) + bf2f(msg[(size_t)s1 * FOUT2 + t])
           + bf2f(msg[(size_t)s2 * FOUT2 + t]) + bf2f(msg[(size_t)s3 * FOUT2 + t]);
    }
    for (; e < eend; ++e) s += bf2f(msg[(size_t)csr_src[e] * FOUT2 + t]);
    const float xv = s * dinv[d] + b[t];
    float m = xv;
#pragma unroll
    for (int o = 32; o > 0; o >>= 1) m = fmaxf(m, __shfl_xor(m, o));
    float ex = __expf(xv - m);
    float sm = ex;
#pragma unroll
    for (int o = 32; o > 0; o >>= 1) sm += __shfl_xor(sm, o);
    out[(size_t)d * FOUT2 + t] = xv - m - __logf(sm);
}

extern "C" void kernel_launch(void* const* d_in, const int* in_sizes, int n_in,
                              void* d_out, int out_size, void* d_ws, size_t ws_size,
                              hipStream_t stream) {
    (void)in_sizes; (void)n_in; (void)out_size; (void)ws_size;
    const float* x      = (const float*)d_in[0];
    const int*   eidx   = (const int*)d_in[1];
    const int*   egoids = (const int*)d_in[2];
    const float* egoadj = (const float*)d_in[3];
    const float* ndeg   = (const float*)d_in[4];
    const float* W_ego1 = (const float*)d_in[5];
    const float* b_ego1 = (const float*)d_in[6];
    const float* W_gcn1 = (const float*)d_in[7];
    const float* b_gcn1 = (const float*)d_in[8];
    const float* W_ego2 = (const float*)d_in[9];
    const float* b_ego2 = (const float*)d_in[10];
    const float* W_gcn2 = (const float*)d_in[11];
    const float* b_gcn2 = (const float*)d_in[12];
    const int* src = eidx;
    const int* dst = eidx + NE;

    // ---- workspace layout (~103 MB) ----
    int* ip = (int*)d_ws;
    int* deg       = ip;                    // NN  (zeroed)
    int* edeg      = deg + NN;              // NN  (zeroed)
    int* rowstart  = edeg + NN;             // NN+1
    int* erowstart = rowstart + NN + 8;     // NN+1
    int* csr_src   = erowstart + NN + 8;    // NE
    int* ecsr      = csr_src + NE;          // NN*KE
    int* scantmp   = ecsr + NN * KE;        // 2*NN
    int* bsums     = scantmp + 2 * NN;      // 2*NB (+pad)
    int* posarr    = bsums + 256;           // TOT
    float* dinv = (float*)(posarr + TOT);               // NN
    unsigned short* mA = (unsigned short*)(dinv + NN);   // NN*128 bf16 msgs L1
    unsigned short* hA = mA + (size_t)NN * FIN;          // NN*128 bf16 hidden
    unsigned short* m2 = hA + (size_t)NN * FIN;          // NN*64  bf16 msgs L2
    unsigned short* Y  = m2 + (size_t)NN * FOUT2;        // NN*KE*128 bf16

    // ---- CSR build overlapped with layer-1 ego apply (hist blocks FIRST) ----
    (void)hipMemsetAsync(deg, 0, 2 * NN * sizeof(int), stream);
    apply1_hist_kernel<<<HB + NN / 4, 256, 0, stream>>>(x, egoids, egoadj, Y,
                                                        dst, deg, edeg, posarr);
    scan_p1_kernel<<<2 * NB, 256, 0, stream>>>(deg, edeg, scantmp, bsums, dinv);
    scan_p2_kernel<<<1, 256, 0, stream>>>(bsums);
    scan_p3_kernel<<<2 * NB, 256, 0, stream>>>(scantmp, bsums, rowstart, erowstart);
    bucket2_kernel<<<HB, 256, 0, stream>>>(src, dst, egoids, rowstart,
                                           erowstart, posarr, csr_src, ecsr);

    // ---- layer 1 ----
    ego_dual_kernel<128, true><<<NN / 8, 256, 0, stream>>>(Y, erowstart, ecsr, ndeg,
                                                           W_ego1, b_ego1, W_gcn1, dinv, mA);
    gcn_gather128_kernel<<<NN / 4, 256, 0, stream>>>(mA, rowstart, csr_src, dinv, b_gcn1, hA);

    // ---- layer 2 ----
    ego_apply2_kernel<<<NN / 4, 256, 0, stream>>>(hA, egoids, egoadj, Y);
    ego_dual_kernel<64, false><<<NN / 8, 256, 0, stream>>>(Y, erowstart, ecsr, ndeg,
                                                           W_ego2, b_ego2, W_gcn2, dinv, m2);
    gcn_gather_lsm_kernel<<<NN / 4, 256, 0, stream>>>(m2, rowstart, csr_src, dinv, b_gcn2, (float*)d_out);
}

// Round 11
// 370.583 us; speedup vs baseline: 6.1241x; 1.0316x over previous
//
#include <hip/hip_runtime.h>
#include <hip/hip_bf16.h>

#define NN    20000   // nodes
#define KE    16      // ego-net size
#define FIN   128     // input feats / hidden
#define FOUT2 64      // output classes
#define NE    640000  // edges
#define NB    79      // scan blocks per array: ceil(NN/256)
#define TOT   (NE + NN * KE)        // 960000 items in unified hist/bucket space
#define HB    469                   // hist/bucket blocks: ceil(TOT/8/256)
#define APAD  17                    // padded row stride for A in LDS

// ---- bf16 helpers (ushort storage, fp32 math) ----
__device__ __forceinline__ float bf2f(unsigned short u) {
    union { float f; unsigned int i; } c; c.i = ((unsigned int)u) << 16; return c.f;
}
__device__ __forceinline__ unsigned short f2bf(float f) {
    union { float f; unsigned int i; } c; c.f = f;
    unsigned int lsb = (c.i >> 16) & 1u;
    c.i += 0x7fffu + lsb;           // round-to-nearest-even
    return (unsigned short)(c.i >> 16);
}
__device__ __forceinline__ float4 ldx4(const float* p, size_t i) {
    return *(const float4*)(p + i);
}
__device__ __forceinline__ float4 ldx4(const unsigned short* p, size_t i) {
    ushort4 u = *(const ushort4*)(p + i);
    float4 r; r.x = bf2f(u.x); r.y = bf2f(u.y); r.z = bf2f(u.z); r.w = bf2f(u.w);
    return r;
}

// ---- shared ego-apply body: Y[n] = (A@A) @ x[ids[n]] -> bf16 ---------------
// 8 nets per 256-thread block; 32 lanes per net, lane owns feature quad 4c.
template <typename T>
__device__ __forceinline__ void ego_apply_body(
    const T* __restrict__ x, const int* __restrict__ ego_ids,
    const float* __restrict__ ego_adj, unsigned short* __restrict__ Y,
    float (*Ar)[KE * APAD], float (*As)[256], int (*ids)[KE], int n_base) {
    const int w = threadIdx.x >> 5;   // net slot 0..7
    const int c = threadIdx.x & 31;   // lane within net
    const int n = n_base + w;
    const float* a = ego_adj + (size_t)n * 256;
#pragma unroll
    for (int e = 0; e < 8; ++e) {     // load A into padded LDS (conflict-light)
        const int idx = c * 8 + e;
        Ar[w][(idx >> 4) * APAD + (idx & 15)] = a[idx];
    }
    if (c < KE) ids[w][c] = ego_ids[n * KE + c];
    __syncthreads();
    {   // A2 entries 8c..8c+7: row i = c>>1, cols k0..k0+7 (k0 = (c&1)*8)
        const int i = c >> 1;
        const int k0 = (c & 1) * 8;
        float s[8] = {};
#pragma unroll
        for (int j = 0; j < KE; ++j) {
            const float aij = Ar[w][i * APAD + j];   // 16 banks via APAD
            const float* arow = &Ar[w][j * APAD + k0];
#pragma unroll
            for (int q = 0; q < 8; ++q) s[q] += aij * arow[q];
        }
        float4 s0 = {s[0], s[1], s[2], s[3]}, s1 = {s[4], s[5], s[6], s[7]};
        *(float4*)&As[w][i * 16 + k0]     = s0;      // contiguous b128 writes
        *(float4*)&As[w][i * 16 + k0 + 4] = s1;
    }
    __syncthreads();
    float4 xg[KE];                    // one full row per 32-lane issue (16B/lane)
#pragma unroll
    for (int k = 0; k < KE; ++k) xg[k] = ldx4(x, (size_t)ids[w][k] * FIN + 4 * c);
    unsigned short* yout = Y + (size_t)n * KE * FIN + 4 * c;
#pragma unroll
    for (int i = 0; i < KE; ++i) {
        float4 acc = {0.f, 0.f, 0.f, 0.f};
#pragma unroll
        for (int k = 0; k < KE; ++k) {
            const float a2 = As[w][i * 16 + k];      // broadcast read
            acc.x += a2 * xg[k].x; acc.y += a2 * xg[k].y;
            acc.z += a2 * xg[k].z; acc.w += a2 * xg[k].w;
        }
        ushort4 o; o.x = f2bf(acc.x); o.y = f2bf(acc.y);
        o.z = f2bf(acc.z); o.w = f2bf(acc.w);
        *(ushort4*)(yout + (size_t)i * FIN) = o;     // 8B/lane bf16 store
    }
}

// ---- fused: hist+pos (blocks [0,HB)) || ego_apply layer-1 (blocks >= HB) ---
__global__ __launch_bounds__(256) void apply1_hist_kernel(
    const float* __restrict__ x, const int* __restrict__ ego_ids,
    const float* __restrict__ ego_adj, unsigned short* __restrict__ Y,
    const int* __restrict__ dst, int* __restrict__ deg, int* __restrict__ edeg,
    int* __restrict__ posarr) {
    __shared__ float Ar[8][KE * APAD];
    __shared__ float As[8][256];
    __shared__ int ids[8][KE];
    if (blockIdx.x < HB) {          // ---- histogram part (resident first) ----
        const int base = (blockIdx.x * 256 + threadIdx.x) * 8;
#pragma unroll
        for (int q = 0; q < 8; ++q) {
            const int i = base + q;
            if (i >= TOT) return;
            if (i < NE) posarr[i] = atomicAdd(&deg[dst[i]], 1);
            else        posarr[i] = atomicAdd(&edeg[ego_ids[i - NE]], 1);
        }
        return;
    }
    ego_apply_body<float>(x, ego_ids, ego_adj, Y, Ar, As, ids, (blockIdx.x - HB) * 8);
}

// ---- plain ego apply (layer 2, bf16 input), 8 nets per 256-thr block -------
__global__ __launch_bounds__(256) void ego_apply2_kernel(
    const unsigned short* __restrict__ x, const int* __restrict__ ego_ids,
    const float* __restrict__ ego_adj, unsigned short* __restrict__ Y) {
    __shared__ float Ar[8][KE * APAD];
    __shared__ float As[8][256];
    __shared__ int ids[8][KE];
    ego_apply_body<unsigned short>(x, ego_ids, ego_adj, Y, Ar, As, ids, blockIdx.x * 8);
}

// ---------------- 3-phase exclusive scan over deg and edeg -------------------
__global__ __launch_bounds__(256) void scan_p1_kernel(
    const int* __restrict__ deg, const int* __restrict__ edeg,
    int* __restrict__ scantmp, int* __restrict__ bsums, float* __restrict__ dinv) {
    const int arr = (blockIdx.x >= NB) ? 1 : 0;
    const int blk = blockIdx.x - arr * NB;
    const int t = threadIdx.x;
    const int i = blk * 256 + t;
    const int* cnt = arr ? edeg : deg;
    int v = (i < NN) ? cnt[i] : 0;
    if (!arr && i < NN) dinv[i] = rsqrtf((float)(v + 1));  // +1 self loop
    __shared__ int sh[256];
    sh[t] = v;
    __syncthreads();
    for (int o = 1; o < 256; o <<= 1) {
        int u = (t >= o) ? sh[t - o] : 0;
        __syncthreads();
        sh[t] += u;
        __syncthreads();
    }
    if (i < NN) scantmp[arr * NN + i] = sh[t] - v;
    if (t == 255) bsums[arr * NB + blk] = sh[255];
}
__global__ __launch_bounds__(256) void scan_p2_kernel(int* __restrict__ bsums) {
    const int t = threadIdx.x;
    __shared__ int sh[256];
    for (int a = 0; a < 2; ++a) {
        int v = (t < NB) ? bsums[a * NB + t] : 0;
        sh[t] = v;
        __syncthreads();
        for (int o = 1; o < 256; o <<= 1) {
            int u = (t >= o) ? sh[t - o] : 0;
            __syncthreads();
            sh[t] += u;
            __syncthreads();
        }
        if (t < NB) bsums[a * NB + t] = sh[t] - v;
        __syncthreads();
    }
}
__global__ __launch_bounds__(256) void scan_p3_kernel(
    const int* __restrict__ scantmp, const int* __restrict__ bsums,
    int* __restrict__ rowstart, int* __restrict__ erowstart) {
    const int arr = (blockIdx.x >= NB) ? 1 : 0;
    const int blk = blockIdx.x - arr * NB;
    const int t = threadIdx.x;
    const int i = blk * 256 + t;
    if (i < NN) {
        int val = scantmp[arr * NN + i] + bsums[arr * NB + blk];
        if (arr) erowstart[i] = val; else rowstart[i] = val;
    }
    if (blockIdx.x == 0 && t == 0) { rowstart[NN] = NE; erowstart[NN] = NN * KE; }
}

// ---- bucket pass: pure scatter, no atomics ---------------------------------
__global__ void bucket2_kernel(const int* __restrict__ src, const int* __restrict__ dst,
                               const int* __restrict__ ego_flat,
                               const int* __restrict__ rowstart, const int* __restrict__ erowstart,
                               const int* __restrict__ posarr,
                               int* __restrict__ csr_src, int* __restrict__ ecsr) {
    const int base = (blockIdx.x * blockDim.x + threadIdx.x) * 8;
#pragma unroll
    for (int q = 0; q < 8; ++q) {
        const int i = base + q;
        if (i >= TOT) return;
        if (i < NE) {
            int d = dst[i];
            csr_src[rowstart[d] + posarr[i]] = src[i];
        } else {
            int p = i - NE;
            int v = ego_flat[p];
            ecsr[erowstart[v] + posarr[i]] = p;
        }
    }
}

// ---- fused: ego reduce + ndeg scale + linear_ego(+relu) + linear_gcn*dinv ---
// Gather uses half-wave split: h=0/1 process interleaved memberships with
// ushort4 loads (16B-effective), combined via shfl_xor lane^32.
template <int FO, bool RELU>
__global__ __launch_bounds__(256) void ego_dual_kernel(
    const unsigned short* __restrict__ Y, const int* __restrict__ erowstart,
    const int* __restrict__ ecsr, const float* __restrict__ ndeg,
    const float* __restrict__ W1, const float* __restrict__ b1,
    const float* __restrict__ W2, const float* __restrict__ dinv,
    unsigned short* __restrict__ msg) {
    constexpr int ROWS = 8;
    const int r0 = blockIdx.x * ROWS;
    const int t = threadIdx.x;
    __shared__ float rows[ROWS][FIN];
    __shared__ float rows2[ROWS][FIN];
    {
        const int wv = t >> 6;          // wave 0..3
        const int h  = (t >> 5) & 1;    // half
        const int c  = t & 31;          // feature quad
        for (int rr = 0; rr < ROWS; rr += 4) {
            const int r = rr + wv;
            const int v = r0 + r;
            float4 acc = {0.f, 0.f, 0.f, 0.f};
            const int pend = erowstart[v + 1];
            int p = erowstart[v] + h;
            for (; p + 2 < pend; p += 4) {
                int rowA = ecsr[p], rowB = ecsr[p + 2];
                float4 a = ldx4(Y, (size_t)rowA * FIN + 4 * c);
                float4 d4 = ldx4(Y, (size_t)rowB * FIN + 4 * c);
                acc.x += a.x + d4.x; acc.y += a.y + d4.y;
                acc.z += a.z + d4.z; acc.w += a.w + d4.w;
            }
            if (p < pend) {
                float4 a = ldx4(Y, (size_t)ecsr[p] * FIN + 4 * c);
                acc.x += a.x; acc.y += a.y; acc.z += a.z; acc.w += a.w;
            }
            acc.x += __shfl_xor(acc.x, 32);
            acc.y += __shfl_xor(acc.y, 32);
            acc.z += __shfl_xor(acc.z, 32);
            acc.w += __shfl_xor(acc.w, 32);
            if (h == 0) {
                const float nd = ndeg[v];
                float4 o = {acc.x * nd, acc.y * nd, acc.z * nd, acc.w * nd};
                *(float4*)&rows[r][4 * c] = o;
            }
        }
    }
    __syncthreads();
    {   // mm1: rows2 = relu(rows @ W1 + b1)
        const int j = t & 127;
        const int g = t >> 7;
        float acc[4] = {};
        for (int k = 0; k < FIN; ++k) {
            float w = W1[k * FIN + j];
#pragma unroll
            for (int r = 0; r < 4; ++r) acc[r] += rows[g * 4 + r][k] * w;
        }
        const float bias = b1[j];
#pragma unroll
        for (int r = 0; r < 4; ++r) {
            float v = acc[r] + bias;
            if (RELU) v = fmaxf(v, 0.f);
            rows2[g * 4 + r][j] = v;
        }
    }
    __syncthreads();
    // mm2: msg = (rows2 @ W2) * dinv -> bf16
    if (FO == 128) {
        const int j = t & 127;
        const int g = t >> 7;
        float acc[4] = {};
        for (int k = 0; k < FIN; ++k) {
            float w = W2[k * FO + j];
#pragma unroll
            for (int r = 0; r < 4; ++r) acc[r] += rows2[g * 4 + r][k] * w;
        }
#pragma unroll
        for (int r = 0; r < 4; ++r) {
            const int v = r0 + g * 4 + r;
            msg[(size_t)v * FO + j] = f2bf(acc[r] * dinv[v]);
        }
    } else {  // FO == 64
        const int j = t & 63;
        const int g = t >> 6;
        float acc[2] = {};
        for (int k = 0; k < FIN; ++k) {
            float w = W2[k * FO + j];
#pragma unroll
            for (int r = 0; r < 2; ++r) acc[r] += rows2[g * 2 + r][k] * w;
        }
#pragma unroll
        for (int r = 0; r < 2; ++r) {
            const int v = r0 + g * 2 + r;
            msg[(size_t)v * FO + j] = f2bf(acc[r] * dinv[v]);
        }
    }
}

// ------- GCN gather (F=128, bf16 msgs), half-split ushort4 ------------------
__global__ __launch_bounds__(256) void gcn_gather128_kernel(
    const unsigned short* __restrict__ msg, const int* __restrict__ rowstart,
    const int* __restrict__ csr_src, const float* __restrict__ dinv,
    const float* __restrict__ b, unsigned short* __restrict__ out) {
    const int tid = threadIdx.x;
    const int d = blockIdx.x * 4 + (tid >> 6);
    const int h = (tid >> 5) & 1;
    const int c = tid & 31;
    float4 acc = {0.f, 0.f, 0.f, 0.f};
    if (h == 0) acc = ldx4(msg, (size_t)d * FIN + 4 * c);  // self loop
    const int eend = rowstart[d + 1];
    int e = rowstart[d] + h;
    for (; e + 2 < eend; e += 4) {
        int s0 = csr_src[e], s1 = csr_src[e + 2];
        float4 a = ldx4(msg, (size_t)s0 * FIN + 4 * c);
        float4 d4 = ldx4(msg, (size_t)s1 * FIN + 4 * c);
        acc.x += a.x + d4.x; acc.y += a.y + d4.y;
        acc.z += a.z + d4.z; acc.w += a.w + d4.w;
    }
    if (e < eend) {
        float4 a = ldx4(msg, (size_t)csr_src[e] * FIN + 4 * c);
        acc.x += a.x; acc.y += a.y; acc.z += a.z; acc.w += a.w;
    }
    acc.x += __shfl_xor(acc.x, 32);
    acc.y += __shfl_xor(acc.y, 32);
    acc.z += __shfl_xor(acc.z, 32);
    acc.w += __shfl_xor(acc.w, 32);
    if (h == 0) {
        const float di = dinv[d];
        const float4 bb = *(const float4*)&b[4 * c];
        ushort4 o;
        o.x = f2bf(acc.x * di + bb.x); o.y = f2bf(acc.y * di + bb.y);
        o.z = f2bf(acc.z * di + bb.z); o.w = f2bf(acc.w * di + bb.w);
        *(ushort4*)(out + (size_t)d * FIN + 4 * c) = o;
    }
}

// ------- fused GCN gather (F=64, bf16 msgs) + bias + log_softmax -> fp32 -----
__global__ __launch_bounds__(256) void gcn_gather_lsm_kernel(
    const unsigned short* __restrict__ msg, const int* __restrict__ rowstart,
    const int* __restrict__ csr_src, const float* __restrict__ dinv,
    const float* __restrict__ b, float* __restrict__ out) {
    const int tid = threadIdx.x;
    const int d = blockIdx.x * 4 + (tid >> 6);  // one 64-lane wave per node
    const int t = tid & 63;
    float s = bf2f(msg[(size_t)d * FOUT2 + t]);  // self loop
    int e = rowstart[d];
    const int eend = rowstart[d + 1];
    for (; e + 4 <= eend; e += 4) {
        int s0 = csr_src[e], s1 = csr_src[e + 1], s2 = csr_src[e + 2], s3 = csr_src[e + 3];
        s += bf2f(msg[(size_t)s0 * FOUT2 + t]) + bf2f(msg[(size_t)s1 * FOUT2 + t])
           + bf2f(msg[(size_t)s2 * FOUT2 + t]) + bf2f(msg[(size_t)s3 * FOUT2 + t]);
    }
    for (; e < eend; ++e) s += bf2f(msg[(size_t)csr_src[e] * FOUT2 + t]);
    const float xv = s * dinv[d] + b[t];
    float m = xv;
#pragma unroll
    for (int o = 32; o > 0; o >>= 1) m = fmaxf(m, __shfl_xor(m, o));
    float ex = __expf(xv - m);
    float sm = ex;
#pragma unroll
    for (int o = 32; o > 0; o >>= 1) sm += __shfl_xor(sm, o);
    out[(size_t)d * FOUT2 + t] = xv - m - __logf(sm);
}

extern "C" void kernel_launch(void* const* d_in, const int* in_sizes, int n_in,
                              void* d_out, int out_size, void* d_ws, size_t ws_size,
                              hipStream_t stream) {
    (void)in_sizes; (void)n_in; (void)out_size; (void)ws_size;
    const float* x      = (const float*)d_in[0];
    const int*   eidx   = (const int*)d_in[1];
    const int*   egoids = (const int*)d_in[2];
    const float* egoadj = (const float*)d_in[3];
    const float* ndeg   = (const float*)d_in[4];
    const float* W_ego1 = (const float*)d_in[5];
    const float* b_ego1 = (const float*)d_in[6];
    const float* W_gcn1 = (const float*)d_in[7];
    const float* b_gcn1 = (const float*)d_in[8];
    const float* W_ego2 = (const float*)d_in[9];
    const float* b_ego2 = (const float*)d_in[10];
    const float* W_gcn2 = (const float*)d_in[11];
    const float* b_gcn2 = (const float*)d_in[12];
    const int* src = eidx;
    const int* dst = eidx + NE;

    // ---- workspace layout (~103 MB) ----
    int* ip = (int*)d_ws;
    int* deg       = ip;                    // NN  (zeroed)
    int* edeg      = deg + NN;              // NN  (zeroed)
    int* rowstart  = edeg + NN;             // NN+1
    int* erowstart = rowstart + NN + 8;     // NN+1
    int* csr_src   = erowstart + NN + 8;    // NE
    int* ecsr      = csr_src + NE;          // NN*KE
    int* scantmp   = ecsr + NN * KE;        // 2*NN
    int* bsums     = scantmp + 2 * NN;      // 2*NB (+pad)
    int* posarr    = bsums + 256;           // TOT
    float* dinv = (float*)(posarr + TOT);               // NN
    unsigned short* mA = (unsigned short*)(dinv + NN);   // NN*128 bf16 msgs L1
    unsigned short* hA = mA + (size_t)NN * FIN;          // NN*128 bf16 hidden
    unsigned short* m2 = hA + (size_t)NN * FIN;          // NN*64  bf16 msgs L2
    unsigned short* Y  = m2 + (size_t)NN * FOUT2;        // NN*KE*128 bf16

    // ---- CSR build overlapped with layer-1 ego apply (hist blocks FIRST) ----
    (void)hipMemsetAsync(deg, 0, 2 * NN * sizeof(int), stream);
    apply1_hist_kernel<<<HB + NN / 8, 256, 0, stream>>>(x, egoids, egoadj, Y,
                                                        dst, deg, edeg, posarr);
    scan_p1_kernel<<<2 * NB, 256, 0, stream>>>(deg, edeg, scantmp, bsums, dinv);
    scan_p2_kernel<<<1, 256, 0, stream>>>(bsums);
    scan_p3_kernel<<<2 * NB, 256, 0, stream>>>(scantmp, bsums, rowstart, erowstart);
    bucket2_kernel<<<HB, 256, 0, stream>>>(src, dst, egoids, rowstart,
                                           erowstart, posarr, csr_src, ecsr);

    // ---- layer 1 ----
    ego_dual_kernel<128, true><<<NN / 8, 256, 0, stream>>>(Y, erowstart, ecsr, ndeg,
                                                           W_ego1, b_ego1, W_gcn1, dinv, mA);
    gcn_gather128_kernel<<<NN / 4, 256, 0, stream>>>(mA, rowstart, csr_src, dinv, b_gcn1, hA);

    // ---- layer 2 ----
    ego_apply2_kernel<<<NN / 8, 256, 0, stream>>>(hA, egoids, egoadj, Y);
    ego_dual_kernel<64, false><<<NN / 8, 256, 0, stream>>>(Y, erowstart, ecsr, ndeg,
                                                           W_ego2, b_ego2, W_gcn2, dinv, m2);
    gcn_gather_lsm_kernel<<<NN / 4, 256, 0, stream>>>(m2, rowstart, csr_src, dinv, b_gcn2, (float*)d_out);
}

// Round 12
// 370.386 us; speedup vs baseline: 6.1273x; 1.0005x over previous
//
#include <hip/hip_runtime.h>
#include <hip/hip_bf16.h>

#define NN    20000   // nodes
#define KE    16      // ego-net size
#define FIN   128     // input feats / hidden
#define FOUT2 64      // output classes
#define NE    640000  // edges
#define NB    79      // scan blocks per array: ceil(NN/256)
#define TOT   (NE + NN * KE)        // 960000 items in unified hist/bucket space
#define HB    469                   // hist/bucket blocks: ceil(TOT/8/256)
#define APAD  17                    // padded row stride for A in LDS

// ---- bf16 helpers (ushort storage, fp32 math) ----
__device__ __forceinline__ float bf2f(unsigned short u) {
    union { float f; unsigned int i; } c; c.i = ((unsigned int)u) << 16; return c.f;
}
__device__ __forceinline__ unsigned short f2bf(float f) {
    union { float f; unsigned int i; } c; c.f = f;
    unsigned int lsb = (c.i >> 16) & 1u;
    c.i += 0x7fffu + lsb;           // round-to-nearest-even
    return (unsigned short)(c.i >> 16);
}
__device__ __forceinline__ float4 ldx4(const unsigned short* p, size_t i) {
    ushort4 u = *(const ushort4*)(p + i);
    float4 r; r.x = bf2f(u.x); r.y = bf2f(u.y); r.z = bf2f(u.z); r.w = bf2f(u.w);
    return r;
}

// ---- x (fp32) -> bf16, 4 elems/thread ----
__global__ __launch_bounds__(256) void xcvt_kernel(const float* __restrict__ x,
                                                   unsigned short* __restrict__ xbf) {
    const int i = (blockIdx.x * 256 + threadIdx.x) * 4;   // NN*FIN % 4 == 0
    float4 v = *(const float4*)&x[i];
    ushort4 o; o.x = f2bf(v.x); o.y = f2bf(v.y); o.z = f2bf(v.z); o.w = f2bf(v.w);
    *(ushort4*)&xbf[i] = o;
}

// ---- shared ego-apply body: Y[n] = (A@A) @ x[ids[n]] -> bf16 ---------------
// 8 nets per 256-thread block; 32 lanes per net, lane owns feature quad 4c.
__device__ __forceinline__ void ego_apply_body(
    const unsigned short* __restrict__ x, const int* __restrict__ ego_ids,
    const float* __restrict__ ego_adj, unsigned short* __restrict__ Y,
    float (*Ar)[KE * APAD], float (*As)[256], int (*ids)[KE], int n_base) {
    const int w = threadIdx.x >> 5;   // net slot 0..7
    const int c = threadIdx.x & 31;   // lane within net
    const int n = n_base + w;
    const float* a = ego_adj + (size_t)n * 256;
#pragma unroll
    for (int e = 0; e < 8; ++e) {     // load A into padded LDS
        const int idx = c * 8 + e;
        Ar[w][(idx >> 4) * APAD + (idx & 15)] = a[idx];
    }
    if (c < KE) ids[w][c] = ego_ids[n * KE + c];
    __syncthreads();
    {   // A2 entries 8c..8c+7: row i = c>>1, cols k0..k0+7 (k0 = (c&1)*8)
        const int i = c >> 1;
        const int k0 = (c & 1) * 8;
        float s[8] = {};
#pragma unroll
        for (int j = 0; j < KE; ++j) {
            const float aij = Ar[w][i * APAD + j];
            const float* arow = &Ar[w][j * APAD + k0];
#pragma unroll
            for (int q = 0; q < 8; ++q) s[q] += aij * arow[q];
        }
        float4 s0 = {s[0], s[1], s[2], s[3]}, s1 = {s[4], s[5], s[6], s[7]};
        *(float4*)&As[w][i * 16 + k0]     = s0;
        *(float4*)&As[w][i * 16 + k0 + 4] = s1;
    }
    __syncthreads();
    float4 xg[KE];                    // bf16 x: 8B/lane loads
#pragma unroll
    for (int k = 0; k < KE; ++k) xg[k] = ldx4(x, (size_t)ids[w][k] * FIN + 4 * c);
    unsigned short* yout = Y + (size_t)n * KE * FIN + 4 * c;
#pragma unroll
    for (int i = 0; i < KE; ++i) {
        float4 acc = {0.f, 0.f, 0.f, 0.f};
#pragma unroll
        for (int k = 0; k < KE; ++k) {
            const float a2 = As[w][i * 16 + k];      // broadcast read
            acc.x += a2 * xg[k].x; acc.y += a2 * xg[k].y;
            acc.z += a2 * xg[k].z; acc.w += a2 * xg[k].w;
        }
        ushort4 o; o.x = f2bf(acc.x); o.y = f2bf(acc.y);
        o.z = f2bf(acc.z); o.w = f2bf(acc.w);
        *(ushort4*)(yout + (size_t)i * FIN) = o;
    }
}

// ---- fused: hist+pos (blocks [0,HB)) || ego_apply layer-1 (blocks >= HB) ---
__global__ __launch_bounds__(256) void apply1_hist_kernel(
    const unsigned short* __restrict__ x, const int* __restrict__ ego_ids,
    const float* __restrict__ ego_adj, unsigned short* __restrict__ Y,
    const int* __restrict__ dst, int* __restrict__ deg, int* __restrict__ edeg,
    int* __restrict__ posarr) {
    __shared__ float Ar[8][KE * APAD];
    __shared__ float As[8][256];
    __shared__ int ids[8][KE];
    if (blockIdx.x < HB) {          // ---- histogram part (resident first) ----
        const int base = blockIdx.x * 2048 + threadIdx.x;
#pragma unroll
        for (int q = 0; q < 8; ++q) {
            const int i = base + q * 256;       // coalesced per q
            if (i < TOT) {
                if (i < NE) posarr[i] = atomicAdd(&deg[dst[i]], 1);
                else        posarr[i] = atomicAdd(&edeg[ego_ids[i - NE]], 1);
            }
        }
        return;
    }
    ego_apply_body(x, ego_ids, ego_adj, Y, Ar, As, ids, (blockIdx.x - HB) * 8);
}

// ---- plain ego apply (layer 2), 8 nets per 256-thr block -------------------
__global__ __launch_bounds__(256) void ego_apply2_kernel(
    const unsigned short* __restrict__ x, const int* __restrict__ ego_ids,
    const float* __restrict__ ego_adj, unsigned short* __restrict__ Y) {
    __shared__ float Ar[8][KE * APAD];
    __shared__ float As[8][256];
    __shared__ int ids[8][KE];
    ego_apply_body(x, ego_ids, ego_adj, Y, Ar, As, ids, blockIdx.x * 8);
}

// ---------------- 2-phase exclusive scan over deg and edeg -------------------
__global__ __launch_bounds__(256) void scan_p1_kernel(
    const int* __restrict__ deg, const int* __restrict__ edeg,
    int* __restrict__ scantmp, int* __restrict__ bsums, float* __restrict__ dinv) {
    const int arr = (blockIdx.x >= NB) ? 1 : 0;
    const int blk = blockIdx.x - arr * NB;
    const int t = threadIdx.x;
    const int i = blk * 256 + t;
    const int* cnt = arr ? edeg : deg;
    int v = (i < NN) ? cnt[i] : 0;
    if (!arr && i < NN) dinv[i] = rsqrtf((float)(v + 1));  // +1 self loop
    __shared__ int sh[256];
    sh[t] = v;
    __syncthreads();
    for (int o = 1; o < 256; o <<= 1) {
        int u = (t >= o) ? sh[t - o] : 0;
        __syncthreads();
        sh[t] += u;
        __syncthreads();
    }
    if (i < NN) scantmp[arr * NN + i] = sh[t] - v;  // exclusive within block
    if (t == 255) bsums[arr * NB + blk] = sh[255];  // raw block sum
}
// p3: each block recomputes its bsums prefix locally (NB=79 ints — trivial)
__global__ __launch_bounds__(256) void scan_p3_kernel(
    const int* __restrict__ scantmp, const int* __restrict__ bsums,
    int* __restrict__ rowstart, int* __restrict__ erowstart) {
    const int arr = (blockIdx.x >= NB) ? 1 : 0;
    const int blk = blockIdx.x - arr * NB;
    const int t = threadIdx.x;
    __shared__ int sh[256];
    int v = (t < NB) ? bsums[arr * NB + t] : 0;
    sh[t] = v;
    __syncthreads();
    for (int o = 1; o < 256; o <<= 1) {
        int u = (t >= o) ? sh[t - o] : 0;
        __syncthreads();
        sh[t] += u;
        __syncthreads();
    }
    const int blkofs = (blk == 0) ? 0 : sh[blk - 1];  // inclusive prefix at blk-1
    const int i = blk * 256 + t;
    if (i < NN) {
        int val = scantmp[arr * NN + i] + blkofs;
        if (arr) erowstart[i] = val; else rowstart[i] = val;
    }
    if (blockIdx.x == 0 && t == 0) { rowstart[NN] = NE; erowstart[NN] = NN * KE; }
}

// ---- bucket pass: pure scatter, no atomics ---------------------------------
__global__ void bucket2_kernel(const int* __restrict__ src, const int* __restrict__ dst,
                               const int* __restrict__ ego_flat,
                               const int* __restrict__ rowstart, const int* __restrict__ erowstart,
                               const int* __restrict__ posarr,
                               int* __restrict__ csr_src, int* __restrict__ ecsr) {
    const int base = blockIdx.x * 2048 + threadIdx.x;
#pragma unroll
    for (int q = 0; q < 8; ++q) {
        const int i = base + q * 256;
        if (i < TOT) {
            if (i < NE) {
                int d = dst[i];
                csr_src[rowstart[d] + posarr[i]] = src[i];
            } else {
                int p = i - NE;
                int v = ego_flat[p];
                ecsr[erowstart[v] + posarr[i]] = p;
            }
        }
    }
}

// ---- fused: ego reduce + ndeg scale + linear_ego(+relu) + linear_gcn*dinv ---
template <int FO, bool RELU>
__global__ __launch_bounds__(256) void ego_dual_kernel(
    const unsigned short* __restrict__ Y, const int* __restrict__ erowstart,
    const int* __restrict__ ecsr, const float* __restrict__ ndeg,
    const float* __restrict__ W1, const float* __restrict__ b1,
    const float* __restrict__ W2, const float* __restrict__ dinv,
    unsigned short* __restrict__ msg) {
    constexpr int ROWS = 8;
    const int r0 = blockIdx.x * ROWS;
    const int t = threadIdx.x;
    __shared__ float rows[ROWS][FIN];
    __shared__ float rows2[ROWS][FIN];
    {   // gather: half-wave split, ushort4 loads, combine via shfl_xor 32
        const int wv = t >> 6;
        const int h  = (t >> 5) & 1;
        const int c  = t & 31;
        for (int rr = 0; rr < ROWS; rr += 4) {
            const int r = rr + wv;
            const int v = r0 + r;
            float4 acc = {0.f, 0.f, 0.f, 0.f};
            const int pend = erowstart[v + 1];
            int p = erowstart[v] + h;
            for (; p + 2 < pend; p += 4) {
                int rowA = ecsr[p], rowB = ecsr[p + 2];
                float4 a = ldx4(Y, (size_t)rowA * FIN + 4 * c);
                float4 d4 = ldx4(Y, (size_t)rowB * FIN + 4 * c);
                acc.x += a.x + d4.x; acc.y += a.y + d4.y;
                acc.z += a.z + d4.z; acc.w += a.w + d4.w;
            }
            if (p < pend) {
                float4 a = ldx4(Y, (size_t)ecsr[p] * FIN + 4 * c);
                acc.x += a.x; acc.y += a.y; acc.z += a.z; acc.w += a.w;
            }
            acc.x += __shfl_xor(acc.x, 32);
            acc.y += __shfl_xor(acc.y, 32);
            acc.z += __shfl_xor(acc.z, 32);
            acc.w += __shfl_xor(acc.w, 32);
            if (h == 0) {
                const float nd = ndeg[v];
                float4 o = {acc.x * nd, acc.y * nd, acc.z * nd, acc.w * nd};
                *(float4*)&rows[r][4 * c] = o;
            }
        }
    }
    __syncthreads();
    {   // mm1: rows2 = relu(rows @ W1 + b1); LDS rows read as float4 (b128)
        const int j = t & 127;
        const int g = t >> 7;
        float acc[4] = {};
        for (int k = 0; k < FIN; k += 4) {
            const float w0 = W1[k * FIN + j],       w1 = W1[(k + 1) * FIN + j];
            const float w2 = W1[(k + 2) * FIN + j], w3 = W1[(k + 3) * FIN + j];
#pragma unroll
            for (int r = 0; r < 4; ++r) {
                float4 rv = *(const float4*)&rows[g * 4 + r][k];
                acc[r] += rv.x * w0 + rv.y * w1 + rv.z * w2 + rv.w * w3;
            }
        }
        const float bias = b1[j];
#pragma unroll
        for (int r = 0; r < 4; ++r) {
            float v = acc[r] + bias;
            if (RELU) v = fmaxf(v, 0.f);
            rows2[g * 4 + r][j] = v;
        }
    }
    __syncthreads();
    // mm2: msg = (rows2 @ W2) * dinv -> bf16
    if (FO == 128) {
        const int j = t & 127;
        const int g = t >> 7;
        float acc[4] = {};
        for (int k = 0; k < FIN; k += 4) {
            const float w0 = W2[k * FO + j],       w1 = W2[(k + 1) * FO + j];
            const float w2 = W2[(k + 2) * FO + j], w3 = W2[(k + 3) * FO + j];
#pragma unroll
            for (int r = 0; r < 4; ++r) {
                float4 rv = *(const float4*)&rows2[g * 4 + r][k];
                acc[r] += rv.x * w0 + rv.y * w1 + rv.z * w2 + rv.w * w3;
            }
        }
#pragma unroll
        for (int r = 0; r < 4; ++r) {
            const int v = r0 + g * 4 + r;
            msg[(size_t)v * FO + j] = f2bf(acc[r] * dinv[v]);
        }
    } else {  // FO == 64
        const int j = t & 63;
        const int g = t >> 6;
        float acc[2] = {};
        for (int k = 0; k < FIN; k += 4) {
            const float w0 = W2[k * FO + j],       w1 = W2[(k + 1) * FO + j];
            const float w2 = W2[(k + 2) * FO + j], w3 = W2[(k + 3) * FO + j];
#pragma unroll
            for (int r = 0; r < 2; ++r) {
                float4 rv = *(const float4*)&rows2[g * 2 + r][k];
                acc[r] += rv.x * w0 + rv.y * w1 + rv.z * w2 + rv.w * w3;
            }
        }
#pragma unroll
        for (int r = 0; r < 2; ++r) {
            const int v = r0 + g * 2 + r;
            msg[(size_t)v * FO + j] = f2bf(acc[r] * dinv[v]);
        }
    }
}

// ------- GCN gather (F=128, bf16 msgs), half-split ushort4 ------------------
__global__ __launch_bounds__(256) void gcn_gather128_kernel(
    const unsigned short* __restrict__ msg, const int* __restrict__ rowstart,
    const int* __restrict__ csr_src, const float* __restrict__ dinv,
    const float* __restrict__ b, unsigned short* __restrict__ out) {
    const int tid = threadIdx.x;
    const int d = blockIdx.x * 4 + (tid >> 6);
    const int h = (tid >> 5) & 1;
    const int c = tid & 31;
    float4 acc = {0.f, 0.f, 0.f, 0.f};
    if (h == 0) acc = ldx4(msg, (size_t)d * FIN + 4 * c);  // self loop
    const int eend = rowstart[d + 1];
    int e = rowstart[d] + h;
    for (; e + 2 < eend; e += 4) {
        int s0 = csr_src[e], s1 = csr_src[e + 2];
        float4 a = ldx4(msg, (size_t)s0 * FIN + 4 * c);
        float4 d4 = ldx4(msg, (size_t)s1 * FIN + 4 * c);
        acc.x += a.x + d4.x; acc.y += a.y + d4.y;
        acc.z += a.z + d4.z; acc.w += a.w + d4.w;
    }
    if (e < eend) {
        float4 a = ldx4(msg, (size_t)csr_src[e] * FIN + 4 * c);
        acc.x += a.x; acc.y += a.y; acc.z += a.z; acc.w += a.w;
    }
    acc.x += __shfl_xor(acc.x, 32);
    acc.y += __shfl_xor(acc.y, 32);
    acc.z += __shfl_xor(acc.z, 32);
    acc.w += __shfl_xor(acc.w, 32);
    if (h == 0) {
        const float di = dinv[d];
        const float4 bb = *(const float4*)&b[4 * c];
        ushort4 o;
        o.x = f2bf(acc.x * di + bb.x); o.y = f2bf(acc.y * di + bb.y);
        o.z = f2bf(acc.z * di + bb.z); o.w = f2bf(acc.w * di + bb.w);
        *(ushort4*)(out + (size_t)d * FIN + 4 * c) = o;
    }
}

// ------- fused GCN gather (F=64, bf16 msgs) + bias + log_softmax -> fp32 -----
__global__ __launch_bounds__(256) void gcn_gather_lsm_kernel(
    const unsigned short* __restrict__ msg, const int* __restrict__ rowstart,
    const int* __restrict__ csr_src, const float* __restrict__ dinv,
    const float* __restrict__ b, float* __restrict__ out) {
    const int tid = threadIdx.x;
    const int d = blockIdx.x * 4 + (tid >> 6);  // one 64-lane wave per node
    const int t = tid & 63;
    float s = bf2f(msg[(size_t)d * FOUT2 + t]);  // self loop
    int e = rowstart[d];
    const int eend = rowstart[d + 1];
    for (; e + 4 <= eend; e += 4) {
        int s0 = csr_src[e], s1 = csr_src[e + 1], s2 = csr_src[e + 2], s3 = csr_src[e + 3];
        s += bf2f(msg[(size_t)s0 * FOUT2 + t]) + bf2f(msg[(size_t)s1 * FOUT2 + t])
           + bf2f(msg[(size_t)s2 * FOUT2 + t]) + bf2f(msg[(size_t)s3 * FOUT2 + t]);
    }
    for (; e < eend; ++e) s += bf2f(msg[(size_t)csr_src[e] * FOUT2 + t]);
    const float xv = s * dinv[d] + b[t];
    float m = xv;
#pragma unroll
    for (int o = 32; o > 0; o >>= 1) m = fmaxf(m, __shfl_xor(m, o));
    float ex = __expf(xv - m);
    float sm = ex;
#pragma unroll
    for (int o = 32; o > 0; o >>= 1) sm += __shfl_xor(sm, o);
    out[(size_t)d * FOUT2 + t] = xv - m - __logf(sm);
}

extern "C" void kernel_launch(void* const* d_in, const int* in_sizes, int n_in,
                              void* d_out, int out_size, void* d_ws, size_t ws_size,
                              hipStream_t stream) {
    (void)in_sizes; (void)n_in; (void)out_size; (void)ws_size;
    const float* x      = (const float*)d_in[0];
    const int*   eidx   = (const int*)d_in[1];
    const int*   egoids = (const int*)d_in[2];
    const float* egoadj = (const float*)d_in[3];
    const float* ndeg   = (const float*)d_in[4];
    const float* W_ego1 = (const float*)d_in[5];
    const float* b_ego1 = (const float*)d_in[6];
    const float* W_gcn1 = (const float*)d_in[7];
    const float* b_gcn1 = (const float*)d_in[8];
    const float* W_ego2 = (const float*)d_in[9];
    const float* b_ego2 = (const float*)d_in[10];
    const float* W_gcn2 = (const float*)d_in[11];
    const float* b_gcn2 = (const float*)d_in[12];
    const int* src = eidx;
    const int* dst = eidx + NE;

    // ---- workspace layout (~108 MB) ----
    int* ip = (int*)d_ws;
    int* deg       = ip;                    // NN  (zeroed)
    int* edeg      = deg + NN;              // NN  (zeroed)
    int* rowstart  = edeg + NN;             // NN+1
    int* erowstart = rowstart + NN + 8;     // NN+1
    int* csr_src   = erowstart + NN + 8;    // NE
    int* ecsr      = csr_src + NE;          // NN*KE
    int* scantmp   = ecsr + NN * KE;        // 2*NN
    int* bsums     = scantmp + 2 * NN;      // 2*NB (+pad)
    int* posarr    = bsums + 256;           // TOT
    float* dinv = (float*)(posarr + TOT);               // NN
    unsigned short* xbf = (unsigned short*)(dinv + NN);  // NN*128 bf16 x
    unsigned short* mA = xbf + (size_t)NN * FIN;         // NN*128 bf16 msgs L1
    unsigned short* hA = mA + (size_t)NN * FIN;          // NN*128 bf16 hidden
    unsigned short* m2 = hA + (size_t)NN * FIN;          // NN*64  bf16 msgs L2
    unsigned short* Y  = m2 + (size_t)NN * FOUT2;        // NN*KE*128 bf16

    // ---- x -> bf16, then CSR build overlapped with layer-1 ego apply -------
    (void)hipMemsetAsync(deg, 0, 2 * NN * sizeof(int), stream);
    xcvt_kernel<<<NN * FIN / 1024, 256, 0, stream>>>(x, xbf);
    apply1_hist_kernel<<<HB + NN / 8, 256, 0, stream>>>(xbf, egoids, egoadj, Y,
                                                        dst, deg, edeg, posarr);
    scan_p1_kernel<<<2 * NB, 256, 0, stream>>>(deg, edeg, scantmp, bsums, dinv);
    scan_p3_kernel<<<2 * NB, 256, 0, stream>>>(scantmp, bsums, rowstart, erowstart);
    bucket2_kernel<<<HB, 256, 0, stream>>>(src, dst, egoids, rowstart,
                                           erowstart, posarr, csr_src, ecsr);

    // ---- layer 1 ----
    ego_dual_kernel<128, true><<<NN / 8, 256, 0, stream>>>(Y, erowstart, ecsr, ndeg,
                                                           W_ego1, b_ego1, W_gcn1, dinv, mA);
    gcn_gather128_kernel<<<NN / 4, 256, 0, stream>>>(mA, rowstart, csr_src, dinv, b_gcn1, hA);

    // ---- layer 2 ----
    ego_apply2_kernel<<<NN / 8, 256, 0, stream>>>(hA, egoids, egoadj, Y);
    ego_dual_kernel<64, false><<<NN / 8, 256, 0, stream>>>(Y, erowstart, ecsr, ndeg,
                                                           W_ego2, b_ego2, W_gcn2, dinv, m2);
    gcn_gather_lsm_kernel<<<NN / 4, 256, 0, stream>>>(m2, rowstart, csr_src, dinv, b_gcn2, (float*)d_out);
}

// Round 13
// 355.713 us; speedup vs baseline: 6.3801x; 1.0412x over previous
//
#include <hip/hip_runtime.h>
#include <hip/hip_bf16.h>

#define NN    20000   // nodes
#define KE    16      // ego-net size
#define FIN   128     // input feats / hidden
#define FOUT2 64      // output classes
#define NE    640000  // edges
#define NB    79      // scan blocks per array: ceil(NN/256)
#define TOT   (NE + NN * KE)        // 960000 items in unified hist/bucket space
#define HB    469                   // hist/bucket blocks: ceil(TOT/8/256)
#define XB    (NN * FIN / 1024)     // xcvt blocks (2500)
#define APAD  17                    // padded row stride for A in LDS

// ---- bf16 helpers (ushort storage, fp32 math) ----
__device__ __forceinline__ float bf2f(unsigned short u) {
    union { float f; unsigned int i; } c; c.i = ((unsigned int)u) << 16; return c.f;
}
__device__ __forceinline__ unsigned short f2bf(float f) {
    union { float f; unsigned int i; } c; c.f = f;
    unsigned int lsb = (c.i >> 16) & 1u;
    c.i += 0x7fffu + lsb;           // round-to-nearest-even
    return (unsigned short)(c.i >> 16);
}
__device__ __forceinline__ float4 ldx4(const unsigned short* p, size_t i) {
    ushort4 u = *(const ushort4*)(p + i);
    float4 r; r.x = bf2f(u.x); r.y = bf2f(u.y); r.z = bf2f(u.z); r.w = bf2f(u.w);
    return r;
}

// ---- fused: hist+pos (blocks [0,HB)) || x fp32->bf16 (blocks >= HB) --------
__global__ __launch_bounds__(256) void hist_xcvt_kernel(
    const int* __restrict__ dst, const int* __restrict__ ego_flat,
    int* __restrict__ deg, int* __restrict__ edeg, int* __restrict__ posarr,
    const float* __restrict__ x, unsigned short* __restrict__ xbf) {
    if (blockIdx.x < HB) {          // histogram + rank capture
        const int base = blockIdx.x * 2048 + threadIdx.x;
#pragma unroll
        for (int q = 0; q < 8; ++q) {
            const int i = base + q * 256;
            if (i < TOT) {
                if (i < NE) posarr[i] = atomicAdd(&deg[dst[i]], 1);
                else        posarr[i] = atomicAdd(&edeg[ego_flat[i - NE]], 1);
            }
        }
        return;
    }
    const int i = ((blockIdx.x - HB) * 256 + threadIdx.x) * 4;
    float4 v = *(const float4*)&x[i];
    ushort4 o; o.x = f2bf(v.x); o.y = f2bf(v.y); o.z = f2bf(v.z); o.w = f2bf(v.w);
    *(ushort4*)&xbf[i] = o;
}

// ---------------- 2-phase exclusive scan over deg and edeg -------------------
__global__ __launch_bounds__(256) void scan_p1_kernel(
    const int* __restrict__ deg, const int* __restrict__ edeg,
    int* __restrict__ scantmp, int* __restrict__ bsums, float* __restrict__ dinv) {
    const int arr = (blockIdx.x >= NB) ? 1 : 0;
    const int blk = blockIdx.x - arr * NB;
    const int t = threadIdx.x;
    const int i = blk * 256 + t;
    const int* cnt = arr ? edeg : deg;
    int v = (i < NN) ? cnt[i] : 0;
    if (!arr && i < NN) dinv[i] = rsqrtf((float)(v + 1));  // +1 self loop
    __shared__ int sh[256];
    sh[t] = v;
    __syncthreads();
    for (int o = 1; o < 256; o <<= 1) {
        int u = (t >= o) ? sh[t - o] : 0;
        __syncthreads();
        sh[t] += u;
        __syncthreads();
    }
    if (i < NN) scantmp[arr * NN + i] = sh[t] - v;  // exclusive within block
    if (t == 255) bsums[arr * NB + blk] = sh[255];  // raw block sum
}
// p3: each block recomputes its bsums prefix locally (NB=79 ints — trivial)
__global__ __launch_bounds__(256) void scan_p3_kernel(
    const int* __restrict__ scantmp, const int* __restrict__ bsums,
    int* __restrict__ rowstart, int* __restrict__ erowstart) {
    const int arr = (blockIdx.x >= NB) ? 1 : 0;
    const int blk = blockIdx.x - arr * NB;
    const int t = threadIdx.x;
    __shared__ int sh[256];
    int v = (t < NB) ? bsums[arr * NB + t] : 0;
    sh[t] = v;
    __syncthreads();
    for (int o = 1; o < 256; o <<= 1) {
        int u = (t >= o) ? sh[t - o] : 0;
        __syncthreads();
        sh[t] += u;
        __syncthreads();
    }
    const int blkofs = (blk == 0) ? 0 : sh[blk - 1];
    const int i = blk * 256 + t;
    if (i < NN) {
        int val = scantmp[arr * NN + i] + blkofs;
        if (arr) erowstart[i] = val; else rowstart[i] = val;
    }
    if (blockIdx.x == 0 && t == 0) { rowstart[NN] = NE; erowstart[NN] = NN * KE; }
}

// ---- bucket pass: edges -> csr_src (scatter); ego -> yslot (coalesced!) -----
// yslot[p] = CSR slot of membership p; apply scatters Y rows there so the
// reduce reads Y sequentially.
__global__ void bucket2_kernel(const int* __restrict__ src, const int* __restrict__ dst,
                               const int* __restrict__ ego_flat,
                               const int* __restrict__ rowstart, const int* __restrict__ erowstart,
                               const int* __restrict__ posarr,
                               int* __restrict__ csr_src, int* __restrict__ yslot) {
    const int base = blockIdx.x * 2048 + threadIdx.x;
#pragma unroll
    for (int q = 0; q < 8; ++q) {
        const int i = base + q * 256;
        if (i < TOT) {
            if (i < NE) {
                int d = dst[i];
                csr_src[rowstart[d] + posarr[i]] = src[i];
            } else {
                int p = i - NE;
                yslot[p] = erowstart[ego_flat[p]] + posarr[i];
            }
        }
    }
}

// ---- ego apply: Y[yslot[n,i]] = ((A@A) @ x[ids[n]])[i] -> bf16 -------------
// 8 nets per 256-thread block; 32 lanes per net; scattered row stores.
__global__ __launch_bounds__(256) void ego_apply_kernel(
    const unsigned short* __restrict__ x, const int* __restrict__ ego_ids,
    const float* __restrict__ ego_adj, const int* __restrict__ yslot,
    unsigned short* __restrict__ Y) {
    __shared__ float Ar[8][KE * APAD];
    __shared__ float As[8][256];
    __shared__ int ids[8][KE];
    __shared__ int slots[8][KE];
    const int w = threadIdx.x >> 5;   // net slot 0..7
    const int c = threadIdx.x & 31;   // lane within net
    const int n = blockIdx.x * 8 + w;
    const float* a = ego_adj + (size_t)n * 256;
#pragma unroll
    for (int e = 0; e < 8; ++e) {
        const int idx = c * 8 + e;
        Ar[w][(idx >> 4) * APAD + (idx & 15)] = a[idx];
    }
    if (c < KE) {
        ids[w][c] = ego_ids[n * KE + c];
        slots[w][c] = yslot[n * KE + c];
    }
    __syncthreads();
    {   // A2 entries 8c..8c+7: row i = c>>1, cols k0..k0+7
        const int i = c >> 1;
        const int k0 = (c & 1) * 8;
        float s[8] = {};
#pragma unroll
        for (int j = 0; j < KE; ++j) {
            const float aij = Ar[w][i * APAD + j];
            const float* arow = &Ar[w][j * APAD + k0];
#pragma unroll
            for (int q = 0; q < 8; ++q) s[q] += aij * arow[q];
        }
        float4 s0 = {s[0], s[1], s[2], s[3]}, s1 = {s[4], s[5], s[6], s[7]};
        *(float4*)&As[w][i * 16 + k0]     = s0;
        *(float4*)&As[w][i * 16 + k0 + 4] = s1;
    }
    __syncthreads();
    float4 xg[KE];
#pragma unroll
    for (int k = 0; k < KE; ++k) xg[k] = ldx4(x, (size_t)ids[w][k] * FIN + 4 * c);
#pragma unroll
    for (int i = 0; i < KE; ++i) {
        float4 acc = {0.f, 0.f, 0.f, 0.f};
#pragma unroll
        for (int k = 0; k < KE; ++k) {
            const float a2 = As[w][i * 16 + k];
            acc.x += a2 * xg[k].x; acc.y += a2 * xg[k].y;
            acc.z += a2 * xg[k].z; acc.w += a2 * xg[k].w;
        }
        ushort4 o; o.x = f2bf(acc.x); o.y = f2bf(acc.y);
        o.z = f2bf(acc.z); o.w = f2bf(acc.w);
        *(ushort4*)(Y + (size_t)slots[w][i] * FIN + 4 * c) = o;  // scatter row
    }
}

// ---- fused: ego reduce (SEQUENTIAL Y) + ndeg + linear1(+relu) + linear2*dinv
template <int FO, bool RELU>
__global__ __launch_bounds__(256) void ego_dual_kernel(
    const unsigned short* __restrict__ Y, const int* __restrict__ erowstart,
    const float* __restrict__ ndeg,
    const float* __restrict__ W1, const float* __restrict__ b1,
    const float* __restrict__ W2, const float* __restrict__ dinv,
    unsigned short* __restrict__ msg) {
    constexpr int ROWS = 8;
    const int r0 = blockIdx.x * ROWS;
    const int t = threadIdx.x;
    __shared__ float rows[ROWS][FIN];
    __shared__ float rows2[ROWS][FIN];
    {   // gather: contiguous slot range per node; parity split + shfl combine
        const int wv = t >> 6;
        const int h  = (t >> 5) & 1;
        const int c  = t & 31;
        for (int rr = 0; rr < ROWS; rr += 4) {
            const int r = rr + wv;
            const int v = r0 + r;
            float4 acc = {0.f, 0.f, 0.f, 0.f};
            const int send = erowstart[v + 1];
            int s = erowstart[v] + h;
            for (; s + 2 < send; s += 4) {
                float4 a = ldx4(Y, (size_t)s * FIN + 4 * c);
                float4 d4 = ldx4(Y, (size_t)(s + 2) * FIN + 4 * c);
                acc.x += a.x + d4.x; acc.y += a.y + d4.y;
                acc.z += a.z + d4.z; acc.w += a.w + d4.w;
            }
            if (s < send) {
                float4 a = ldx4(Y, (size_t)s * FIN + 4 * c);
                acc.x += a.x; acc.y += a.y; acc.z += a.z; acc.w += a.w;
            }
            acc.x += __shfl_xor(acc.x, 32);
            acc.y += __shfl_xor(acc.y, 32);
            acc.z += __shfl_xor(acc.z, 32);
            acc.w += __shfl_xor(acc.w, 32);
            if (h == 0) {
                const float nd = ndeg[v];
                float4 o = {acc.x * nd, acc.y * nd, acc.z * nd, acc.w * nd};
                *(float4*)&rows[r][4 * c] = o;
            }
        }
    }
    __syncthreads();
    {   // mm1: rows2 = relu(rows @ W1 + b1); LDS rows read as float4
        const int j = t & 127;
        const int g = t >> 7;
        float acc[4] = {};
        for (int k = 0; k < FIN; k += 4) {
            const float w0 = W1[k * FIN + j],       w1 = W1[(k + 1) * FIN + j];
            const float w2 = W1[(k + 2) * FIN + j], w3 = W1[(k + 3) * FIN + j];
#pragma unroll
            for (int r = 0; r < 4; ++r) {
                float4 rv = *(const float4*)&rows[g * 4 + r][k];
                acc[r] += rv.x * w0 + rv.y * w1 + rv.z * w2 + rv.w * w3;
            }
        }
        const float bias = b1[j];
#pragma unroll
        for (int r = 0; r < 4; ++r) {
            float v = acc[r] + bias;
            if (RELU) v = fmaxf(v, 0.f);
            rows2[g * 4 + r][j] = v;
        }
    }
    __syncthreads();
    // mm2: msg = (rows2 @ W2) * dinv -> bf16
    if (FO == 128) {
        const int j = t & 127;
        const int g = t >> 7;
        float acc[4] = {};
        for (int k = 0; k < FIN; k += 4) {
            const float w0 = W2[k * FO + j],       w1 = W2[(k + 1) * FO + j];
            const float w2 = W2[(k + 2) * FO + j], w3 = W2[(k + 3) * FO + j];
#pragma unroll
            for (int r = 0; r < 4; ++r) {
                float4 rv = *(const float4*)&rows2[g * 4 + r][k];
                acc[r] += rv.x * w0 + rv.y * w1 + rv.z * w2 + rv.w * w3;
            }
        }
#pragma unroll
        for (int r = 0; r < 4; ++r) {
            const int v = r0 + g * 4 + r;
            msg[(size_t)v * FO + j] = f2bf(acc[r] * dinv[v]);
        }
    } else {  // FO == 64
        const int j = t & 63;
        const int g = t >> 6;
        float acc[2] = {};
        for (int k = 0; k < FIN; k += 4) {
            const float w0 = W2[k * FO + j],       w1 = W2[(k + 1) * FO + j];
            const float w2 = W2[(k + 2) * FO + j], w3 = W2[(k + 3) * FO + j];
#pragma unroll
            for (int r = 0; r < 2; ++r) {
                float4 rv = *(const float4*)&rows2[g * 2 + r][k];
                acc[r] += rv.x * w0 + rv.y * w1 + rv.z * w2 + rv.w * w3;
            }
        }
#pragma unroll
        for (int r = 0; r < 2; ++r) {
            const int v = r0 + g * 2 + r;
            msg[(size_t)v * FO + j] = f2bf(acc[r] * dinv[v]);
        }
    }
}

// ------- GCN gather (F=128, bf16 msgs), half-split ushort4 (msg L2-resident) -
__global__ __launch_bounds__(256) void gcn_gather128_kernel(
    const unsigned short* __restrict__ msg, const int* __restrict__ rowstart,
    const int* __restrict__ csr_src, const float* __restrict__ dinv,
    const float* __restrict__ b, unsigned short* __restrict__ out) {
    const int tid = threadIdx.x;
    const int d = blockIdx.x * 4 + (tid >> 6);
    const int h = (tid >> 5) & 1;
    const int c = tid & 31;
    float4 acc = {0.f, 0.f, 0.f, 0.f};
    if (h == 0) acc = ldx4(msg, (size_t)d * FIN + 4 * c);  // self loop
    const int eend = rowstart[d + 1];
    int e = rowstart[d] + h;
    for (; e + 2 < eend; e += 4) {
        int s0 = csr_src[e], s1 = csr_src[e + 2];
        float4 a = ldx4(msg, (size_t)s0 * FIN + 4 * c);
        float4 d4 = ldx4(msg, (size_t)s1 * FIN + 4 * c);
        acc.x += a.x + d4.x; acc.y += a.y + d4.y;
        acc.z += a.z + d4.z; acc.w += a.w + d4.w;
    }
    if (e < eend) {
        float4 a = ldx4(msg, (size_t)csr_src[e] * FIN + 4 * c);
        acc.x += a.x; acc.y += a.y; acc.z += a.z; acc.w += a.w;
    }
    acc.x += __shfl_xor(acc.x, 32);
    acc.y += __shfl_xor(acc.y, 32);
    acc.z += __shfl_xor(acc.z, 32);
    acc.w += __shfl_xor(acc.w, 32);
    if (h == 0) {
        const float di = dinv[d];
        const float4 bb = *(const float4*)&b[4 * c];
        ushort4 o;
        o.x = f2bf(acc.x * di + bb.x); o.y = f2bf(acc.y * di + bb.y);
        o.z = f2bf(acc.z * di + bb.z); o.w = f2bf(acc.w * di + bb.w);
        *(ushort4*)(out + (size_t)d * FIN + 4 * c) = o;
    }
}

// ------- fused GCN gather (F=64, bf16 msgs) + bias + log_softmax -> fp32 -----
__global__ __launch_bounds__(256) void gcn_gather_lsm_kernel(
    const unsigned short* __restrict__ msg, const int* __restrict__ rowstart,
    const int* __restrict__ csr_src, const float* __restrict__ dinv,
    const float* __restrict__ b, float* __restrict__ out) {
    const int tid = threadIdx.x;
    const int d = blockIdx.x * 4 + (tid >> 6);  // one 64-lane wave per node
    const int t = tid & 63;
    float s = bf2f(msg[(size_t)d * FOUT2 + t]);  // self loop
    int e = rowstart[d];
    const int eend = rowstart[d + 1];
    for (; e + 4 <= eend; e += 4) {
        int s0 = csr_src[e], s1 = csr_src[e + 1], s2 = csr_src[e + 2], s3 = csr_src[e + 3];
        s += bf2f(msg[(size_t)s0 * FOUT2 + t]) + bf2f(msg[(size_t)s1 * FOUT2 + t])
           + bf2f(msg[(size_t)s2 * FOUT2 + t]) + bf2f(msg[(size_t)s3 * FOUT2 + t]);
    }
    for (; e < eend; ++e) s += bf2f(msg[(size_t)csr_src[e] * FOUT2 + t]);
    const float xv = s * dinv[d] + b[t];
    float m = xv;
#pragma unroll
    for (int o = 32; o > 0; o >>= 1) m = fmaxf(m, __shfl_xor(m, o));
    float ex = __expf(xv - m);
    float sm = ex;
#pragma unroll
    for (int o = 32; o > 0; o >>= 1) sm += __shfl_xor(sm, o);
    out[(size_t)d * FOUT2 + t] = xv - m - __logf(sm);
}

extern "C" void kernel_launch(void* const* d_in, const int* in_sizes, int n_in,
                              void* d_out, int out_size, void* d_ws, size_t ws_size,
                              hipStream_t stream) {
    (void)in_sizes; (void)n_in; (void)out_size; (void)ws_size;
    const float* x      = (const float*)d_in[0];
    const int*   eidx   = (const int*)d_in[1];
    const int*   egoids = (const int*)d_in[2];
    const float* egoadj = (const float*)d_in[3];
    const float* ndeg   = (const float*)d_in[4];
    const float* W_ego1 = (const float*)d_in[5];
    const float* b_ego1 = (const float*)d_in[6];
    const float* W_gcn1 = (const float*)d_in[7];
    const float* b_gcn1 = (const float*)d_in[8];
    const float* W_ego2 = (const float*)d_in[9];
    const float* b_ego2 = (const float*)d_in[10];
    const float* W_gcn2 = (const float*)d_in[11];
    const float* b_gcn2 = (const float*)d_in[12];
    const int* src = eidx;
    const int* dst = eidx + NE;

    // ---- workspace layout (~107 MB) ----
    int* ip = (int*)d_ws;
    int* deg       = ip;                    // NN  (zeroed)
    int* edeg      = deg + NN;              // NN  (zeroed)
    int* rowstart  = edeg + NN;             // NN+1
    int* erowstart = rowstart + NN + 8;     // NN+1
    int* csr_src   = erowstart + NN + 8;    // NE
    int* yslot     = csr_src + NE;          // NN*KE
    int* scantmp   = yslot + NN * KE;       // 2*NN
    int* bsums     = scantmp + 2 * NN;      // 2*NB (+pad)
    int* posarr    = bsums + 256;           // TOT
    float* dinv = (float*)(posarr + TOT);               // NN
    unsigned short* xbf = (unsigned short*)(dinv + NN);  // NN*128 bf16 x
    unsigned short* mA = xbf + (size_t)NN * FIN;         // NN*128 bf16 msgs L1
    unsigned short* hA = mA + (size_t)NN * FIN;          // NN*128 bf16 hidden
    unsigned short* m2 = hA + (size_t)NN * FIN;          // NN*64  bf16 msgs L2
    unsigned short* Y  = m2 + (size_t)NN * FOUT2;        // NN*KE*128 bf16 (CSR order)

    // ---- CSR build (hist || xcvt fused) ----
    (void)hipMemsetAsync(deg, 0, 2 * NN * sizeof(int), stream);
    hist_xcvt_kernel<<<HB + XB, 256, 0, stream>>>(dst, egoids, deg, edeg, posarr, x, xbf);
    scan_p1_kernel<<<2 * NB, 256, 0, stream>>>(deg, edeg, scantmp, bsums, dinv);
    scan_p3_kernel<<<2 * NB, 256, 0, stream>>>(scantmp, bsums, rowstart, erowstart);
    bucket2_kernel<<<HB, 256, 0, stream>>>(src, dst, egoids, rowstart,
                                           erowstart, posarr, csr_src, yslot);

    // ---- layer 1 ----
    ego_apply_kernel<<<NN / 8, 256, 0, stream>>>(xbf, egoids, egoadj, yslot, Y);
    ego_dual_kernel<128, true><<<NN / 8, 256, 0, stream>>>(Y, erowstart, ndeg,
                                                           W_ego1, b_ego1, W_gcn1, dinv, mA);
    gcn_gather128_kernel<<<NN / 4, 256, 0, stream>>>(mA, rowstart, csr_src, dinv, b_gcn1, hA);

    // ---- layer 2 ----
    ego_apply_kernel<<<NN / 8, 256, 0, stream>>>(hA, egoids, egoadj, yslot, Y);
    ego_dual_kernel<64, false><<<NN / 8, 256, 0, stream>>>(Y, erowstart, ndeg,
                                                           W_ego2, b_ego2, W_gcn2, dinv, m2);
    gcn_gather_lsm_kernel<<<NN / 4, 256, 0, stream>>>(m2, rowstart, csr_src, dinv, b_gcn2, (float*)d_out);
}

// Round 14
// 322.538 us; speedup vs baseline: 7.0363x; 1.1029x over previous
//
#include <hip/hip_runtime.h>
#include <hip/hip_bf16.h>

#define NN    20000   // nodes
#define KE    16      // ego-net size
#define FIN   128     // input feats / hidden
#define FOUT2 64      // output classes
#define NE    640000  // edges
#define NB    79      // scan blocks per array: ceil(NN/256)
#define TOT   (NE + NN * KE)        // 960000 items in unified hist/bucket space
#define HB    469                   // hist blocks: ceil(TOT/8/256)
#define GB1   1250                  // dense-GEMM blocks (16 rows each)
#define APAD  17                    // padded row stride for A in LDS

// ---- bf16 helpers (ushort storage, fp32 math) ----
__device__ __forceinline__ float bf2f(unsigned short u) {
    union { float f; unsigned int i; } c; c.i = ((unsigned int)u) << 16; return c.f;
}
__device__ __forceinline__ unsigned short f2bf(float f) {
    union { float f; unsigned int i; } c; c.f = f;
    unsigned int lsb = (c.i >> 16) & 1u;
    c.i += 0x7fffu + lsb;           // round-to-nearest-even
    return (unsigned short)(c.i >> 16);
}
__device__ __forceinline__ float4 ldx4(const unsigned short* p, size_t i) {
    ushort4 u = *(const ushort4*)(p + i);
    float4 r; r.x = bf2f(u.x); r.y = bf2f(u.y); r.z = bf2f(u.z); r.w = bf2f(u.w);
    return r;
}
__device__ __forceinline__ float2 ldu2(const unsigned short* p, size_t i) {
    ushort2 u = *(const ushort2*)(p + i);
    float2 r; r.x = bf2f(u.x); r.y = bf2f(u.y); return r;
}

// ---- mega: hist+pos [0,HB) || xW1 = x @ W_ego1 [HB,HB+GB1) || W_combo ------
__global__ __launch_bounds__(256) void mega_kernel(
    const int* __restrict__ dst, const int* __restrict__ ego_flat,
    int* __restrict__ deg, int* __restrict__ edeg, int* __restrict__ posarr,
    const float* __restrict__ x, const float* __restrict__ W1,
    unsigned short* __restrict__ xW1,
    const float* __restrict__ We2, const float* __restrict__ Wg2,
    const float* __restrict__ be2, float* __restrict__ Wc, float* __restrict__ bc) {
    __shared__ float rl[16][FIN];
    const int t = threadIdx.x;
    if (blockIdx.x < HB) {          // ---- histogram + rank capture ----
        const int base = blockIdx.x * 2048 + t;
#pragma unroll
        for (int q = 0; q < 8; ++q) {
            const int i = base + q * 256;
            if (i < TOT) {
                if (i < NE) posarr[i] = atomicAdd(&deg[dst[i]], 1);
                else        posarr[i] = atomicAdd(&edeg[ego_flat[i - NE]], 1);
            }
        }
        return;
    }
    if (blockIdx.x < HB + GB1) {    // ---- dense GEMM: xW1 = x @ W1 -> bf16 ----
        const int r0 = (blockIdx.x - HB) * 16;
        for (int idx = t; idx < 16 * FIN; idx += 256)
            rl[idx >> 7][idx & 127] = x[(size_t)(r0 + (idx >> 7)) * FIN + (idx & 127)];
        __syncthreads();
        const int j = t & 127, g = t >> 7;   // g: row group 0/1 -> rows 8g..8g+7
        float acc[8] = {};
        for (int k = 0; k < FIN; k += 4) {
            const float w0 = W1[k * FIN + j],       w1 = W1[(k + 1) * FIN + j];
            const float w2 = W1[(k + 2) * FIN + j], w3 = W1[(k + 3) * FIN + j];
#pragma unroll
            for (int r = 0; r < 8; ++r) {
                float4 rv = *(const float4*)&rl[g * 8 + r][k];
                acc[r] += rv.x * w0 + rv.y * w1 + rv.z * w2 + rv.w * w3;
            }
        }
#pragma unroll
        for (int r = 0; r < 8; ++r)
            xW1[(size_t)(r0 + g * 8 + r) * FIN + j] = f2bf(acc[r]);
        return;
    }
    // ---- W_combo = W_ego2 @ W_gcn2 (128x64), b_combo = b_ego2 @ W_gcn2 ----
    const int wb = blockIdx.x - HB - GB1;
    if (wb < 32) {
        const int row = wb * 4 + (t >> 6);
        const int j = t & 63;
        float s = 0.f;
        for (int k = 0; k < FIN; ++k) s += We2[row * FIN + k] * Wg2[k * FOUT2 + j];
        Wc[row * FOUT2 + j] = s;
    } else if (t < FOUT2) {
        float s = 0.f;
        for (int k = 0; k < FIN; ++k) s += be2[k] * Wg2[k * FOUT2 + t];
        bc[t] = s;
    }
}

// ---------------- 2-phase exclusive scan over deg and edeg -------------------
__global__ __launch_bounds__(256) void scan_p1_kernel(
    const int* __restrict__ deg, const int* __restrict__ edeg,
    int* __restrict__ scantmp, int* __restrict__ bsums, float* __restrict__ dinv) {
    const int arr = (blockIdx.x >= NB) ? 1 : 0;
    const int blk = blockIdx.x - arr * NB;
    const int t = threadIdx.x;
    const int i = blk * 256 + t;
    const int* cnt = arr ? edeg : deg;
    int v = (i < NN) ? cnt[i] : 0;
    if (!arr && i < NN) dinv[i] = rsqrtf((float)(v + 1));  // +1 self loop
    __shared__ int sh[256];
    sh[t] = v;
    __syncthreads();
    for (int o = 1; o < 256; o <<= 1) {
        int u = (t >= o) ? sh[t - o] : 0;
        __syncthreads();
        sh[t] += u;
        __syncthreads();
    }
    if (i < NN) scantmp[arr * NN + i] = sh[t] - v;
    if (t == 255) bsums[arr * NB + blk] = sh[255];
}
__global__ __launch_bounds__(256) void scan_p3_kernel(
    const int* __restrict__ scantmp, const int* __restrict__ bsums,
    int* __restrict__ rowstart, int* __restrict__ erowstart) {
    const int arr = (blockIdx.x >= NB) ? 1 : 0;
    const int blk = blockIdx.x - arr * NB;
    const int t = threadIdx.x;
    __shared__ int sh[256];
    int v = (t < NB) ? bsums[arr * NB + t] : 0;
    sh[t] = v;
    __syncthreads();
    for (int o = 1; o < 256; o <<= 1) {
        int u = (t >= o) ? sh[t - o] : 0;
        __syncthreads();
        sh[t] += u;
        __syncthreads();
    }
    const int blkofs = (blk == 0) ? 0 : sh[blk - 1];
    const int i = blk * 256 + t;
    if (i < NN) {
        int val = scantmp[arr * NN + i] + blkofs;
        if (arr) erowstart[i] = val; else rowstart[i] = val;
    }
    if (blockIdx.x == 0 && t == 0) { rowstart[NN] = NE; erowstart[NN] = NN * KE; }
}

// ---- bucket: edges -> csr_src; ego memberships -> yslot (coalesced) --------
__global__ void bucket2_kernel(const int* __restrict__ src, const int* __restrict__ dst,
                               const int* __restrict__ ego_flat,
                               const int* __restrict__ rowstart, const int* __restrict__ erowstart,
                               const int* __restrict__ posarr,
                               int* __restrict__ csr_src, int* __restrict__ yslot) {
    const int base = blockIdx.x * 2048 + threadIdx.x;
#pragma unroll
    for (int q = 0; q < 8; ++q) {
        const int i = base + q * 256;
        if (i < TOT) {
            if (i < NE) {
                int d = dst[i];
                csr_src[rowstart[d] + posarr[i]] = src[i];
            } else {
                int p = i - NE;
                yslot[p] = erowstart[ego_flat[p]] + posarr[i];
            }
        }
    }
}

// ---- ego apply (128-wide): Y[yslot[n,i]] = ((A@A) @ xW1[ids[n]])[i] --------
__global__ __launch_bounds__(256) void ego_apply_kernel(
    const unsigned short* __restrict__ x, const int* __restrict__ ego_ids,
    const float* __restrict__ ego_adj, const int* __restrict__ yslot,
    unsigned short* __restrict__ Y) {
    __shared__ float Ar[8][KE * APAD];
    __shared__ float As[8][256];
    __shared__ int ids[8][KE];
    __shared__ int slots[8][KE];
    const int w = threadIdx.x >> 5;
    const int c = threadIdx.x & 31;
    const int n = blockIdx.x * 8 + w;
    const float* a = ego_adj + (size_t)n * 256;
#pragma unroll
    for (int e = 0; e < 8; ++e) {
        const int idx = c * 8 + e;
        Ar[w][(idx >> 4) * APAD + (idx & 15)] = a[idx];
    }
    if (c < KE) {
        ids[w][c] = ego_ids[n * KE + c];
        slots[w][c] = yslot[n * KE + c];
    }
    __syncthreads();
    {
        const int i = c >> 1;
        const int k0 = (c & 1) * 8;
        float s[8] = {};
#pragma unroll
        for (int j = 0; j < KE; ++j) {
            const float aij = Ar[w][i * APAD + j];
            const float* arow = &Ar[w][j * APAD + k0];
#pragma unroll
            for (int q = 0; q < 8; ++q) s[q] += aij * arow[q];
        }
        float4 s0 = {s[0], s[1], s[2], s[3]}, s1 = {s[4], s[5], s[6], s[7]};
        *(float4*)&As[w][i * 16 + k0]     = s0;
        *(float4*)&As[w][i * 16 + k0 + 4] = s1;
    }
    __syncthreads();
    float4 xg[KE];
#pragma unroll
    for (int k = 0; k < KE; ++k) xg[k] = ldx4(x, (size_t)ids[w][k] * FIN + 4 * c);
#pragma unroll
    for (int i = 0; i < KE; ++i) {
        float4 acc = {0.f, 0.f, 0.f, 0.f};
#pragma unroll
        for (int k = 0; k < KE; ++k) {
            const float a2 = As[w][i * 16 + k];
            acc.x += a2 * xg[k].x; acc.y += a2 * xg[k].y;
            acc.z += a2 * xg[k].z; acc.w += a2 * xg[k].w;
        }
        ushort4 o; o.x = f2bf(acc.x); o.y = f2bf(acc.y);
        o.z = f2bf(acc.z); o.w = f2bf(acc.w);
        *(ushort4*)(Y + (size_t)slots[w][i] * FIN + 4 * c) = o;
    }
}

// ---- dual1: rows = relu(ndeg*sumY + b1); msg = (rows @ Wg1)*dinv -> bf16 ----
__global__ __launch_bounds__(256) void dual1_kernel(
    const unsigned short* __restrict__ Y, const int* __restrict__ erowstart,
    const float* __restrict__ ndeg, const float* __restrict__ b1,
    const float* __restrict__ Wg1, const float* __restrict__ dinv,
    unsigned short* __restrict__ msg) {
    constexpr int ROWS = 8;
    const int r0 = blockIdx.x * ROWS;
    const int t = threadIdx.x;
    __shared__ float rows[ROWS][FIN];
    {   // gather sequential Y + bias + relu
        const int wv = t >> 6;
        const int h  = (t >> 5) & 1;
        const int c  = t & 31;
        for (int rr = 0; rr < ROWS; rr += 4) {
            const int r = rr + wv;
            const int v = r0 + r;
            float4 acc = {0.f, 0.f, 0.f, 0.f};
            const int send = erowstart[v + 1];
            int s = erowstart[v] + h;
            for (; s + 2 < send; s += 4) {
                float4 a = ldx4(Y, (size_t)s * FIN + 4 * c);
                float4 d4 = ldx4(Y, (size_t)(s + 2) * FIN + 4 * c);
                acc.x += a.x + d4.x; acc.y += a.y + d4.y;
                acc.z += a.z + d4.z; acc.w += a.w + d4.w;
            }
            if (s < send) {
                float4 a = ldx4(Y, (size_t)s * FIN + 4 * c);
                acc.x += a.x; acc.y += a.y; acc.z += a.z; acc.w += a.w;
            }
            acc.x += __shfl_xor(acc.x, 32);
            acc.y += __shfl_xor(acc.y, 32);
            acc.z += __shfl_xor(acc.z, 32);
            acc.w += __shfl_xor(acc.w, 32);
            if (h == 0) {
                const float nd = ndeg[v];
                const float4 bb = *(const float4*)&b1[4 * c];
                float4 o;
                o.x = fmaxf(acc.x * nd + bb.x, 0.f);
                o.y = fmaxf(acc.y * nd + bb.y, 0.f);
                o.z = fmaxf(acc.z * nd + bb.z, 0.f);
                o.w = fmaxf(acc.w * nd + bb.w, 0.f);
                *(float4*)&rows[r][4 * c] = o;
            }
        }
    }
    __syncthreads();
    {   // msg = (rows @ Wg1) * dinv
        const int j = t & 127;
        const int g = t >> 7;
        float acc[4] = {};
        for (int k = 0; k < FIN; k += 4) {
            const float w0 = Wg1[k * FIN + j],       w1 = Wg1[(k + 1) * FIN + j];
            const float w2 = Wg1[(k + 2) * FIN + j], w3 = Wg1[(k + 3) * FIN + j];
#pragma unroll
            for (int r = 0; r < 4; ++r) {
                float4 rv = *(const float4*)&rows[g * 4 + r][k];
                acc[r] += rv.x * w0 + rv.y * w1 + rv.z * w2 + rv.w * w3;
            }
        }
#pragma unroll
        for (int r = 0; r < 4; ++r) {
            const int v = r0 + g * 4 + r;
            msg[(size_t)v * FIN + j] = f2bf(acc[r] * dinv[v]);
        }
    }
}

// ------- GCN gather (F=128), half-split ushort4 -----------------------------
__global__ __launch_bounds__(256) void gcn_gather128_kernel(
    const unsigned short* __restrict__ msg, const int* __restrict__ rowstart,
    const int* __restrict__ csr_src, const float* __restrict__ dinv,
    const float* __restrict__ b, unsigned short* __restrict__ out) {
    const int tid = threadIdx.x;
    const int d = blockIdx.x * 4 + (tid >> 6);
    const int h = (tid >> 5) & 1;
    const int c = tid & 31;
    float4 acc = {0.f, 0.f, 0.f, 0.f};
    if (h == 0) acc = ldx4(msg, (size_t)d * FIN + 4 * c);  // self loop
    const int eend = rowstart[d + 1];
    int e = rowstart[d] + h;
    for (; e + 2 < eend; e += 4) {
        int s0 = csr_src[e], s1 = csr_src[e + 2];
        float4 a = ldx4(msg, (size_t)s0 * FIN + 4 * c);
        float4 d4 = ldx4(msg, (size_t)s1 * FIN + 4 * c);
        acc.x += a.x + d4.x; acc.y += a.y + d4.y;
        acc.z += a.z + d4.z; acc.w += a.w + d4.w;
    }
    if (e < eend) {
        float4 a = ldx4(msg, (size_t)csr_src[e] * FIN + 4 * c);
        acc.x += a.x; acc.y += a.y; acc.z += a.z; acc.w += a.w;
    }
    acc.x += __shfl_xor(acc.x, 32);
    acc.y += __shfl_xor(acc.y, 32);
    acc.z += __shfl_xor(acc.z, 32);
    acc.w += __shfl_xor(acc.w, 32);
    if (h == 0) {
        const float di = dinv[d];
        const float4 bb = *(const float4*)&b[4 * c];
        ushort4 o;
        o.x = f2bf(acc.x * di + bb.x); o.y = f2bf(acc.y * di + bb.y);
        o.z = f2bf(acc.z * di + bb.z); o.w = f2bf(acc.w * di + bb.w);
        *(ushort4*)(out + (size_t)d * FIN + 4 * c) = o;
    }
}

// ---- gemm2: hW2 = hA @ W_combo (128->64) -> bf16 ---------------------------
__global__ __launch_bounds__(256) void gemm2_kernel(
    const unsigned short* __restrict__ hA, const float* __restrict__ Wc,
    unsigned short* __restrict__ hW2) {
    __shared__ float rl[16][FIN];
    const int t = threadIdx.x;
    const int r0 = blockIdx.x * 16;
    for (int idx = t; idx < 16 * FIN; idx += 256)
        rl[idx >> 7][idx & 127] = bf2f(hA[(size_t)(r0 + (idx >> 7)) * FIN + (idx & 127)]);
    __syncthreads();
    const int j = t & 63, g = t >> 6;    // g 0..3 -> rows 4g..4g+3
    float acc[4] = {};
    for (int k = 0; k < FIN; k += 4) {
        const float w0 = Wc[k * FOUT2 + j],       w1 = Wc[(k + 1) * FOUT2 + j];
        const float w2 = Wc[(k + 2) * FOUT2 + j], w3 = Wc[(k + 3) * FOUT2 + j];
#pragma unroll
        for (int r = 0; r < 4; ++r) {
            float4 rv = *(const float4*)&rl[g * 4 + r][k];
            acc[r] += rv.x * w0 + rv.y * w1 + rv.z * w2 + rv.w * w3;
        }
    }
#pragma unroll
    for (int r = 0; r < 4; ++r)
        hW2[(size_t)(r0 + g * 4 + r) * FOUT2 + j] = f2bf(acc[r]);
}

// ---- ego apply (64-wide): Y2[yslot] = (A@A) @ hW2[ids] ---------------------
__global__ __launch_bounds__(256) void apply2_kernel(
    const unsigned short* __restrict__ hW2, const int* __restrict__ ego_ids,
    const float* __restrict__ ego_adj, const int* __restrict__ yslot,
    unsigned short* __restrict__ Y2) {
    __shared__ float Ar[8][KE * APAD];
    __shared__ float As[8][256];
    __shared__ int ids[8][KE];
    __shared__ int slots[8][KE];
    const int w = threadIdx.x >> 5;
    const int c = threadIdx.x & 31;
    const int n = blockIdx.x * 8 + w;
    const float* a = ego_adj + (size_t)n * 256;
#pragma unroll
    for (int e = 0; e < 8; ++e) {
        const int idx = c * 8 + e;
        Ar[w][(idx >> 4) * APAD + (idx & 15)] = a[idx];
    }
    if (c < KE) {
        ids[w][c] = ego_ids[n * KE + c];
        slots[w][c] = yslot[n * KE + c];
    }
    __syncthreads();
    {
        const int i = c >> 1;
        const int k0 = (c & 1) * 8;
        float s[8] = {};
#pragma unroll
        for (int j = 0; j < KE; ++j) {
            const float aij = Ar[w][i * APAD + j];
            const float* arow = &Ar[w][j * APAD + k0];
#pragma unroll
            for (int q = 0; q < 8; ++q) s[q] += aij * arow[q];
        }
        float4 s0 = {s[0], s[1], s[2], s[3]}, s1 = {s[4], s[5], s[6], s[7]};
        *(float4*)&As[w][i * 16 + k0]     = s0;
        *(float4*)&As[w][i * 16 + k0 + 4] = s1;
    }
    __syncthreads();
    float2 xg[KE];
#pragma unroll
    for (int k = 0; k < KE; ++k) xg[k] = ldu2(hW2, (size_t)ids[w][k] * FOUT2 + 2 * c);
#pragma unroll
    for (int i = 0; i < KE; ++i) {
        float sx = 0.f, sy = 0.f;
#pragma unroll
        for (int k = 0; k < KE; ++k) {
            const float a2 = As[w][i * 16 + k];
            sx += a2 * xg[k].x; sy += a2 * xg[k].y;
        }
        ushort2 o; o.x = f2bf(sx); o.y = f2bf(sy);
        *(ushort2*)(Y2 + (size_t)slots[w][i] * FOUT2 + 2 * c) = o;
    }
}

// ---- dual2 (matmul-free): m2 = ((ndeg*sumY2) + b_combo)*dinv -> bf16 -------
__global__ __launch_bounds__(256) void dual2_kernel(
    const unsigned short* __restrict__ Y2, const int* __restrict__ erowstart,
    const float* __restrict__ ndeg, const float* __restrict__ bc,
    const float* __restrict__ dinv, unsigned short* __restrict__ m2) {
    const int tid = threadIdx.x;
    const int d = blockIdx.x * 4 + (tid >> 6);
    const int h = (tid >> 5) & 1;
    const int c = tid & 31;
    float2 acc = {0.f, 0.f};
    const int send = erowstart[d + 1];
    int s = erowstart[d] + h;
    for (; s + 2 < send; s += 4) {
        float2 a = ldu2(Y2, (size_t)s * FOUT2 + 2 * c);
        float2 b2 = ldu2(Y2, (size_t)(s + 2) * FOUT2 + 2 * c);
        acc.x += a.x + b2.x; acc.y += a.y + b2.y;
    }
    if (s < send) {
        float2 a = ldu2(Y2, (size_t)s * FOUT2 + 2 * c);
        acc.x += a.x; acc.y += a.y;
    }
    acc.x += __shfl_xor(acc.x, 32);
    acc.y += __shfl_xor(acc.y, 32);
    if (h == 0) {
        const float nd = ndeg[d], di = dinv[d];
        const float2 bb = *(const float2*)&bc[2 * c];
        ushort2 o;
        o.x = f2bf((acc.x * nd + bb.x) * di);
        o.y = f2bf((acc.y * nd + bb.y) * di);
        *(ushort2*)(m2 + (size_t)d * FOUT2 + 2 * c) = o;
    }
}

// ------- fused GCN gather (F=64) + bias + log_softmax -> fp32 ---------------
__global__ __launch_bounds__(256) void gcn_gather_lsm_kernel(
    const unsigned short* __restrict__ msg, const int* __restrict__ rowstart,
    const int* __restrict__ csr_src, const float* __restrict__ dinv,
    const float* __restrict__ b, float* __restrict__ out) {
    const int tid = threadIdx.x;
    const int d = blockIdx.x * 4 + (tid >> 6);
    const int t = tid & 63;
    float s = bf2f(msg[(size_t)d * FOUT2 + t]);  // self loop
    int e = rowstart[d];
    const int eend = rowstart[d + 1];
    for (; e + 4 <= eend; e += 4) {
        int s0 = csr_src[e], s1 = csr_src[e + 1], s2 = csr_src[e + 2], s3 = csr_src[e + 3];
        s += bf2f(msg[(size_t)s0 * FOUT2 + t]) + bf2f(msg[(size_t)s1 * FOUT2 + t])
           + bf2f(msg[(size_t)s2 * FOUT2 + t]) + bf2f(msg[(size_t)s3 * FOUT2 + t]);
    }
    for (; e < eend; ++e) s += bf2f(msg[(size_t)csr_src[e] * FOUT2 + t]);
    const float xv = s * dinv[d] + b[t];
    float m = xv;
#pragma unroll
    for (int o = 32; o > 0; o >>= 1) m = fmaxf(m, __shfl_xor(m, o));
    float ex = __expf(xv - m);
    float sm = ex;
#pragma unroll
    for (int o = 32; o > 0; o >>= 1) sm += __shfl_xor(sm, o);
    out[(size_t)d * FOUT2 + t] = xv - m - __logf(sm);
}

extern "C" void kernel_launch(void* const* d_in, const int* in_sizes, int n_in,
                              void* d_out, int out_size, void* d_ws, size_t ws_size,
                              hipStream_t stream) {
    (void)in_sizes; (void)n_in; (void)out_size; (void)ws_size;
    const float* x      = (const float*)d_in[0];
    const int*   eidx   = (const int*)d_in[1];
    const int*   egoids = (const int*)d_in[2];
    const float* egoadj = (const float*)d_in[3];
    const float* ndeg   = (const float*)d_in[4];
    const float* W_ego1 = (const float*)d_in[5];
    const float* b_ego1 = (const float*)d_in[6];
    const float* W_gcn1 = (const float*)d_in[7];
    const float* b_gcn1 = (const float*)d_in[8];
    const float* W_ego2 = (const float*)d_in[9];
    const float* b_ego2 = (const float*)d_in[10];
    const float* W_gcn2 = (const float*)d_in[11];
    const float* b_gcn2 = (const float*)d_in[12];
    const int* src = eidx;
    const int* dst = eidx + NE;

    // ---- workspace layout (~111 MB) ----
    int* ip = (int*)d_ws;
    int* deg       = ip;                    // NN  (zeroed)
    int* edeg      = deg + NN;              // NN  (zeroed)
    int* rowstart  = edeg + NN;             // NN+1
    int* erowstart = rowstart + NN + 8;     // NN+1
    int* csr_src   = erowstart + NN + 8;    // NE
    int* yslot     = csr_src + NE;          // NN*KE
    int* scantmp   = yslot + NN * KE;       // 2*NN
    int* bsums     = scantmp + 2 * NN;      // 2*NB (+pad)
    int* posarr    = bsums + 256;           // TOT
    float* dinv = (float*)(posarr + TOT);               // NN
    float* Wc   = dinv + NN;                            // 128*64 fp32
    float* bc   = Wc + FIN * FOUT2;                     // 64 (+pad)
    unsigned short* xW1 = (unsigned short*)(bc + 64);    // NN*128 bf16
    unsigned short* mA  = xW1 + (size_t)NN * FIN;        // NN*128 bf16 msgs L1
    unsigned short* hA  = mA + (size_t)NN * FIN;         // NN*128 bf16 hidden
    unsigned short* hW2 = hA + (size_t)NN * FIN;         // NN*64  bf16
    unsigned short* m2  = hW2 + (size_t)NN * FOUT2;      // NN*64  bf16 msgs L2
    unsigned short* Y   = m2 + (size_t)NN * FOUT2;       // NN*KE*128 bf16 (CSR order)

    // ---- CSR build || xW1 GEMM || W_combo ----
    (void)hipMemsetAsync(deg, 0, 2 * NN * sizeof(int), stream);
    mega_kernel<<<HB + GB1 + 33, 256, 0, stream>>>(dst, egoids, deg, edeg, posarr,
                                                   x, W_ego1, xW1,
                                                   W_ego2, W_gcn2, b_ego2, Wc, bc);
    scan_p1_kernel<<<2 * NB, 256, 0, stream>>>(deg, edeg, scantmp, bsums, dinv);
    scan_p3_kernel<<<2 * NB, 256, 0, stream>>>(scantmp, bsums, rowstart, erowstart);
    bucket2_kernel<<<HB, 256, 0, stream>>>(src, dst, egoids, rowstart,
                                           erowstart, posarr, csr_src, yslot);

    // ---- layer 1 ----
    ego_apply_kernel<<<NN / 8, 256, 0, stream>>>(xW1, egoids, egoadj, yslot, Y);
    dual1_kernel<<<NN / 8, 256, 0, stream>>>(Y, erowstart, ndeg, b_ego1, W_gcn1, dinv, mA);
    gcn_gather128_kernel<<<NN / 4, 256, 0, stream>>>(mA, rowstart, csr_src, dinv, b_gcn1, hA);

    // ---- layer 2 (weights pre-combined; ego runs on 64-wide hW2) ----
    gemm2_kernel<<<GB1, 256, 0, stream>>>(hA, Wc, hW2);
    apply2_kernel<<<NN / 8, 256, 0, stream>>>(hW2, egoids, egoadj, yslot, Y);
    dual2_kernel<<<NN / 4, 256, 0, stream>>>(Y, erowstart, ndeg, bc, dinv, m2);
    gcn_gather_lsm_kernel<<<NN / 4, 256, 0, stream>>>(m2, rowstart, csr_src, dinv, b_gcn2, (float*)d_out);
}